// Round 12
// baseline (4272.050 us; speedup 1.0000x reference)
//
#include <hip/hip_runtime.h>
#include <hip/hip_bf16.h>
#include <math.h>

// Dims: B=16 S=512 D=768 H=12 DH=64 F=3072 LYR=12 NLAB=2; rows = B*S = 8192
typedef __bf16 bf16_t;
typedef __attribute__((ext_vector_type(8))) __bf16 bf16x8;
typedef __attribute__((ext_vector_type(4))) float f32x4;

typedef const __attribute__((address_space(1))) void av1_void;
typedef __attribute__((address_space(3))) void av3_void;

#define DEV static __device__ __forceinline__

DEV void gload16(const void* g, void* l) {
  __builtin_amdgcn_global_load_lds((av1_void*)g, (av3_void*)l, 16, 0, 0);
}

// ---- block reduction over 3 waves (block=192) ----
DEV float bsum3(float v, float* red) {
#pragma unroll
  for (int o = 32; o > 0; o >>= 1) v += __shfl_xor(v, o, 64);
  __syncthreads();
  if ((threadIdx.x & 63) == 0) red[threadIdx.x >> 6] = v;
  __syncthreads();
  return red[0] + red[1] + red[2];
}

// ---- embedding gather + emb-LN -> x (fp32), then ln1(layer0) -> h (bf16) ----
__global__ __launch_bounds__(192) void k_embed(
    const int* __restrict__ ids, const float* __restrict__ tok,
    const float* __restrict__ pos, const float* __restrict__ gam,
    const float* __restrict__ bet, const float* __restrict__ gam2,
    const float* __restrict__ bet2, float* __restrict__ x,
    bf16_t* __restrict__ h) {
  __shared__ float red[3];
  int row = blockIdx.x;          // b*512 + s
  int s = row & 511;
  int t = threadIdx.x;
  int id = ids[row];
  const float4 tv = *(const float4*)&tok[(size_t)id * 768 + t * 4];
  const float4 pv = *(const float4*)&pos[(size_t)s * 768 + t * 4];
  float v[4] = {tv.x + pv.x, tv.y + pv.y, tv.z + pv.z, tv.w + pv.w};
  float tot = bsum3(v[0] + v[1] + v[2] + v[3], red);
  float mu = tot * (1.f / 768.f);
  float sq = 0.f;
#pragma unroll
  for (int u = 0; u < 4; ++u) { float d = v[u] - mu; sq += d * d; }
  float var = bsum3(sq, red) * (1.f / 768.f);
  float rstd = rsqrtf(var + 1e-5f);
  const float4 g4 = *(const float4*)&gam[t * 4];
  const float4 b4 = *(const float4*)&bet[t * 4];
  float o[4];
  o[0] = (v[0] - mu) * rstd * g4.x + b4.x;
  o[1] = (v[1] - mu) * rstd * g4.y + b4.y;
  o[2] = (v[2] - mu) * rstd * g4.z + b4.z;
  o[3] = (v[3] - mu) * rstd * g4.w + b4.w;
  float4 ov = {o[0], o[1], o[2], o[3]};
  *(float4*)&x[(size_t)row * 768 + t * 4] = ov;
  // second LN (ln1 of layer 0) -> h
  float tot2 = bsum3(o[0] + o[1] + o[2] + o[3], red);
  float mu2 = tot2 * (1.f / 768.f);
  float sq2 = 0.f;
#pragma unroll
  for (int u = 0; u < 4; ++u) { float d = o[u] - mu2; sq2 += d * d; }
  float var2 = bsum3(sq2, red) * (1.f / 768.f);
  float rstd2 = rsqrtf(var2 + 1e-5f);
  const float4 G = *(const float4*)&gam2[t * 4];
  const float4 Bb = *(const float4*)&bet2[t * 4];
  union { bf16_t ob[4]; uint2 u2; } pk;
  pk.ob[0] = (bf16_t)((o[0] - mu2) * rstd2 * G.x + Bb.x);
  pk.ob[1] = (bf16_t)((o[1] - mu2) * rstd2 * G.y + Bb.y);
  pk.ob[2] = (bf16_t)((o[2] - mu2) * rstd2 * G.z + Bb.z);
  pk.ob[3] = (bf16_t)((o[3] - mu2) * rstd2 * G.w + Bb.w);
  *(uint2*)&h[(size_t)row * 768 + t * 4] = pk.u2;
}

// ---- LN: x (fp32) -> h (bf16) ----
__global__ __launch_bounds__(192) void k_ln(
    const float* __restrict__ xin, bf16_t* __restrict__ hout,
    const float* __restrict__ gam, const float* __restrict__ bet) {
  __shared__ float red[3];
  int row = blockIdx.x;
  int t = threadIdx.x;
  const float4 xv = *(const float4*)&xin[(size_t)row * 768 + t * 4];
  float v[4] = {xv.x, xv.y, xv.z, xv.w};
  float tot = bsum3(v[0] + v[1] + v[2] + v[3], red);
  float mu = tot * (1.f / 768.f);
  float sq = 0.f;
#pragma unroll
  for (int u = 0; u < 4; ++u) { float d = v[u] - mu; sq += d * d; }
  float var = bsum3(sq, red) * (1.f / 768.f);
  float rstd = rsqrtf(var + 1e-5f);
  const float4 g4 = *(const float4*)&gam[t * 4];
  const float4 b4 = *(const float4*)&bet[t * 4];
  union { bf16_t o[4]; uint2 u2; } pk;
  pk.o[0] = (bf16_t)((v[0] - mu) * rstd * g4.x + b4.x);
  pk.o[1] = (bf16_t)((v[1] - mu) * rstd * g4.y + b4.y);
  pk.o[2] = (bf16_t)((v[2] - mu) * rstd * g4.z + b4.z);
  pk.o[3] = (bf16_t)((v[3] - mu) * rstd * g4.w + b4.w);
  *(uint2*)&hout[(size_t)row * 768 + t * 4] = pk.u2;
}

// ---- transpose-convert fp32 [K][N] -> bf16 [N][K], per z-slice ----
__global__ __launch_bounds__(256) void k_convT(
    const float* __restrict__ in, size_t in_slice, bf16_t* __restrict__ out,
    size_t out_slice, int N, int K) {
  __shared__ float tbuf[32][33];
  int slice = blockIdx.z;
  const float* ip = in + (size_t)slice * in_slice;
  bf16_t* op = out + (size_t)slice * out_slice;
  int n0 = blockIdx.x * 32, k0 = blockIdx.y * 32;
  int c = threadIdx.x & 31, r8 = threadIdx.x >> 5;
#pragma unroll
  for (int i = 0; i < 4; ++i) {
    int rr = r8 + i * 8;
    tbuf[rr][c] = ip[(size_t)(k0 + rr) * N + n0 + c];
  }
  __syncthreads();
#pragma unroll
  for (int i = 0; i < 4; ++i) {
    int rr = r8 + i * 8;
    op[(size_t)(n0 + rr) * K + k0 + c] = (bf16_t)tbuf[c][rr];
  }
}

// ---- fused wq/wk/wv transpose-convert, NL layers: z = l*36 + which*12 + head
__global__ __launch_bounds__(256) void k_convT3(
    const float* __restrict__ wq, const float* __restrict__ wk,
    const float* __restrict__ wv, bf16_t* __restrict__ out,
    size_t in_lstride, size_t out_lstride) {
  __shared__ float tbuf[32][33];
  int z = blockIdx.z;
  int l = z / 36, r = z % 36;
  int which = r / 12, head = r % 12;
  const float* ip = (which == 0 ? wq : which == 1 ? wk : wv) +
                    (size_t)l * in_lstride + (size_t)head * 768 * 64;
  bf16_t* op = out + (size_t)l * out_lstride + (size_t)which * 768 * 768 +
               (size_t)head * 64 * 768;
  int n0 = blockIdx.x * 32, k0 = blockIdx.y * 32;   // N=64, K=768
  int c = threadIdx.x & 31, r8 = threadIdx.x >> 5;
#pragma unroll
  for (int i = 0; i < 4; ++i) {
    int rr = r8 + i * 8;
    tbuf[rr][c] = ip[(size_t)(k0 + rr) * 64 + n0 + c];
  }
  __syncthreads();
#pragma unroll
  for (int i = 0; i < 4; ++i) {
    int rr = r8 + i * 8;
    op[(size_t)(n0 + rr) * 768 + k0 + c] = (bf16_t)tbuf[c][rr];
  }
}

// ======================================================================
// 128x128 GEMM (round-10 proven core): BK=64, SINGLE-buffered LDS (32KB ->
// 5 blocks/CU), 2 barriers/K-step, hoisted staging pointers, row&7 XOR
// swizzle (conflict-free), XCD block swizzle. Split-K via blockIdx.y:
// each split covers kseg = K/NS; EPI1 accumulates with atomicAdd and only
// split 0 adds bias.
// EPI 0: store bf16; EPI 1: Cf atomic+= C (+bias); EPI 2: gelu -> bf16
// grid = dim3(gx*gy, NS); gx*gy % 8 == 0; kseg % 64 == 0.
// ======================================================================
template <int EPI>
__global__ __launch_bounds__(256) void k_gemm(
    const bf16_t* __restrict__ A, int lda, const bf16_t* __restrict__ Bt,
    int ldb, int kseg, float* __restrict__ Cf, bf16_t* __restrict__ Cb,
    int ldc, const float* __restrict__ bias, int gx) {
  __shared__ __attribute__((aligned(16))) bf16_t As[128 * 64];
  __shared__ __attribute__((aligned(16))) bf16_t Bs[128 * 64];
  const int nwg = gridDim.x;
  const int bid = blockIdx.x;
  const int sid = blockIdx.y;
  const int koff = sid * kseg;
  const int cpx = nwg >> 3;                 // grid.x % 8 == 0
  const int swz = (bid & 7) * cpx + (bid >> 3);
  const int bx = swz % gx, by = swz / gx;   // consecutive swz share row-panel
  const int m0 = by << 7, n0 = bx << 7;
  const int tid = threadIdx.x;
  const int lane = tid & 63, w = tid >> 6;
  const int wm = w >> 1, wn = w & 1;
  const int r = lane & 15, g4 = lane >> 4;

  f32x4 acc[4][4];
#pragma unroll
  for (int m = 0; m < 4; ++m)
#pragma unroll
    for (int n = 0; n < 4; ++n)
#pragma unroll
      for (int e = 0; e < 4; ++e) acc[m][n][e] = 0.f;

  // hoisted staging pointers: slot s -> row = s>>3, chunk c = (s&7)^(row&7)
  const bf16_t* pa[4];
  const bf16_t* pb[4];
  char* la[4];
  char* lb[4];
#pragma unroll
  for (int u = 0; u < 4; ++u) {
    int s = u * 256 + tid;                  // 16B slot in [128 rows][8 chunks]
    int row = s >> 3;
    int c = (s & 7) ^ (row & 7);
    pa[u] = A + (size_t)(m0 + row) * lda + koff + c * 8;
    pb[u] = Bt + (size_t)(n0 + row) * ldb + koff + c * 8;
    la[u] = (char*)As + (size_t)(u * 256 + (w << 6)) * 16;  // wave-uniform base
    lb[u] = (char*)Bs + (size_t)(u * 256 + (w << 6)) * 16;
  }

  const int NT = kseg >> 6;
  for (int t = 0; t < NT; ++t) {
    const int k0 = t << 6;
#pragma unroll
    for (int u = 0; u < 4; ++u) gload16(pa[u] + k0, la[u]);
#pragma unroll
    for (int u = 0; u < 4; ++u) gload16(pb[u] + k0, lb[u]);
    __syncthreads();                        // tiles ready (vmcnt drained)

#pragma unroll
    for (int kk = 0; kk < 2; ++kk) {
      bf16x8 af[4], bb[4];
#pragma unroll
      for (int m = 0; m < 4; ++m) {
        int row = wm * 64 + m * 16 + r;
        af[m] = *(const bf16x8*)&As[row * 64 +
                                    (((kk << 2) + g4) ^ (row & 7)) * 8];
      }
#pragma unroll
      for (int n = 0; n < 4; ++n) {
        int row = wn * 64 + n * 16 + r;
        bb[n] = *(const bf16x8*)&Bs[row * 64 +
                                    (((kk << 2) + g4) ^ (row & 7)) * 8];
      }
#pragma unroll
      for (int m = 0; m < 4; ++m)
#pragma unroll
        for (int n = 0; n < 4; ++n)
          acc[m][n] = __builtin_amdgcn_mfma_f32_16x16x32_bf16(af[m], bb[n],
                                                              acc[m][n], 0, 0, 0);
    }
    __syncthreads();                        // all reads done before restage
  }

#pragma unroll
  for (int m = 0; m < 4; ++m) {
#pragma unroll
    for (int n = 0; n < 4; ++n) {
      int col = n0 + wn * 64 + n * 16 + r;
      float bv = 0.f;
      if constexpr (EPI != 0) {
        if (sid == 0) bv = bias[col];
      }
#pragma unroll
      for (int j = 0; j < 4; ++j) {
        int row = m0 + wm * 64 + m * 16 + g4 * 4 + j;
        float v = acc[m][n][j];
        if constexpr (EPI == 0) {
          Cb[(size_t)row * ldc + col] = (bf16_t)v;
        } else if constexpr (EPI == 1) {
          unsafeAtomicAdd(&Cf[(size_t)row * ldc + col], v + bv);
        } else {
          float tt = v + bv;
          float ge = 0.5f * tt * (1.f + erff(tt * 0.70710678118f));
          Cb[(size_t)row * ldc + col] = (bf16_t)ge;
        }
      }
    }
  }
}

// ---- lse[b,h,s] = logsumexp_t( q.k/8 ) ; 64 q-rows per block ----
__global__ __launch_bounds__(256) void k_lse(const bf16_t* __restrict__ qkv,
                                             float* __restrict__ lseb) {
  __shared__ __attribute__((aligned(16))) bf16_t Ks[512 * 64];
  __shared__ __attribute__((aligned(16))) bf16_t Qs[64 * 64];
  int bh = blockIdx.x;
  int b = bh / 12, hh = bh % 12;
  int s0 = blockIdx.y * 64;
  int tid = threadIdx.x, lane = tid & 63, w = tid >> 6;
  int r = lane & 15, g4 = lane >> 4;
  const bf16_t* kb = qkv + (size_t)b * 512 * 2304 + 768 + hh * 64;
  const bf16_t* qb = qkv + ((size_t)(b * 512 + s0)) * 2304 + hh * 64;
#pragma unroll
  for (int i = 0; i < 16; ++i) {
    int c = i * 256 + tid;
    gload16(kb + (size_t)(c >> 3) * 2304 + (c & 7) * 8,
            (char*)Ks + (size_t)(i * 256 + (w << 6)) * 16);
  }
#pragma unroll
  for (int i = 0; i < 2; ++i) {
    int c = i * 256 + tid;
    gload16(qb + (size_t)(c >> 3) * 2304 + (c & 7) * 8,
            (char*)Qs + (size_t)(i * 256 + (w << 6)) * 16);
  }
  __syncthreads();

  f32x4 acc[32];
#pragma unroll
  for (int n = 0; n < 32; ++n)
#pragma unroll
    for (int e = 0; e < 4; ++e) acc[n][e] = 0.f;

#pragma unroll
  for (int kk = 0; kk < 2; ++kk) {
    bf16x8 aq = *(const bf16x8*)&Qs[(w * 16 + r) * 64 + kk * 32 + g4 * 8];
#pragma unroll
    for (int n = 0; n < 32; ++n) {
      bf16x8 bk = *(const bf16x8*)&Ks[(n * 16 + r) * 64 + kk * 32 + g4 * 8];
      acc[n] = __builtin_amdgcn_mfma_f32_16x16x32_bf16(aq, bk, acc[n], 0, 0, 0);
    }
  }
#pragma unroll
  for (int j = 0; j < 4; ++j) {
    float mx = -1e30f;
#pragma unroll
    for (int n = 0; n < 32; ++n) mx = fmaxf(mx, acc[n][j] * 0.125f);
#pragma unroll
    for (int o = 1; o < 16; o <<= 1) mx = fmaxf(mx, __shfl_xor(mx, o, 64));
    float sm = 0.f;
#pragma unroll
    for (int n = 0; n < 32; ++n) sm += expf(acc[n][j] * 0.125f - mx);
#pragma unroll
    for (int o = 1; o < 16; o <<= 1) sm += __shfl_xor(sm, o, 64);
    if (r == 0)
      lseb[(size_t)bh * 512 + s0 + w * 16 + g4 * 4 + j] = mx + logf(sm);
  }
}

// ---- fused attn tail: M=K^TV/8 & sumv in LDS, then ctx = qM - lse*sumv ----
__global__ __launch_bounds__(256) void k_attn2(
    const bf16_t* __restrict__ qkv, const float* __restrict__ lseb,
    bf16_t* __restrict__ ctx) {
  __shared__ __attribute__((aligned(16))) char arena[65536];  // Ks+Vs | Qs
  __shared__ __attribute__((aligned(16))) bf16_t Mt[64 * 64];
  __shared__ float svs[64];
  bf16_t* Ks = (bf16_t*)arena;                 // [128][64] bf16 (16KB)
  float* Vs = (float*)(arena + 16384);         // [128][64] f32 (32KB)
  bf16_t* Qs = (bf16_t*)arena;                 // [512][64] bf16 (64KB), phase 2

  int bh = blockIdx.x;
  int b = bh / 12, hh = bh % 12;
  int tid = threadIdx.x, lane = tid & 63, w = tid >> 6;
  const bf16_t* kb = qkv + (size_t)b * 512 * 2304 + 768 + hh * 64;
  const bf16_t* vb = qkv + (size_t)b * 512 * 2304 + 1536 + hh * 64;
  const bf16_t* qb = qkv + (size_t)b * 512 * 2304 + hh * 64;

  // ---- phase 1: M = K^T V / 8 (64x64), sumv ----
  int e1 = lane, grp = w;                      // e1 over K-dim, grp over e2/16
  f32x4 macc[4];
#pragma unroll
  for (int jj = 0; jj < 4; ++jj)
#pragma unroll
    for (int e = 0; e < 4; ++e) macc[jj][e] = 0.f;
  float sv = 0.f;

  for (int t0 = 0; t0 < 512; t0 += 128) {
#pragma unroll
    for (int i = 0; i < 4; ++i) {
      int c = i * 256 + tid;
      gload16(kb + (size_t)(t0 + (c >> 3)) * 2304 + (c & 7) * 8,
              (char*)Ks + (size_t)(i * 256 + (w << 6)) * 16);
    }
#pragma unroll
    for (int i = 0; i < 4; ++i) {
      int c = i * 256 + tid;
      int row = c >> 3, col = (c & 7) * 8;
      bf16x8 raw = *(const bf16x8*)(vb + (size_t)(t0 + row) * 2304 + col);
      f32x4 v0, v1;
#pragma unroll
      for (int u = 0; u < 4; ++u) { v0[u] = (float)raw[u]; v1[u] = (float)raw[u + 4]; }
      *(f32x4*)&Vs[row * 64 + col] = v0;
      *(f32x4*)&Vs[row * 64 + col + 4] = v1;
    }
    __syncthreads();
    for (int tt = 0; tt < 128; ++tt) {
      float kv = (float)Ks[tt * 64 + e1];
#pragma unroll
      for (int jj = 0; jj < 4; ++jj) {
        f32x4 vv = *(const f32x4*)&Vs[tt * 64 + grp * 16 + jj * 4];
        macc[jj] += kv * vv;
      }
    }
    if (tid < 64) {
      for (int tt = 0; tt < 128; ++tt) sv += Vs[tt * 64 + tid];
    }
    __syncthreads();
  }
  // write M^T into LDS as bf16: Mt[e2][e1]
#pragma unroll
  for (int jj = 0; jj < 4; ++jj)
#pragma unroll
    for (int u = 0; u < 4; ++u)
      Mt[(grp * 16 + jj * 4 + u) * 64 + e1] = (bf16_t)(macc[jj][u] * 0.125f);
  if (tid < 64) svs[tid] = sv;
  __syncthreads();                              // arena free, Mt/svs ready

  // ---- phase 2: ctx = q.M - lse*sumv ----
  int r = lane & 15, g4 = lane >> 4;
#pragma unroll
  for (int i = 0; i < 16; ++i) {
    int c = i * 256 + tid;
    gload16(qb + (size_t)(c >> 3) * 2304 + (c & 7) * 8,
            (char*)Qs + (size_t)(i * 256 + (w << 6)) * 16);
  }
  __syncthreads();                              // Qs ready

  f32x4 acc[8][4];
#pragma unroll
  for (int m = 0; m < 8; ++m)
#pragma unroll
    for (int n = 0; n < 4; ++n)
#pragma unroll
      for (int e = 0; e < 4; ++e) acc[m][n][e] = 0.f;

#pragma unroll
  for (int kk = 0; kk < 2; ++kk) {
    bf16x8 bm[4];
#pragma unroll
    for (int n = 0; n < 4; ++n)
      bm[n] = *(const bf16x8*)&Mt[(n * 16 + r) * 64 + kk * 32 + g4 * 8];
#pragma unroll
    for (int m = 0; m < 8; ++m) {
      bf16x8 aq = *(const bf16x8*)&Qs[(w * 128 + m * 16 + r) * 64 + kk * 32 + g4 * 8];
#pragma unroll
      for (int n = 0; n < 4; ++n)
        acc[m][n] = __builtin_amdgcn_mfma_f32_16x16x32_bf16(aq, bm[n], acc[m][n], 0, 0, 0);
    }
  }
#pragma unroll
  for (int m = 0; m < 8; ++m) {
#pragma unroll
    for (int n = 0; n < 4; ++n) {
      int col = n * 16 + r;
      float svv = svs[col];
#pragma unroll
      for (int j = 0; j < 4; ++j) {
        int s = w * 128 + m * 16 + g4 * 4 + j;
        float lv = lseb[(size_t)bh * 512 + s];
        float val = acc[m][n][j] - lv * svv;
        ctx[((size_t)(b * 512 + s)) * 768 + hh * 64 + col] = (bf16_t)val;
      }
    }
  }
}

// ---- final LN (row s=0 per batch) + classifier ----
__global__ __launch_bounds__(192) void k_final(
    const float* __restrict__ x, const float* __restrict__ gam,
    const float* __restrict__ bet, const float* __restrict__ cw,
    const float* __restrict__ cb, float* __restrict__ out) {
  __shared__ float red[3];
  int b = blockIdx.x, t = threadIdx.x;
  const float* xr = x + (size_t)b * 512 * 768;
  const float4 xv = *(const float4*)&xr[t * 4];
  float v[4] = {xv.x, xv.y, xv.z, xv.w};
  float tot = bsum3(v[0] + v[1] + v[2] + v[3], red);
  float mu = tot * (1.f / 768.f);
  float sq = 0.f;
#pragma unroll
  for (int u = 0; u < 4; ++u) { float d = v[u] - mu; sq += d * d; }
  float var = bsum3(sq, red) * (1.f / 768.f);
  float rstd = rsqrtf(var + 1e-5f);
  const float4 g4 = *(const float4*)&gam[t * 4];
  const float4 b4 = *(const float4*)&bet[t * 4];
  float nv[4];
  nv[0] = (v[0] - mu) * rstd * g4.x + b4.x;
  nv[1] = (v[1] - mu) * rstd * g4.y + b4.y;
  nv[2] = (v[2] - mu) * rstd * g4.z + b4.z;
  nv[3] = (v[3] - mu) * rstd * g4.w + b4.w;
  const float4 wa = *(const float4*)&cw[t * 8];
  const float4 wb = *(const float4*)&cw[t * 8 + 4];
  float d0 = nv[0] * wa.x + nv[1] * wa.z + nv[2] * wb.x + nv[3] * wb.z;
  float d1 = nv[0] * wa.y + nv[1] * wa.w + nv[2] * wb.y + nv[3] * wb.w;
  d0 = bsum3(d0, red);
  d1 = bsum3(d1, red);
  if (t == 0) {
    out[b * 2 + 0] = d0 + cb[0];
    out[b * 2 + 1] = d1 + cb[1];
  }
}

// ---- workspace layout ----
static constexpr size_t OFF_X = 0;                                  // f32 8192x768
static constexpr size_t OFF_H = OFF_X + 8192ull * 768 * 4;          // bf16 8192x768
static constexpr size_t OFF_QG = OFF_H + 8192ull * 768 * 2;         // bf16 arena (qkv | gelu)
static constexpr size_t OFF_CTX = OFF_QG + 8192ull * 3072 * 2;      // bf16 8192x768
static constexpr size_t OFF_LSE = OFF_CTX + 8192ull * 768 * 2;      // f32 192*512
static constexpr size_t OFF_W = OFF_LSE + 192ull * 512 * 4;         // bf16 weights
static constexpr size_t WPL = 7077888;                              // elems per layer
static constexpr size_t WS_SMALL = OFF_W + WPL * 2;                 // 1-layer buffer
static constexpr size_t WS_BIG = OFF_W + 12ull * WPL * 2;           // all layers

extern "C" void kernel_launch(void* const* d_in, const int* in_sizes, int n_in,
                              void* d_out, int out_size, void* d_ws,
                              size_t ws_size, hipStream_t stream) {
  const int* ids = (const int*)d_in[0];
  const float* tok = (const float*)d_in[1];
  const float* pos = (const float*)d_in[2];
  const float* eln_s = (const float*)d_in[3];
  const float* eln_b = (const float*)d_in[4];
  const float* wq = (const float*)d_in[5];
  const float* wk = (const float*)d_in[6];
  const float* wv = (const float*)d_in[7];
  const float* wo = (const float*)d_in[8];
  const float* wo_b = (const float*)d_in[9];
  const float* ln1_s = (const float*)d_in[10];
  const float* ln1_b = (const float*)d_in[11];
  const float* ln2_s = (const float*)d_in[12];
  const float* ln2_b = (const float*)d_in[13];
  const float* ff1w = (const float*)d_in[14];
  const float* ff1b = (const float*)d_in[15];
  const float* ff2w = (const float*)d_in[16];
  const float* ff2b = (const float*)d_in[17];
  const float* fln_s = (const float*)d_in[18];
  const float* fln_b = (const float*)d_in[19];
  const float* cw = (const float*)d_in[20];
  const float* cb = (const float*)d_in[21];
  float* out = (float*)d_out;

  if (ws_size < WS_SMALL) return;
  const bool big = ws_size >= WS_BIG;

  char* ws = (char*)d_ws;
  float* x = (float*)(ws + OFF_X);
  bf16_t* h = (bf16_t*)(ws + OFF_H);
  bf16_t* qkv = (bf16_t*)(ws + OFF_QG);
  bf16_t* gbuf = (bf16_t*)(ws + OFF_QG);
  bf16_t* ctx = (bf16_t*)(ws + OFF_CTX);
  float* lseb = (float*)(ws + OFF_LSE);
  bf16_t* wT = (bf16_t*)(ws + OFF_W);

  // embedding + emb-LN + ln1(layer0)
  k_embed<<<8192, 192, 0, stream>>>(ids, tok, pos, eln_s, eln_b,
                                    ln1_s, ln1_b, x, h);

  if (big) {
    // convert ALL layers' weights upfront: 4 launches
    k_convT3<<<dim3(2, 24, 432), 256, 0, stream>>>(wq, wk, wv, wT,
                                                   589824, WPL);
    k_convT<<<dim3(24, 24, 12), 256, 0, stream>>>(wo, 589824,
                                                  wT + 1769472, WPL, 768, 768);
    k_convT<<<dim3(96, 24, 12), 256, 0, stream>>>(ff1w, 2359296,
                                                  wT + 2359296, WPL, 3072, 768);
    k_convT<<<dim3(24, 96, 12), 256, 0, stream>>>(ff2w, 2359296,
                                                  wT + 4718592, WPL, 768, 3072);
  }

  for (int l = 0; l < 12; ++l) {
    bf16_t* wl = big ? wT + (size_t)l * WPL : wT;
    bf16_t* qkvT = wl;
    bf16_t* woT = wl + 1769472;
    bf16_t* ff1T = wl + 2359296;
    bf16_t* ff2T = wl + 4718592;

    if (l > 0)
      k_ln<<<8192, 192, 0, stream>>>(x, h, ln1_s + l * 768, ln1_b + l * 768);
    if (!big) {
      k_convT3<<<dim3(2, 24, 36), 256, 0, stream>>>(
          wq + (size_t)l * 589824, wk + (size_t)l * 589824,
          wv + (size_t)l * 589824, qkvT, 589824, 0);
      k_convT<<<dim3(24, 24, 1), 256, 0, stream>>>(wo + (size_t)l * 589824, 0,
                                                   woT, 0, 768, 768);
      k_convT<<<dim3(96, 24, 1), 256, 0, stream>>>(ff1w + (size_t)l * 2359296,
                                                   0, ff1T, 0, 3072, 768);
      k_convT<<<dim3(24, 96, 1), 256, 0, stream>>>(ff2w + (size_t)l * 2359296,
                                                   0, ff2T, 0, 768, 3072);
    }
    // QKV: M=8192 N=2304 K=768 -> grid 18*64=1152, no split
    k_gemm<0><<<dim3(1152, 1), 256, 0, stream>>>(h, 768, qkvT, 768, 768,
                                                 nullptr, qkv, 2304, nullptr,
                                                 18);
    // attention (log-softmax decomposition)
    k_lse<<<dim3(192, 8), 256, 0, stream>>>(qkv, lseb);
    k_attn2<<<192, 256, 0, stream>>>(qkv, lseb, ctx);
    // WO + residual: split-K=2 -> grid (384,2), kseg=384
    k_gemm<1><<<dim3(384, 2), 256, 0, stream>>>(ctx, 768, woT, 768, 384, x,
                                                nullptr, 768, wo_b + l * 768,
                                                6);
    // FFN
    k_ln<<<8192, 192, 0, stream>>>(x, h, ln2_s + l * 768, ln2_b + l * 768);
    // FF1: grid 24*64=1536, no split (GELU epilogue)
    k_gemm<2><<<dim3(1536, 1), 256, 0, stream>>>(h, 768, ff1T, 768, 768,
                                                 nullptr, gbuf, 3072,
                                                 ff1b + l * 3072, 24);
    // FF2: split-K=2 -> grid (384,2), kseg=1536
    k_gemm<1><<<dim3(384, 2), 256, 0, stream>>>(gbuf, 3072, ff2T, 3072, 1536,
                                                x, nullptr, 768,
                                                ff2b + l * 768, 6);
  }
  k_final<<<16, 192, 0, stream>>>(x, fln_s, fln_b, cw, cb, out);
}

// Round 13
// 4074.571 us; speedup vs baseline: 1.0485x; 1.0485x over previous
//
#include <hip/hip_runtime.h>
#include <hip/hip_bf16.h>
#include <math.h>

// Dims: B=16 S=512 D=768 H=12 DH=64 F=3072 LYR=12 NLAB=2; rows = B*S = 8192
typedef __bf16 bf16_t;
typedef __attribute__((ext_vector_type(8))) __bf16 bf16x8;
typedef __attribute__((ext_vector_type(4))) float f32x4;

typedef const __attribute__((address_space(1))) void av1_void;
typedef __attribute__((address_space(3))) void av3_void;

#define DEV static __device__ __forceinline__

DEV void gload16(const void* g, void* l) {
  __builtin_amdgcn_global_load_lds((av1_void*)g, (av3_void*)l, 16, 0, 0);
}

// ---- block reduction over 3 waves (block=192) ----
DEV float bsum3(float v, float* red) {
#pragma unroll
  for (int o = 32; o > 0; o >>= 1) v += __shfl_xor(v, o, 64);
  __syncthreads();
  if ((threadIdx.x & 63) == 0) red[threadIdx.x >> 6] = v;
  __syncthreads();
  return red[0] + red[1] + red[2];
}

// ---- embedding gather + emb-LN -> x (fp32), then ln1(layer0) -> h (bf16) ----
__global__ __launch_bounds__(192) void k_embed(
    const int* __restrict__ ids, const float* __restrict__ tok,
    const float* __restrict__ pos, const float* __restrict__ gam,
    const float* __restrict__ bet, const float* __restrict__ gam2,
    const float* __restrict__ bet2, float* __restrict__ x,
    bf16_t* __restrict__ h) {
  __shared__ float red[3];
  int row = blockIdx.x;          // b*512 + s
  int s = row & 511;
  int t = threadIdx.x;
  int id = ids[row];
  const float4 tv = *(const float4*)&tok[(size_t)id * 768 + t * 4];
  const float4 pv = *(const float4*)&pos[(size_t)s * 768 + t * 4];
  float v[4] = {tv.x + pv.x, tv.y + pv.y, tv.z + pv.z, tv.w + pv.w};
  float tot = bsum3(v[0] + v[1] + v[2] + v[3], red);
  float mu = tot * (1.f / 768.f);
  float sq = 0.f;
#pragma unroll
  for (int u = 0; u < 4; ++u) { float d = v[u] - mu; sq += d * d; }
  float var = bsum3(sq, red) * (1.f / 768.f);
  float rstd = rsqrtf(var + 1e-5f);
  const float4 g4 = *(const float4*)&gam[t * 4];
  const float4 b4 = *(const float4*)&bet[t * 4];
  float o[4];
  o[0] = (v[0] - mu) * rstd * g4.x + b4.x;
  o[1] = (v[1] - mu) * rstd * g4.y + b4.y;
  o[2] = (v[2] - mu) * rstd * g4.z + b4.z;
  o[3] = (v[3] - mu) * rstd * g4.w + b4.w;
  float4 ov = {o[0], o[1], o[2], o[3]};
  *(float4*)&x[(size_t)row * 768 + t * 4] = ov;
  // second LN (ln1 of layer 0) -> h
  float tot2 = bsum3(o[0] + o[1] + o[2] + o[3], red);
  float mu2 = tot2 * (1.f / 768.f);
  float sq2 = 0.f;
#pragma unroll
  for (int u = 0; u < 4; ++u) { float d = o[u] - mu2; sq2 += d * d; }
  float var2 = bsum3(sq2, red) * (1.f / 768.f);
  float rstd2 = rsqrtf(var2 + 1e-5f);
  const float4 G = *(const float4*)&gam2[t * 4];
  const float4 Bb = *(const float4*)&bet2[t * 4];
  union { bf16_t ob[4]; uint2 u2; } pk;
  pk.ob[0] = (bf16_t)((o[0] - mu2) * rstd2 * G.x + Bb.x);
  pk.ob[1] = (bf16_t)((o[1] - mu2) * rstd2 * G.y + Bb.y);
  pk.ob[2] = (bf16_t)((o[2] - mu2) * rstd2 * G.z + Bb.z);
  pk.ob[3] = (bf16_t)((o[3] - mu2) * rstd2 * G.w + Bb.w);
  *(uint2*)&h[(size_t)row * 768 + t * 4] = pk.u2;
}

// ---- LN: x (fp32) -> h (bf16); wave-per-row, lane owns 12 cols ----
__global__ __launch_bounds__(256) void k_ln(
    const float* __restrict__ xin, bf16_t* __restrict__ hout,
    const float* __restrict__ gam, const float* __restrict__ bet) {
  int row = blockIdx.x * 4 + (threadIdx.x >> 6);
  int lane = threadIdx.x & 63;
  const float* xr = xin + (size_t)row * 768 + lane * 12;
  float4 a = *(const float4*)&xr[0];
  float4 b = *(const float4*)&xr[4];
  float4 c = *(const float4*)&xr[8];
  float v[12] = {a.x, a.y, a.z, a.w, b.x, b.y, b.z, b.w, c.x, c.y, c.z, c.w};
  float sm = 0.f;
#pragma unroll
  for (int u = 0; u < 12; ++u) sm += v[u];
#pragma unroll
  for (int o = 32; o > 0; o >>= 1) sm += __shfl_xor(sm, o, 64);
  float mu = sm * (1.f / 768.f);
  float sq = 0.f;
#pragma unroll
  for (int u = 0; u < 12; ++u) { float d = v[u] - mu; sq += d * d; }
#pragma unroll
  for (int o = 32; o > 0; o >>= 1) sq += __shfl_xor(sq, o, 64);
  float rstd = rsqrtf(sq * (1.f / 768.f) + 1e-5f);
  const float4 ga = *(const float4*)&gam[lane * 12];
  const float4 gb = *(const float4*)&gam[lane * 12 + 4];
  const float4 gc = *(const float4*)&gam[lane * 12 + 8];
  const float4 ba = *(const float4*)&bet[lane * 12];
  const float4 bb = *(const float4*)&bet[lane * 12 + 4];
  const float4 bc = *(const float4*)&bet[lane * 12 + 8];
  float g[12] = {ga.x, ga.y, ga.z, ga.w, gb.x, gb.y, gb.z, gb.w,
                 gc.x, gc.y, gc.z, gc.w};
  float be[12] = {ba.x, ba.y, ba.z, ba.w, bb.x, bb.y, bb.z, bb.w,
                  bc.x, bc.y, bc.z, bc.w};
  union { bf16_t o[12]; uint2 u2[3]; } pk;
#pragma unroll
  for (int u = 0; u < 12; ++u)
    pk.o[u] = (bf16_t)((v[u] - mu) * rstd * g[u] + be[u]);
  bf16_t* hr = hout + (size_t)row * 768 + lane * 12;
#pragma unroll
  for (int u = 0; u < 3; ++u) *(uint2*)&hr[u * 4] = pk.u2[u];
}

// ---- transpose-convert fp32 [K][N] -> bf16 [N][K], per z-slice ----
__global__ __launch_bounds__(256) void k_convT(
    const float* __restrict__ in, size_t in_slice, bf16_t* __restrict__ out,
    size_t out_slice, int N, int K) {
  __shared__ float tbuf[32][33];
  int slice = blockIdx.z;
  const float* ip = in + (size_t)slice * in_slice;
  bf16_t* op = out + (size_t)slice * out_slice;
  int n0 = blockIdx.x * 32, k0 = blockIdx.y * 32;
  int c = threadIdx.x & 31, r8 = threadIdx.x >> 5;
#pragma unroll
  for (int i = 0; i < 4; ++i) {
    int rr = r8 + i * 8;
    tbuf[rr][c] = ip[(size_t)(k0 + rr) * N + n0 + c];
  }
  __syncthreads();
#pragma unroll
  for (int i = 0; i < 4; ++i) {
    int rr = r8 + i * 8;
    op[(size_t)(n0 + rr) * K + k0 + c] = (bf16_t)tbuf[c][rr];
  }
}

// ---- fused wq/wk/wv transpose-convert, NL layers: z = l*36 + which*12 + head
__global__ __launch_bounds__(256) void k_convT3(
    const float* __restrict__ wq, const float* __restrict__ wk,
    const float* __restrict__ wv, bf16_t* __restrict__ out,
    size_t in_lstride, size_t out_lstride) {
  __shared__ float tbuf[32][33];
  int z = blockIdx.z;
  int l = z / 36, r = z % 36;
  int which = r / 12, head = r % 12;
  const float* ip = (which == 0 ? wq : which == 1 ? wk : wv) +
                    (size_t)l * in_lstride + (size_t)head * 768 * 64;
  bf16_t* op = out + (size_t)l * out_lstride + (size_t)which * 768 * 768 +
               (size_t)head * 64 * 768;
  int n0 = blockIdx.x * 32, k0 = blockIdx.y * 32;   // N=64, K=768
  int c = threadIdx.x & 31, r8 = threadIdx.x >> 5;
#pragma unroll
  for (int i = 0; i < 4; ++i) {
    int rr = r8 + i * 8;
    tbuf[rr][c] = ip[(size_t)(k0 + rr) * 64 + n0 + c];
  }
  __syncthreads();
#pragma unroll
  for (int i = 0; i < 4; ++i) {
    int rr = r8 + i * 8;
    op[(size_t)(n0 + rr) * 768 + k0 + c] = (bf16_t)tbuf[c][rr];
  }
}

// ======================================================================
// k_gemm1 (round-10 core): BK=64, SINGLE-buffered LDS (32KB -> 5
// blocks/CU). Best for LARGE grids (QKV, FF1): cross-block overlap.
// EPI 0: store bf16; EPI 2: gelu(C+bias) -> bf16
// ======================================================================
template <int EPI>
__global__ __launch_bounds__(256) void k_gemm1(
    const bf16_t* __restrict__ A, int lda, const bf16_t* __restrict__ Bt,
    int ldb, int K, float* __restrict__ Cf, bf16_t* __restrict__ Cb, int ldc,
    const float* __restrict__ bias, int gx) {
  __shared__ __attribute__((aligned(16))) bf16_t As[128 * 64];
  __shared__ __attribute__((aligned(16))) bf16_t Bs[128 * 64];
  const int nwg = gridDim.x;
  const int bid = blockIdx.x;
  const int cpx = nwg >> 3;
  const int swz = (bid & 7) * cpx + (bid >> 3);
  const int bx = swz % gx, by = swz / gx;
  const int m0 = by << 7, n0 = bx << 7;
  const int tid = threadIdx.x;
  const int lane = tid & 63, w = tid >> 6;
  const int wm = w >> 1, wn = w & 1;
  const int r = lane & 15, g4 = lane >> 4;

  f32x4 acc[4][4];
#pragma unroll
  for (int m = 0; m < 4; ++m)
#pragma unroll
    for (int n = 0; n < 4; ++n)
#pragma unroll
      for (int e = 0; e < 4; ++e) acc[m][n][e] = 0.f;

  const bf16_t* pa[4];
  const bf16_t* pb[4];
  char* la[4];
  char* lb[4];
#pragma unroll
  for (int u = 0; u < 4; ++u) {
    int s = u * 256 + tid;                  // 16B slot in [128 rows][8 chunks]
    int row = s >> 3;
    int c = (s & 7) ^ (row & 7);
    pa[u] = A + (size_t)(m0 + row) * lda + c * 8;
    pb[u] = Bt + (size_t)(n0 + row) * ldb + c * 8;
    la[u] = (char*)As + (size_t)(u * 256 + (w << 6)) * 16;
    lb[u] = (char*)Bs + (size_t)(u * 256 + (w << 6)) * 16;
  }

  const int NT = K >> 6;
  for (int t = 0; t < NT; ++t) {
    const int k0 = t << 6;
#pragma unroll
    for (int u = 0; u < 4; ++u) gload16(pa[u] + k0, la[u]);
#pragma unroll
    for (int u = 0; u < 4; ++u) gload16(pb[u] + k0, lb[u]);
    __syncthreads();

#pragma unroll
    for (int kk = 0; kk < 2; ++kk) {
      bf16x8 af[4], bb[4];
#pragma unroll
      for (int m = 0; m < 4; ++m) {
        int row = wm * 64 + m * 16 + r;
        af[m] = *(const bf16x8*)&As[row * 64 +
                                    (((kk << 2) + g4) ^ (row & 7)) * 8];
      }
#pragma unroll
      for (int n = 0; n < 4; ++n) {
        int row = wn * 64 + n * 16 + r;
        bb[n] = *(const bf16x8*)&Bs[row * 64 +
                                    (((kk << 2) + g4) ^ (row & 7)) * 8];
      }
#pragma unroll
      for (int m = 0; m < 4; ++m)
#pragma unroll
        for (int n = 0; n < 4; ++n)
          acc[m][n] = __builtin_amdgcn_mfma_f32_16x16x32_bf16(af[m], bb[n],
                                                              acc[m][n], 0, 0, 0);
    }
    __syncthreads();
  }

#pragma unroll
  for (int m = 0; m < 4; ++m) {
#pragma unroll
    for (int n = 0; n < 4; ++n) {
      int col = n0 + wn * 64 + n * 16 + r;
      float bv = 0.f;
      if constexpr (EPI != 0) bv = bias[col];
#pragma unroll
      for (int j = 0; j < 4; ++j) {
        int row = m0 + wm * 64 + m * 16 + g4 * 4 + j;
        float v = acc[m][n][j];
        if constexpr (EPI == 0) {
          Cb[(size_t)row * ldc + col] = (bf16_t)v;
        } else if constexpr (EPI == 1) {
          size_t o = (size_t)row * ldc + col;
          Cf[o] += v + bv;
        } else {
          float tt = v + bv;
          float ge = 0.5f * tt * (1.f + erff(tt * 0.70710678118f));
          Cb[(size_t)row * ldc + col] = (bf16_t)ge;
        }
      }
    }
  }
}

// ======================================================================
// k_gemm3 (round-11 core): BK=32, THREE-buffer LDS, counted vmcnt(4),
// loads in flight across barriers. Best for SMALL grids (WO, FF2):
// fill-starved, needs in-block pipelining.
// EPI 1: Cf += C + bias (fp32 residual)
// ======================================================================
template <int EPI>
__global__ __launch_bounds__(256) void k_gemm3(
    const bf16_t* __restrict__ A, int lda, const bf16_t* __restrict__ Bt,
    int ldb, int K, float* __restrict__ Cf, bf16_t* __restrict__ Cb, int ldc,
    const float* __restrict__ bias, int gx) {
  __shared__ __attribute__((aligned(16))) bf16_t As[3][128 * 32];
  __shared__ __attribute__((aligned(16))) bf16_t Bs[3][128 * 32];
  const int nwg = gridDim.x;
  const int bid = blockIdx.x;
  const int cpx = nwg >> 3;
  const int swz = (bid & 7) * cpx + (bid >> 3);
  const int bx = swz % gx, by = swz / gx;
  const int m0 = by << 7, n0 = bx << 7;
  const int tid = threadIdx.x;
  const int lane = tid & 63, w = tid >> 6;
  const int wm = w >> 1, wn = w & 1;
  const int r = lane & 15, g4 = lane >> 4;

  f32x4 acc[4][4];
#pragma unroll
  for (int m = 0; m < 4; ++m)
#pragma unroll
    for (int n = 0; n < 4; ++n)
#pragma unroll
      for (int e = 0; e < 4; ++e) acc[m][n][e] = 0.f;

  const bf16_t* pa[2];
  const bf16_t* pb[2];
  uint32_t lo[2];
#pragma unroll
  for (int u = 0; u < 2; ++u) {
    int s = u * 256 + tid;                  // 16B slot in [128 rows][4 chunks]
    int row = s >> 2;
    int c = (s & 3) ^ ((row >> 1) & 3);
    pa[u] = A + (size_t)(m0 + row) * lda + c * 8;
    pb[u] = Bt + (size_t)(n0 + row) * ldb + c * 8;
    lo[u] = (uint32_t)(u * 256 + (w << 6)) * 16;
  }

  const int NT = K >> 5;
  auto STAGE = [&](int t, int bufi) {
    int k0 = (t < NT ? t : NT - 1) << 5;    // clamped dummy tail stage
#pragma unroll
    for (int u = 0; u < 2; ++u) gload16(pa[u] + k0, (char*)&As[bufi][0] + lo[u]);
#pragma unroll
    for (int u = 0; u < 2; ++u) gload16(pb[u] + k0, (char*)&Bs[bufi][0] + lo[u]);
  };

  STAGE(0, 0);
  STAGE(1, 1);
  int bi = 0, si = 2;
  const int co = (g4 ^ ((r >> 1) & 3)) << 3;
  for (int t = 0; t < NT; ++t) {
    asm volatile("s_waitcnt vmcnt(4)" ::: "memory");
    asm volatile("s_barrier" ::: "memory");
    bf16x8 af[4], bb[4];
#pragma unroll
    for (int m = 0; m < 4; ++m) {
      int row = wm * 64 + m * 16 + r;
      af[m] = *(const bf16x8*)&As[bi][row * 32 + co];
    }
#pragma unroll
    for (int n = 0; n < 4; ++n) {
      int row = wn * 64 + n * 16 + r;
      bb[n] = *(const bf16x8*)&Bs[bi][row * 32 + co];
    }
#pragma unroll
    for (int m = 0; m < 4; ++m)
#pragma unroll
      for (int n = 0; n < 4; ++n)
        acc[m][n] = __builtin_amdgcn_mfma_f32_16x16x32_bf16(af[m], bb[n],
                                                            acc[m][n], 0, 0, 0);
    asm volatile("s_barrier" ::: "memory");
    STAGE(t + 2, si);
    si = bi;
    bi = (bi == 2) ? 0 : bi + 1;
  }
  asm volatile("s_waitcnt vmcnt(0)" ::: "memory");

#pragma unroll
  for (int m = 0; m < 4; ++m) {
#pragma unroll
    for (int n = 0; n < 4; ++n) {
      int col = n0 + wn * 64 + n * 16 + r;
      float bv = 0.f;
      if constexpr (EPI != 0) bv = bias[col];
#pragma unroll
      for (int j = 0; j < 4; ++j) {
        int row = m0 + wm * 64 + m * 16 + g4 * 4 + j;
        float v = acc[m][n][j];
        if constexpr (EPI == 0) {
          Cb[(size_t)row * ldc + col] = (bf16_t)v;
        } else if constexpr (EPI == 1) {
          size_t o = (size_t)row * ldc + col;
          Cf[o] += v + bv;
        } else {
          float tt = v + bv;
          float ge = 0.5f * tt * (1.f + erff(tt * 0.70710678118f));
          Cb[(size_t)row * ldc + col] = (bf16_t)ge;
        }
      }
    }
  }
}

// ---- lse[b,h,s] = logsumexp_t( q.k/8 ) ; 64 q-rows per block ----
__global__ __launch_bounds__(256) void k_lse(const bf16_t* __restrict__ qkv,
                                             float* __restrict__ lseb) {
  __shared__ __attribute__((aligned(16))) bf16_t Ks[512 * 64];
  __shared__ __attribute__((aligned(16))) bf16_t Qs[64 * 64];
  int bh = blockIdx.x;
  int b = bh / 12, hh = bh % 12;
  int s0 = blockIdx.y * 64;
  int tid = threadIdx.x, lane = tid & 63, w = tid >> 6;
  int r = lane & 15, g4 = lane >> 4;
  const bf16_t* kb = qkv + (size_t)b * 512 * 2304 + 768 + hh * 64;
  const bf16_t* qb = qkv + ((size_t)(b * 512 + s0)) * 2304 + hh * 64;
#pragma unroll
  for (int i = 0; i < 16; ++i) {
    int c = i * 256 + tid;
    gload16(kb + (size_t)(c >> 3) * 2304 + (c & 7) * 8,
            (char*)Ks + (size_t)(i * 256 + (w << 6)) * 16);
  }
#pragma unroll
  for (int i = 0; i < 2; ++i) {
    int c = i * 256 + tid;
    gload16(qb + (size_t)(c >> 3) * 2304 + (c & 7) * 8,
            (char*)Qs + (size_t)(i * 256 + (w << 6)) * 16);
  }
  __syncthreads();

  f32x4 acc[32];
#pragma unroll
  for (int n = 0; n < 32; ++n)
#pragma unroll
    for (int e = 0; e < 4; ++e) acc[n][e] = 0.f;

#pragma unroll
  for (int kk = 0; kk < 2; ++kk) {
    bf16x8 aq = *(const bf16x8*)&Qs[(w * 16 + r) * 64 + kk * 32 + g4 * 8];
#pragma unroll
    for (int n = 0; n < 32; ++n) {
      bf16x8 bk = *(const bf16x8*)&Ks[(n * 16 + r) * 64 + kk * 32 + g4 * 8];
      acc[n] = __builtin_amdgcn_mfma_f32_16x16x32_bf16(aq, bk, acc[n], 0, 0, 0);
    }
  }
#pragma unroll
  for (int j = 0; j < 4; ++j) {
    float mx = -1e30f;
#pragma unroll
    for (int n = 0; n < 32; ++n) mx = fmaxf(mx, acc[n][j] * 0.125f);
#pragma unroll
    for (int o = 1; o < 16; o <<= 1) mx = fmaxf(mx, __shfl_xor(mx, o, 64));
    float sm = 0.f;
#pragma unroll
    for (int n = 0; n < 32; ++n) sm += expf(acc[n][j] * 0.125f - mx);
#pragma unroll
    for (int o = 1; o < 16; o <<= 1) sm += __shfl_xor(sm, o, 64);
    if (r == 0)
      lseb[(size_t)bh * 512 + s0 + w * 16 + g4 * 4 + j] = mx + logf(sm);
  }
}

// ---- fused attn tail: M=K^TV/8 & sumv in LDS, then ctx = qM - lse*sumv ----
__global__ __launch_bounds__(256) void k_attn2(
    const bf16_t* __restrict__ qkv, const float* __restrict__ lseb,
    bf16_t* __restrict__ ctx) {
  __shared__ __attribute__((aligned(16))) char arena[65536];  // Ks+Vs | Qs
  __shared__ __attribute__((aligned(16))) bf16_t Mt[64 * 64];
  __shared__ float svs[64];
  bf16_t* Ks = (bf16_t*)arena;                 // [128][64] bf16 (16KB)
  float* Vs = (float*)(arena + 16384);         // [128][64] f32 (32KB)
  bf16_t* Qs = (bf16_t*)arena;                 // [512][64] bf16 (64KB), phase 2

  int bh = blockIdx.x;
  int b = bh / 12, hh = bh % 12;
  int tid = threadIdx.x, lane = tid & 63, w = tid >> 6;
  const bf16_t* kb = qkv + (size_t)b * 512 * 2304 + 768 + hh * 64;
  const bf16_t* vb = qkv + (size_t)b * 512 * 2304 + 1536 + hh * 64;
  const bf16_t* qb = qkv + (size_t)b * 512 * 2304 + hh * 64;

  // ---- phase 1: M = K^T V / 8 (64x64), sumv ----
  int e1 = lane, grp = w;                      // e1 over K-dim, grp over e2/16
  f32x4 macc[4];
#pragma unroll
  for (int jj = 0; jj < 4; ++jj)
#pragma unroll
    for (int e = 0; e < 4; ++e) macc[jj][e] = 0.f;
  float sv = 0.f;

  for (int t0 = 0; t0 < 512; t0 += 128) {
#pragma unroll
    for (int i = 0; i < 4; ++i) {
      int c = i * 256 + tid;
      gload16(kb + (size_t)(t0 + (c >> 3)) * 2304 + (c & 7) * 8,
              (char*)Ks + (size_t)(i * 256 + (w << 6)) * 16);
    }
#pragma unroll
    for (int i = 0; i < 4; ++i) {
      int c = i * 256 + tid;
      int row = c >> 3, col = (c & 7) * 8;
      bf16x8 raw = *(const bf16x8*)(vb + (size_t)(t0 + row) * 2304 + col);
      f32x4 v0, v1;
#pragma unroll
      for (int u = 0; u < 4; ++u) { v0[u] = (float)raw[u]; v1[u] = (float)raw[u + 4]; }
      *(f32x4*)&Vs[row * 64 + col] = v0;
      *(f32x4*)&Vs[row * 64 + col + 4] = v1;
    }
    __syncthreads();
    for (int tt = 0; tt < 128; ++tt) {
      float kv = (float)Ks[tt * 64 + e1];
#pragma unroll
      for (int jj = 0; jj < 4; ++jj) {
        f32x4 vv = *(const f32x4*)&Vs[tt * 64 + grp * 16 + jj * 4];
        macc[jj] += kv * vv;
      }
    }
    if (tid < 64) {
      for (int tt = 0; tt < 128; ++tt) sv += Vs[tt * 64 + tid];
    }
    __syncthreads();
  }
  // write M^T into LDS as bf16: Mt[e2][e1]
#pragma unroll
  for (int jj = 0; jj < 4; ++jj)
#pragma unroll
    for (int u = 0; u < 4; ++u)
      Mt[(grp * 16 + jj * 4 + u) * 64 + e1] = (bf16_t)(macc[jj][u] * 0.125f);
  if (tid < 64) svs[tid] = sv;
  __syncthreads();                              // arena free, Mt/svs ready

  // ---- phase 2: ctx = q.M - lse*sumv ----
  int r = lane & 15, g4 = lane >> 4;
#pragma unroll
  for (int i = 0; i < 16; ++i) {
    int c = i * 256 + tid;
    gload16(qb + (size_t)(c >> 3) * 2304 + (c & 7) * 8,
            (char*)Qs + (size_t)(i * 256 + (w << 6)) * 16);
  }
  __syncthreads();                              // Qs ready

  f32x4 acc[8][4];
#pragma unroll
  for (int m = 0; m < 8; ++m)
#pragma unroll
    for (int n = 0; n < 4; ++n)
#pragma unroll
      for (int e = 0; e < 4; ++e) acc[m][n][e] = 0.f;

#pragma unroll
  for (int kk = 0; kk < 2; ++kk) {
    bf16x8 bm[4];
#pragma unroll
    for (int n = 0; n < 4; ++n)
      bm[n] = *(const bf16x8*)&Mt[(n * 16 + r) * 64 + kk * 32 + g4 * 8];
#pragma unroll
    for (int m = 0; m < 8; ++m) {
      bf16x8 aq = *(const bf16x8*)&Qs[(w * 128 + m * 16 + r) * 64 + kk * 32 + g4 * 8];
#pragma unroll
      for (int n = 0; n < 4; ++n)
        acc[m][n] = __builtin_amdgcn_mfma_f32_16x16x32_bf16(aq, bm[n], acc[m][n], 0, 0, 0);
    }
  }
#pragma unroll
  for (int m = 0; m < 8; ++m) {
#pragma unroll
    for (int n = 0; n < 4; ++n) {
      int col = n * 16 + r;
      float svv = svs[col];
#pragma unroll
      for (int j = 0; j < 4; ++j) {
        int s = w * 128 + m * 16 + g4 * 4 + j;
        float lv = lseb[(size_t)bh * 512 + s];
        float val = acc[m][n][j] - lv * svv;
        ctx[((size_t)(b * 512 + s)) * 768 + hh * 64 + col] = (bf16_t)val;
      }
    }
  }
}

// ---- final LN (row s=0 per batch) + classifier ----
__global__ __launch_bounds__(192) void k_final(
    const float* __restrict__ x, const float* __restrict__ gam,
    const float* __restrict__ bet, const float* __restrict__ cw,
    const float* __restrict__ cb, float* __restrict__ out) {
  __shared__ float red[3];
  int b = blockIdx.x, t = threadIdx.x;
  const float* xr = x + (size_t)b * 512 * 768;
  const float4 xv = *(const float4*)&xr[t * 4];
  float v[4] = {xv.x, xv.y, xv.z, xv.w};
  float tot = bsum3(v[0] + v[1] + v[2] + v[3], red);
  float mu = tot * (1.f / 768.f);
  float sq = 0.f;
#pragma unroll
  for (int u = 0; u < 4; ++u) { float d = v[u] - mu; sq += d * d; }
  float var = bsum3(sq, red) * (1.f / 768.f);
  float rstd = rsqrtf(var + 1e-5f);
  const float4 g4 = *(const float4*)&gam[t * 4];
  const float4 b4 = *(const float4*)&bet[t * 4];
  float nv[4];
  nv[0] = (v[0] - mu) * rstd * g4.x + b4.x;
  nv[1] = (v[1] - mu) * rstd * g4.y + b4.y;
  nv[2] = (v[2] - mu) * rstd * g4.z + b4.z;
  nv[3] = (v[3] - mu) * rstd * g4.w + b4.w;
  const float4 wa = *(const float4*)&cw[t * 8];
  const float4 wb = *(const float4*)&cw[t * 8 + 4];
  float d0 = nv[0] * wa.x + nv[1] * wa.z + nv[2] * wb.x + nv[3] * wb.z;
  float d1 = nv[0] * wa.y + nv[1] * wa.w + nv[2] * wb.y + nv[3] * wb.w;
  d0 = bsum3(d0, red);
  d1 = bsum3(d1, red);
  if (t == 0) {
    out[b * 2 + 0] = d0 + cb[0];
    out[b * 2 + 1] = d1 + cb[1];
  }
}

// ---- workspace layout ----
static constexpr size_t OFF_X = 0;                                  // f32 8192x768
static constexpr size_t OFF_H = OFF_X + 8192ull * 768 * 4;          // bf16 8192x768
static constexpr size_t OFF_QG = OFF_H + 8192ull * 768 * 2;         // bf16 arena (qkv | gelu)
static constexpr size_t OFF_CTX = OFF_QG + 8192ull * 3072 * 2;      // bf16 8192x768
static constexpr size_t OFF_LSE = OFF_CTX + 8192ull * 768 * 2;      // f32 192*512
static constexpr size_t OFF_W = OFF_LSE + 192ull * 512 * 4;         // bf16 weights
static constexpr size_t WPL = 7077888;                              // elems per layer
static constexpr size_t WS_SMALL = OFF_W + WPL * 2;                 // 1-layer buffer
static constexpr size_t WS_BIG = OFF_W + 12ull * WPL * 2;           // all layers

extern "C" void kernel_launch(void* const* d_in, const int* in_sizes, int n_in,
                              void* d_out, int out_size, void* d_ws,
                              size_t ws_size, hipStream_t stream) {
  const int* ids = (const int*)d_in[0];
  const float* tok = (const float*)d_in[1];
  const float* pos = (const float*)d_in[2];
  const float* eln_s = (const float*)d_in[3];
  const float* eln_b = (const float*)d_in[4];
  const float* wq = (const float*)d_in[5];
  const float* wk = (const float*)d_in[6];
  const float* wv = (const float*)d_in[7];
  const float* wo = (const float*)d_in[8];
  const float* wo_b = (const float*)d_in[9];
  const float* ln1_s = (const float*)d_in[10];
  const float* ln1_b = (const float*)d_in[11];
  const float* ln2_s = (const float*)d_in[12];
  const float* ln2_b = (const float*)d_in[13];
  const float* ff1w = (const float*)d_in[14];
  const float* ff1b = (const float*)d_in[15];
  const float* ff2w = (const float*)d_in[16];
  const float* ff2b = (const float*)d_in[17];
  const float* fln_s = (const float*)d_in[18];
  const float* fln_b = (const float*)d_in[19];
  const float* cw = (const float*)d_in[20];
  const float* cb = (const float*)d_in[21];
  float* out = (float*)d_out;

  if (ws_size < WS_SMALL) return;
  const bool big = ws_size >= WS_BIG;

  char* ws = (char*)d_ws;
  float* x = (float*)(ws + OFF_X);
  bf16_t* h = (bf16_t*)(ws + OFF_H);
  bf16_t* qkv = (bf16_t*)(ws + OFF_QG);
  bf16_t* gbuf = (bf16_t*)(ws + OFF_QG);
  bf16_t* ctx = (bf16_t*)(ws + OFF_CTX);
  float* lseb = (float*)(ws + OFF_LSE);
  bf16_t* wT = (bf16_t*)(ws + OFF_W);

  // embedding + emb-LN + ln1(layer0)
  k_embed<<<8192, 192, 0, stream>>>(ids, tok, pos, eln_s, eln_b,
                                    ln1_s, ln1_b, x, h);

  if (big) {
    // convert ALL layers' weights upfront: 4 launches
    k_convT3<<<dim3(2, 24, 432), 256, 0, stream>>>(wq, wk, wv, wT,
                                                   589824, WPL);
    k_convT<<<dim3(24, 24, 12), 256, 0, stream>>>(wo, 589824,
                                                  wT + 1769472, WPL, 768, 768);
    k_convT<<<dim3(96, 24, 12), 256, 0, stream>>>(ff1w, 2359296,
                                                  wT + 2359296, WPL, 3072, 768);
    k_convT<<<dim3(24, 96, 12), 256, 0, stream>>>(ff2w, 2359296,
                                                  wT + 4718592, WPL, 768, 3072);
  }

  for (int l = 0; l < 12; ++l) {
    bf16_t* wl = big ? wT + (size_t)l * WPL : wT;
    bf16_t* qkvT = wl;
    bf16_t* woT = wl + 1769472;
    bf16_t* ff1T = wl + 2359296;
    bf16_t* ff2T = wl + 4718592;

    if (l > 0)
      k_ln<<<2048, 256, 0, stream>>>(x, h, ln1_s + l * 768, ln1_b + l * 768);
    if (!big) {
      k_convT3<<<dim3(2, 24, 36), 256, 0, stream>>>(
          wq + (size_t)l * 589824, wk + (size_t)l * 589824,
          wv + (size_t)l * 589824, qkvT, 589824, 0);
      k_convT<<<dim3(24, 24, 1), 256, 0, stream>>>(wo + (size_t)l * 589824, 0,
                                                   woT, 0, 768, 768);
      k_convT<<<dim3(96, 24, 1), 256, 0, stream>>>(ff1w + (size_t)l * 2359296,
                                                   0, ff1T, 0, 3072, 768);
      k_convT<<<dim3(24, 96, 1), 256, 0, stream>>>(ff2w + (size_t)l * 2359296,
                                                   0, ff2T, 0, 768, 3072);
    }
    // QKV: M=8192 N=2304 K=768 -> grid 1152 (large: single-buf core)
    k_gemm1<0><<<1152, 256, 0, stream>>>(h, 768, qkvT, 768, 768,
                                         nullptr, qkv, 2304, nullptr, 18);
    // attention (log-softmax decomposition)
    k_lse<<<dim3(192, 8), 256, 0, stream>>>(qkv, lseb);
    k_attn2<<<192, 256, 0, stream>>>(qkv, lseb, ctx);
    // WO + residual: grid 384 (small: pipelined 3-buf core)
    k_gemm3<1><<<384, 256, 0, stream>>>(ctx, 768, woT, 768, 768, x,
                                        nullptr, 768, wo_b + l * 768, 6);
    // FFN
    k_ln<<<2048, 256, 0, stream>>>(x, h, ln2_s + l * 768, ln2_b + l * 768);
    // FF1: grid 1536 (large: single-buf core)
    k_gemm1<2><<<1536, 256, 0, stream>>>(h, 768, ff1T, 768, 768,
                                         nullptr, gbuf, 3072,
                                         ff1b + l * 3072, 24);
    // FF2: grid 384 (small: pipelined 3-buf core)
    k_gemm3<1><<<384, 256, 0, stream>>>(gbuf, 3072, ff2T, 3072, 3072, x,
                                        nullptr, 768, ff2b + l * 768, 6);
  }
  k_final<<<16, 192, 0, stream>>>(x, fln_s, fln_b, cw, cb, out);
}

// Round 14
// 4007.075 us; speedup vs baseline: 1.0661x; 1.0168x over previous
//
#include <hip/hip_runtime.h>
#include <hip/hip_bf16.h>
#include <math.h>

// Dims: B=16 S=512 D=768 H=12 DH=64 F=3072 LYR=12 NLAB=2; rows = B*S = 8192
typedef __bf16 bf16_t;
typedef __attribute__((ext_vector_type(8))) __bf16 bf16x8;
typedef __attribute__((ext_vector_type(4))) float f32x4;

typedef const __attribute__((address_space(1))) void av1_void;
typedef __attribute__((address_space(3))) void av3_void;

#define DEV static __device__ __forceinline__

DEV void gload16(const void* g, void* l) {
  __builtin_amdgcn_global_load_lds((av1_void*)g, (av3_void*)l, 16, 0, 0);
}

// ---- block reduction over 3 waves (block=192) ----
DEV float bsum3(float v, float* red) {
#pragma unroll
  for (int o = 32; o > 0; o >>= 1) v += __shfl_xor(v, o, 64);
  __syncthreads();
  if ((threadIdx.x & 63) == 0) red[threadIdx.x >> 6] = v;
  __syncthreads();
  return red[0] + red[1] + red[2];
}

// ---- embedding gather + emb-LN -> x (fp32), then ln1(layer0) -> h (bf16) ----
__global__ __launch_bounds__(192) void k_embed(
    const int* __restrict__ ids, const float* __restrict__ tok,
    const float* __restrict__ pos, const float* __restrict__ gam,
    const float* __restrict__ bet, const float* __restrict__ gam2,
    const float* __restrict__ bet2, float* __restrict__ x,
    bf16_t* __restrict__ h) {
  __shared__ float red[3];
  int row = blockIdx.x;          // b*512 + s
  int s = row & 511;
  int t = threadIdx.x;
  int id = ids[row];
  const float4 tv = *(const float4*)&tok[(size_t)id * 768 + t * 4];
  const float4 pv = *(const float4*)&pos[(size_t)s * 768 + t * 4];
  float v[4] = {tv.x + pv.x, tv.y + pv.y, tv.z + pv.z, tv.w + pv.w};
  float tot = bsum3(v[0] + v[1] + v[2] + v[3], red);
  float mu = tot * (1.f / 768.f);
  float sq = 0.f;
#pragma unroll
  for (int u = 0; u < 4; ++u) { float d = v[u] - mu; sq += d * d; }
  float var = bsum3(sq, red) * (1.f / 768.f);
  float rstd = rsqrtf(var + 1e-5f);
  const float4 g4 = *(const float4*)&gam[t * 4];
  const float4 b4 = *(const float4*)&bet[t * 4];
  float o[4];
  o[0] = (v[0] - mu) * rstd * g4.x + b4.x;
  o[1] = (v[1] - mu) * rstd * g4.y + b4.y;
  o[2] = (v[2] - mu) * rstd * g4.z + b4.z;
  o[3] = (v[3] - mu) * rstd * g4.w + b4.w;
  float4 ov = {o[0], o[1], o[2], o[3]};
  *(float4*)&x[(size_t)row * 768 + t * 4] = ov;
  // second LN (ln1 of layer 0) -> h
  float tot2 = bsum3(o[0] + o[1] + o[2] + o[3], red);
  float mu2 = tot2 * (1.f / 768.f);
  float sq2 = 0.f;
#pragma unroll
  for (int u = 0; u < 4; ++u) { float d = o[u] - mu2; sq2 += d * d; }
  float var2 = bsum3(sq2, red) * (1.f / 768.f);
  float rstd2 = rsqrtf(var2 + 1e-5f);
  const float4 G = *(const float4*)&gam2[t * 4];
  const float4 Bb = *(const float4*)&bet2[t * 4];
  union { bf16_t ob[4]; uint2 u2; } pk;
  pk.ob[0] = (bf16_t)((o[0] - mu2) * rstd2 * G.x + Bb.x);
  pk.ob[1] = (bf16_t)((o[1] - mu2) * rstd2 * G.y + Bb.y);
  pk.ob[2] = (bf16_t)((o[2] - mu2) * rstd2 * G.z + Bb.z);
  pk.ob[3] = (bf16_t)((o[3] - mu2) * rstd2 * G.w + Bb.w);
  *(uint2*)&h[(size_t)row * 768 + t * 4] = pk.u2;
}

// ---- LN: x (fp32) -> h (bf16); wave-per-row, lane owns 12 cols ----
__global__ __launch_bounds__(256) void k_ln(
    const float* __restrict__ xin, bf16_t* __restrict__ hout,
    const float* __restrict__ gam, const float* __restrict__ bet) {
  int row = blockIdx.x * 4 + (threadIdx.x >> 6);
  int lane = threadIdx.x & 63;
  const float* xr = xin + (size_t)row * 768 + lane * 12;
  float4 a = *(const float4*)&xr[0];
  float4 b = *(const float4*)&xr[4];
  float4 c = *(const float4*)&xr[8];
  float v[12] = {a.x, a.y, a.z, a.w, b.x, b.y, b.z, b.w, c.x, c.y, c.z, c.w};
  float sm = 0.f;
#pragma unroll
  for (int u = 0; u < 12; ++u) sm += v[u];
#pragma unroll
  for (int o = 32; o > 0; o >>= 1) sm += __shfl_xor(sm, o, 64);
  float mu = sm * (1.f / 768.f);
  float sq = 0.f;
#pragma unroll
  for (int u = 0; u < 12; ++u) { float d = v[u] - mu; sq += d * d; }
#pragma unroll
  for (int o = 32; o > 0; o >>= 1) sq += __shfl_xor(sq, o, 64);
  float rstd = rsqrtf(sq * (1.f / 768.f) + 1e-5f);
  const float4 ga = *(const float4*)&gam[lane * 12];
  const float4 gb = *(const float4*)&gam[lane * 12 + 4];
  const float4 gc = *(const float4*)&gam[lane * 12 + 8];
  const float4 ba = *(const float4*)&bet[lane * 12];
  const float4 bb = *(const float4*)&bet[lane * 12 + 4];
  const float4 bc = *(const float4*)&bet[lane * 12 + 8];
  float g[12] = {ga.x, ga.y, ga.z, ga.w, gb.x, gb.y, gb.z, gb.w,
                 gc.x, gc.y, gc.z, gc.w};
  float be[12] = {ba.x, ba.y, ba.z, ba.w, bb.x, bb.y, bb.z, bb.w,
                  bc.x, bc.y, bc.z, bc.w};
  union { bf16_t o[12]; uint2 u2[3]; } pk;
#pragma unroll
  for (int u = 0; u < 12; ++u)
    pk.o[u] = (bf16_t)((v[u] - mu) * rstd * g[u] + be[u]);
  bf16_t* hr = hout + (size_t)row * 768 + lane * 12;
#pragma unroll
  for (int u = 0; u < 3; ++u) *(uint2*)&hr[u * 4] = pk.u2[u];
}

// ---- transpose-convert fp32 [K][N] -> bf16 [N][K], per z-slice ----
__global__ __launch_bounds__(256) void k_convT(
    const float* __restrict__ in, size_t in_slice, bf16_t* __restrict__ out,
    size_t out_slice, int N, int K) {
  __shared__ float tbuf[32][33];
  int slice = blockIdx.z;
  const float* ip = in + (size_t)slice * in_slice;
  bf16_t* op = out + (size_t)slice * out_slice;
  int n0 = blockIdx.x * 32, k0 = blockIdx.y * 32;
  int c = threadIdx.x & 31, r8 = threadIdx.x >> 5;
#pragma unroll
  for (int i = 0; i < 4; ++i) {
    int rr = r8 + i * 8;
    tbuf[rr][c] = ip[(size_t)(k0 + rr) * N + n0 + c];
  }
  __syncthreads();
#pragma unroll
  for (int i = 0; i < 4; ++i) {
    int rr = r8 + i * 8;
    op[(size_t)(n0 + rr) * K + k0 + c] = (bf16_t)tbuf[c][rr];
  }
}

// ---- fused wq/wk/wv transpose-convert, NL layers: z = l*36 + which*12 + head
__global__ __launch_bounds__(256) void k_convT3(
    const float* __restrict__ wq, const float* __restrict__ wk,
    const float* __restrict__ wv, bf16_t* __restrict__ out,
    size_t in_lstride, size_t out_lstride) {
  __shared__ float tbuf[32][33];
  int z = blockIdx.z;
  int l = z / 36, r = z % 36;
  int which = r / 12, head = r % 12;
  const float* ip = (which == 0 ? wq : which == 1 ? wk : wv) +
                    (size_t)l * in_lstride + (size_t)head * 768 * 64;
  bf16_t* op = out + (size_t)l * out_lstride + (size_t)which * 768 * 768 +
               (size_t)head * 64 * 768;
  int n0 = blockIdx.x * 32, k0 = blockIdx.y * 32;   // N=64, K=768
  int c = threadIdx.x & 31, r8 = threadIdx.x >> 5;
#pragma unroll
  for (int i = 0; i < 4; ++i) {
    int rr = r8 + i * 8;
    tbuf[rr][c] = ip[(size_t)(k0 + rr) * 64 + n0 + c];
  }
  __syncthreads();
#pragma unroll
  for (int i = 0; i < 4; ++i) {
    int rr = r8 + i * 8;
    op[(size_t)(n0 + rr) * 768 + k0 + c] = (bf16_t)tbuf[c][rr];
  }
}

// ======================================================================
// k_gemm1 (round-10 core): BK=64, SINGLE-buffered LDS (32KB -> 5
// blocks/CU). Best for LARGE grids (QKV, FF1): cross-block overlap.
// ======================================================================
template <int EPI>
__global__ __launch_bounds__(256) void k_gemm1(
    const bf16_t* __restrict__ A, int lda, const bf16_t* __restrict__ Bt,
    int ldb, int K, float* __restrict__ Cf, bf16_t* __restrict__ Cb, int ldc,
    const float* __restrict__ bias, int gx) {
  __shared__ __attribute__((aligned(16))) bf16_t As[128 * 64];
  __shared__ __attribute__((aligned(16))) bf16_t Bs[128 * 64];
  const int nwg = gridDim.x;
  const int bid = blockIdx.x;
  const int cpx = nwg >> 3;
  const int swz = (bid & 7) * cpx + (bid >> 3);
  const int bx = swz % gx, by = swz / gx;
  const int m0 = by << 7, n0 = bx << 7;
  const int tid = threadIdx.x;
  const int lane = tid & 63, w = tid >> 6;
  const int wm = w >> 1, wn = w & 1;
  const int r = lane & 15, g4 = lane >> 4;

  f32x4 acc[4][4];
#pragma unroll
  for (int m = 0; m < 4; ++m)
#pragma unroll
    for (int n = 0; n < 4; ++n)
#pragma unroll
      for (int e = 0; e < 4; ++e) acc[m][n][e] = 0.f;

  const bf16_t* pa[4];
  const bf16_t* pb[4];
  char* la[4];
  char* lb[4];
#pragma unroll
  for (int u = 0; u < 4; ++u) {
    int s = u * 256 + tid;
    int row = s >> 3;
    int c = (s & 7) ^ (row & 7);
    pa[u] = A + (size_t)(m0 + row) * lda + c * 8;
    pb[u] = Bt + (size_t)(n0 + row) * ldb + c * 8;
    la[u] = (char*)As + (size_t)(u * 256 + (w << 6)) * 16;
    lb[u] = (char*)Bs + (size_t)(u * 256 + (w << 6)) * 16;
  }

  const int NT = K >> 6;
  for (int t = 0; t < NT; ++t) {
    const int k0 = t << 6;
#pragma unroll
    for (int u = 0; u < 4; ++u) gload16(pa[u] + k0, la[u]);
#pragma unroll
    for (int u = 0; u < 4; ++u) gload16(pb[u] + k0, lb[u]);
    __syncthreads();

#pragma unroll
    for (int kk = 0; kk < 2; ++kk) {
      bf16x8 af[4], bb[4];
#pragma unroll
      for (int m = 0; m < 4; ++m) {
        int row = wm * 64 + m * 16 + r;
        af[m] = *(const bf16x8*)&As[row * 64 +
                                    (((kk << 2) + g4) ^ (row & 7)) * 8];
      }
#pragma unroll
      for (int n = 0; n < 4; ++n) {
        int row = wn * 64 + n * 16 + r;
        bb[n] = *(const bf16x8*)&Bs[row * 64 +
                                    (((kk << 2) + g4) ^ (row & 7)) * 8];
      }
#pragma unroll
      for (int m = 0; m < 4; ++m)
#pragma unroll
        for (int n = 0; n < 4; ++n)
          acc[m][n] = __builtin_amdgcn_mfma_f32_16x16x32_bf16(af[m], bb[n],
                                                              acc[m][n], 0, 0, 0);
    }
    __syncthreads();
  }

#pragma unroll
  for (int m = 0; m < 4; ++m) {
#pragma unroll
    for (int n = 0; n < 4; ++n) {
      int col = n0 + wn * 64 + n * 16 + r;
      float bv = 0.f;
      if constexpr (EPI != 0) bv = bias[col];
#pragma unroll
      for (int j = 0; j < 4; ++j) {
        int row = m0 + wm * 64 + m * 16 + g4 * 4 + j;
        float v = acc[m][n][j];
        if constexpr (EPI == 0) {
          Cb[(size_t)row * ldc + col] = (bf16_t)v;
        } else if constexpr (EPI == 1) {
          size_t o = (size_t)row * ldc + col;
          Cf[o] += v + bv;
        } else {
          float tt = v + bv;
          float ge = 0.5f * tt * (1.f + erff(tt * 0.70710678118f));
          Cb[(size_t)row * ldc + col] = (bf16_t)ge;
        }
      }
    }
  }
}

// ======================================================================
// k_gemm3 (round-11 core): BK=32, THREE-buffer LDS, counted vmcnt(4).
// Best for SMALL grids (WO, FF2): fill-starved, needs in-block pipeline.
// ======================================================================
template <int EPI>
__global__ __launch_bounds__(256) void k_gemm3(
    const bf16_t* __restrict__ A, int lda, const bf16_t* __restrict__ Bt,
    int ldb, int K, float* __restrict__ Cf, bf16_t* __restrict__ Cb, int ldc,
    const float* __restrict__ bias, int gx) {
  __shared__ __attribute__((aligned(16))) bf16_t As[3][128 * 32];
  __shared__ __attribute__((aligned(16))) bf16_t Bs[3][128 * 32];
  const int nwg = gridDim.x;
  const int bid = blockIdx.x;
  const int cpx = nwg >> 3;
  const int swz = (bid & 7) * cpx + (bid >> 3);
  const int bx = swz % gx, by = swz / gx;
  const int m0 = by << 7, n0 = bx << 7;
  const int tid = threadIdx.x;
  const int lane = tid & 63, w = tid >> 6;
  const int wm = w >> 1, wn = w & 1;
  const int r = lane & 15, g4 = lane >> 4;

  f32x4 acc[4][4];
#pragma unroll
  for (int m = 0; m < 4; ++m)
#pragma unroll
    for (int n = 0; n < 4; ++n)
#pragma unroll
      for (int e = 0; e < 4; ++e) acc[m][n][e] = 0.f;

  const bf16_t* pa[2];
  const bf16_t* pb[2];
  uint32_t lo[2];
#pragma unroll
  for (int u = 0; u < 2; ++u) {
    int s = u * 256 + tid;
    int row = s >> 2;
    int c = (s & 3) ^ ((row >> 1) & 3);
    pa[u] = A + (size_t)(m0 + row) * lda + c * 8;
    pb[u] = Bt + (size_t)(n0 + row) * ldb + c * 8;
    lo[u] = (uint32_t)(u * 256 + (w << 6)) * 16;
  }

  const int NT = K >> 5;
  auto STAGE = [&](int t, int bufi) {
    int k0 = (t < NT ? t : NT - 1) << 5;
#pragma unroll
    for (int u = 0; u < 2; ++u) gload16(pa[u] + k0, (char*)&As[bufi][0] + lo[u]);
#pragma unroll
    for (int u = 0; u < 2; ++u) gload16(pb[u] + k0, (char*)&Bs[bufi][0] + lo[u]);
  };

  STAGE(0, 0);
  STAGE(1, 1);
  int bi = 0, si = 2;
  const int co = (g4 ^ ((r >> 1) & 3)) << 3;
  for (int t = 0; t < NT; ++t) {
    asm volatile("s_waitcnt vmcnt(4)" ::: "memory");
    asm volatile("s_barrier" ::: "memory");
    bf16x8 af[4], bb[4];
#pragma unroll
    for (int m = 0; m < 4; ++m) {
      int row = wm * 64 + m * 16 + r;
      af[m] = *(const bf16x8*)&As[bi][row * 32 + co];
    }
#pragma unroll
    for (int n = 0; n < 4; ++n) {
      int row = wn * 64 + n * 16 + r;
      bb[n] = *(const bf16x8*)&Bs[bi][row * 32 + co];
    }
#pragma unroll
    for (int m = 0; m < 4; ++m)
#pragma unroll
      for (int n = 0; n < 4; ++n)
        acc[m][n] = __builtin_amdgcn_mfma_f32_16x16x32_bf16(af[m], bb[n],
                                                            acc[m][n], 0, 0, 0);
    asm volatile("s_barrier" ::: "memory");
    STAGE(t + 2, si);
    si = bi;
    bi = (bi == 2) ? 0 : bi + 1;
  }
  asm volatile("s_waitcnt vmcnt(0)" ::: "memory");

#pragma unroll
  for (int m = 0; m < 4; ++m) {
#pragma unroll
    for (int n = 0; n < 4; ++n) {
      int col = n0 + wn * 64 + n * 16 + r;
      float bv = 0.f;
      if constexpr (EPI != 0) bv = bias[col];
#pragma unroll
      for (int j = 0; j < 4; ++j) {
        int row = m0 + wm * 64 + m * 16 + g4 * 4 + j;
        float v = acc[m][n][j];
        if constexpr (EPI == 0) {
          Cb[(size_t)row * ldc + col] = (bf16_t)v;
        } else if constexpr (EPI == 1) {
          size_t o = (size_t)row * ldc + col;
          Cf[o] += v + bv;
        } else {
          float tt = v + bv;
          float ge = 0.5f * tt * (1.f + erff(tt * 0.70710678118f));
          Cb[(size_t)row * ldc + col] = (bf16_t)ge;
        }
      }
    }
  }
}

// ======================================================================
// Fused attention (log-softmax decomposition), one block per (b,h):
//   1. stage K[512][64] once (XOR-swizzled, resident)
//   2. stream V tiles -> M = K^T V / 8 (scalar FMA) + per-wave sumv
//   3. 8 double-buffered Q-chunks: QK^T (MFMA) -> lse (in-register)
//      -> ctx = Q*Mt - lse (x) sumv -> store
// LDS: 64 + 32 + 16 + 8 + ~1.3 KB = ~121 KB (1 block/CU; grid 192 < 256)
// ======================================================================
__global__ __launch_bounds__(256) void k_attn(const bf16_t* __restrict__ qkv,
                                              bf16_t* __restrict__ ctx) {
  __shared__ __attribute__((aligned(16))) bf16_t Ks[512 * 64];   // swizzled
  __shared__ __attribute__((aligned(16))) float Vs[128 * 64];
  __shared__ __attribute__((aligned(16))) bf16_t Qs[2][64 * 64]; // swizzled
  __shared__ __attribute__((aligned(16))) bf16_t Mt[64 * 64];    // swizzled
  __shared__ float svp[4 * 64];
  __shared__ float svs[64];

  int bh = blockIdx.x;
  int b = bh / 12, hh = bh % 12;
  int tid = threadIdx.x, lane = tid & 63, w = tid >> 6;
  int r = lane & 15, g4 = lane >> 4;
  const bf16_t* qb = qkv + (size_t)b * 512 * 2304 + hh * 64;
  const bf16_t* kb = qb + 768;
  const bf16_t* vb = qb + 1536;

  // stage full K (swizzled): 4096 16B slots
#pragma unroll
  for (int i = 0; i < 16; ++i) {
    int s = i * 256 + tid;
    int row = s >> 3;
    int c = (s & 7) ^ (row & 7);
    gload16(kb + (size_t)row * 2304 + c * 8,
            (char*)Ks + (size_t)(i * 256 + (w << 6)) * 16);
  }

  // ---- phase 1: M = K^T V / 8 (lane owns e1=lane; wave owns e2 range) ----
  f32x4 macc[4];
#pragma unroll
  for (int jj = 0; jj < 4; ++jj)
#pragma unroll
    for (int e = 0; e < 4; ++e) macc[jj][e] = 0.f;
  float svacc = 0.f;
  const int e1 = lane;
  const int e1hi = (e1 >> 3), e1lo = (e1 & 7);

  for (int t0 = 0; t0 < 512; t0 += 128) {
#pragma unroll
    for (int i = 0; i < 4; ++i) {
      int cs = i * 256 + tid;
      int row = cs >> 3, col = (cs & 7) * 8;
      bf16x8 raw = *(const bf16x8*)(vb + (size_t)(t0 + row) * 2304 + col);
      f32x4 v0, v1;
#pragma unroll
      for (int u = 0; u < 4; ++u) { v0[u] = (float)raw[u]; v1[u] = (float)raw[u + 4]; }
      *(f32x4*)&Vs[row * 64 + col] = v0;
      *(f32x4*)&Vs[row * 64 + col + 4] = v1;
    }
    __syncthreads();          // V tile ready (and Ks on first iter)
    for (int tt = 0; tt < 128; ++tt) {
      int t = t0 + tt;
      float kv = (float)Ks[t * 64 + (((e1hi ^ (t & 7)) << 3) | e1lo)];
#pragma unroll
      for (int jj = 0; jj < 4; ++jj) {
        f32x4 vv = *(const f32x4*)&Vs[tt * 64 + w * 16 + jj * 4];
        macc[jj] += kv * vv;
      }
    }
    // per-wave sumv partial: wave w sums rows [w*32, w*32+32)
    for (int q = 0; q < 32; ++q)
      svacc += Vs[((w << 5) + q) * 64 + lane];
    __syncthreads();          // done reading before next tile overwrite
  }

  // write Mt (transposed, bf16, swizzled): Mt[e2][e1] = M[e1][e2]*0.125
#pragma unroll
  for (int jj = 0; jj < 4; ++jj)
#pragma unroll
    for (int u = 0; u < 4; ++u) {
      int e2 = w * 16 + jj * 4 + u;
      Mt[e2 * 64 + (((e1hi ^ (e2 & 7)) << 3) | e1lo)] =
          (bf16_t)(macc[jj][u] * 0.125f);
    }
  svp[w * 64 + lane] = svacc;
  __syncthreads();
  if (w == 0)
    svs[lane] = svp[lane] + svp[64 + lane] + svp[128 + lane] + svp[192 + lane];

  // ---- phase 2: per 64-row Q chunk: QK^T -> lse -> ctx ----
  auto stageQ = [&](int qc, int bufi) {
#pragma unroll
    for (int u = 0; u < 2; ++u) {
      int s = u * 256 + tid;
      int row = s >> 3;
      int c = (s & 7) ^ (row & 7);
      gload16(qb + (size_t)(qc * 64 + row) * 2304 + c * 8,
              (char*)&Qs[bufi][0] + (size_t)(u * 256 + (w << 6)) * 16);
    }
  };
  stageQ(0, 0);
  const int arow = w * 16 + r;

  for (int qc = 0; qc < 8; ++qc) {
    __syncthreads();          // Q(qc) ready; svs visible (qc=0); prev reads done
    if (qc < 7) stageQ(qc + 1, (qc + 1) & 1);
    const bf16_t* Qb = &Qs[qc & 1][0];

    f32x4 acc2[32];
#pragma unroll
    for (int n = 0; n < 32; ++n)
#pragma unroll
      for (int e = 0; e < 4; ++e) acc2[n][e] = 0.f;

#pragma unroll
    for (int kk = 0; kk < 2; ++kk) {
      bf16x8 aq = *(const bf16x8*)&Qb[arow * 64 +
                                      (((kk << 2) + g4) ^ (arow & 7)) * 8];
#pragma unroll
      for (int n = 0; n < 32; ++n) {
        int krow = n * 16 + r;
        bf16x8 bk = *(const bf16x8*)&Ks[krow * 64 +
                                        (((kk << 2) + g4) ^ (krow & 7)) * 8];
        acc2[n] = __builtin_amdgcn_mfma_f32_16x16x32_bf16(aq, bk, acc2[n], 0, 0, 0);
      }
    }

    float lse_j[4];
#pragma unroll
    for (int j = 0; j < 4; ++j) {
      float mx = -1e30f;
#pragma unroll
      for (int n = 0; n < 32; ++n) mx = fmaxf(mx, acc2[n][j] * 0.125f);
#pragma unroll
      for (int o = 1; o < 16; o <<= 1) mx = fmaxf(mx, __shfl_xor(mx, o, 64));
      float sm = 0.f;
#pragma unroll
      for (int n = 0; n < 32; ++n) sm += expf(acc2[n][j] * 0.125f - mx);
#pragma unroll
      for (int o = 1; o < 16; o <<= 1) sm += __shfl_xor(sm, o, 64);
      lse_j[j] = mx + logf(sm);
    }

    f32x4 acc3[4];
#pragma unroll
    for (int n = 0; n < 4; ++n)
#pragma unroll
      for (int e = 0; e < 4; ++e) acc3[n][e] = 0.f;
#pragma unroll
    for (int kk = 0; kk < 2; ++kk) {
      bf16x8 aq = *(const bf16x8*)&Qb[arow * 64 +
                                      (((kk << 2) + g4) ^ (arow & 7)) * 8];
#pragma unroll
      for (int n2 = 0; n2 < 4; ++n2) {
        int mrow = n2 * 16 + r;
        bf16x8 bm = *(const bf16x8*)&Mt[mrow * 64 +
                                        (((kk << 2) + g4) ^ (mrow & 7)) * 8];
        acc3[n2] = __builtin_amdgcn_mfma_f32_16x16x32_bf16(aq, bm, acc3[n2], 0, 0, 0);
      }
    }
#pragma unroll
    for (int n2 = 0; n2 < 4; ++n2) {
      int col = n2 * 16 + r;
      float svv = svs[col];
#pragma unroll
      for (int j = 0; j < 4; ++j) {
        int srow = qc * 64 + w * 16 + g4 * 4 + j;
        ctx[((size_t)(b * 512 + srow)) * 768 + hh * 64 + col] =
            (bf16_t)(acc3[n2][j] - lse_j[j] * svv);
      }
    }
  }
}

// ---- final LN (row s=0 per batch) + classifier ----
__global__ __launch_bounds__(192) void k_final(
    const float* __restrict__ x, const float* __restrict__ gam,
    const float* __restrict__ bet, const float* __restrict__ cw,
    const float* __restrict__ cb, float* __restrict__ out) {
  __shared__ float red[3];
  int b = blockIdx.x, t = threadIdx.x;
  const float* xr = x + (size_t)b * 512 * 768;
  const float4 xv = *(const float4*)&xr[t * 4];
  float v[4] = {xv.x, xv.y, xv.z, xv.w};
  float tot = bsum3(v[0] + v[1] + v[2] + v[3], red);
  float mu = tot * (1.f / 768.f);
  float sq = 0.f;
#pragma unroll
  for (int u = 0; u < 4; ++u) { float d = v[u] - mu; sq += d * d; }
  float var = bsum3(sq, red) * (1.f / 768.f);
  float rstd = rsqrtf(var + 1e-5f);
  const float4 g4 = *(const float4*)&gam[t * 4];
  const float4 b4 = *(const float4*)&bet[t * 4];
  float nv[4];
  nv[0] = (v[0] - mu) * rstd * g4.x + b4.x;
  nv[1] = (v[1] - mu) * rstd * g4.y + b4.y;
  nv[2] = (v[2] - mu) * rstd * g4.z + b4.z;
  nv[3] = (v[3] - mu) * rstd * g4.w + b4.w;
  const float4 wa = *(const float4*)&cw[t * 8];
  const float4 wb = *(const float4*)&cw[t * 8 + 4];
  float d0 = nv[0] * wa.x + nv[1] * wa.z + nv[2] * wb.x + nv[3] * wb.z;
  float d1 = nv[0] * wa.y + nv[1] * wa.w + nv[2] * wb.y + nv[3] * wb.w;
  d0 = bsum3(d0, red);
  d1 = bsum3(d1, red);
  if (t == 0) {
    out[b * 2 + 0] = d0 + cb[0];
    out[b * 2 + 1] = d1 + cb[1];
  }
}

// ---- workspace layout ----
static constexpr size_t OFF_X = 0;                                  // f32 8192x768
static constexpr size_t OFF_H = OFF_X + 8192ull * 768 * 4;          // bf16 8192x768
static constexpr size_t OFF_QG = OFF_H + 8192ull * 768 * 2;         // bf16 arena (qkv | gelu)
static constexpr size_t OFF_CTX = OFF_QG + 8192ull * 3072 * 2;      // bf16 8192x768
static constexpr size_t OFF_LSE = OFF_CTX + 8192ull * 768 * 2;      // f32 (unused)
static constexpr size_t OFF_W = OFF_LSE + 192ull * 512 * 4;         // bf16 weights
static constexpr size_t WPL = 7077888;                              // elems per layer
static constexpr size_t WS_SMALL = OFF_W + WPL * 2;                 // 1-layer buffer
static constexpr size_t WS_BIG = OFF_W + 12ull * WPL * 2;           // all layers

extern "C" void kernel_launch(void* const* d_in, const int* in_sizes, int n_in,
                              void* d_out, int out_size, void* d_ws,
                              size_t ws_size, hipStream_t stream) {
  const int* ids = (const int*)d_in[0];
  const float* tok = (const float*)d_in[1];
  const float* pos = (const float*)d_in[2];
  const float* eln_s = (const float*)d_in[3];
  const float* eln_b = (const float*)d_in[4];
  const float* wq = (const float*)d_in[5];
  const float* wk = (const float*)d_in[6];
  const float* wv = (const float*)d_in[7];
  const float* wo = (const float*)d_in[8];
  const float* wo_b = (const float*)d_in[9];
  const float* ln1_s = (const float*)d_in[10];
  const float* ln1_b = (const float*)d_in[11];
  const float* ln2_s = (const float*)d_in[12];
  const float* ln2_b = (const float*)d_in[13];
  const float* ff1w = (const float*)d_in[14];
  const float* ff1b = (const float*)d_in[15];
  const float* ff2w = (const float*)d_in[16];
  const float* ff2b = (const float*)d_in[17];
  const float* fln_s = (const float*)d_in[18];
  const float* fln_b = (const float*)d_in[19];
  const float* cw = (const float*)d_in[20];
  const float* cb = (const float*)d_in[21];
  float* out = (float*)d_out;

  if (ws_size < WS_SMALL) return;
  const bool big = ws_size >= WS_BIG;

  char* ws = (char*)d_ws;
  float* x = (float*)(ws + OFF_X);
  bf16_t* h = (bf16_t*)(ws + OFF_H);
  bf16_t* qkv = (bf16_t*)(ws + OFF_QG);
  bf16_t* gbuf = (bf16_t*)(ws + OFF_QG);
  bf16_t* ctx = (bf16_t*)(ws + OFF_CTX);
  bf16_t* wT = (bf16_t*)(ws + OFF_W);

  // embedding + emb-LN + ln1(layer0)
  k_embed<<<8192, 192, 0, stream>>>(ids, tok, pos, eln_s, eln_b,
                                    ln1_s, ln1_b, x, h);

  if (big) {
    // convert ALL layers' weights upfront: 4 launches
    k_convT3<<<dim3(2, 24, 432), 256, 0, stream>>>(wq, wk, wv, wT,
                                                   589824, WPL);
    k_convT<<<dim3(24, 24, 12), 256, 0, stream>>>(wo, 589824,
                                                  wT + 1769472, WPL, 768, 768);
    k_convT<<<dim3(96, 24, 12), 256, 0, stream>>>(ff1w, 2359296,
                                                  wT + 2359296, WPL, 3072, 768);
    k_convT<<<dim3(24, 96, 12), 256, 0, stream>>>(ff2w, 2359296,
                                                  wT + 4718592, WPL, 768, 3072);
  }

  for (int l = 0; l < 12; ++l) {
    bf16_t* wl = big ? wT + (size_t)l * WPL : wT;
    bf16_t* qkvT = wl;
    bf16_t* woT = wl + 1769472;
    bf16_t* ff1T = wl + 2359296;
    bf16_t* ff2T = wl + 4718592;

    if (l > 0)
      k_ln<<<2048, 256, 0, stream>>>(x, h, ln1_s + l * 768, ln1_b + l * 768);
    if (!big) {
      k_convT3<<<dim3(2, 24, 36), 256, 0, stream>>>(
          wq + (size_t)l * 589824, wk + (size_t)l * 589824,
          wv + (size_t)l * 589824, qkvT, 589824, 0);
      k_convT<<<dim3(24, 24, 1), 256, 0, stream>>>(wo + (size_t)l * 589824, 0,
                                                   woT, 0, 768, 768);
      k_convT<<<dim3(96, 24, 1), 256, 0, stream>>>(ff1w + (size_t)l * 2359296,
                                                   0, ff1T, 0, 3072, 768);
      k_convT<<<dim3(24, 96, 1), 256, 0, stream>>>(ff2w + (size_t)l * 2359296,
                                                   0, ff2T, 0, 768, 3072);
    }
    // QKV: M=8192 N=2304 K=768 -> grid 1152 (large: single-buf core)
    k_gemm1<0><<<1152, 256, 0, stream>>>(h, 768, qkvT, 768, 768,
                                         nullptr, qkv, 2304, nullptr, 18);
    // fused attention (log-softmax decomposition)
    k_attn<<<192, 256, 0, stream>>>(qkv, ctx);
    // WO + residual: grid 384 (small: pipelined 3-buf core)
    k_gemm3<1><<<384, 256, 0, stream>>>(ctx, 768, woT, 768, 768, x,
                                        nullptr, 768, wo_b + l * 768, 6);
    // FFN
    k_ln<<<2048, 256, 0, stream>>>(x, h, ln2_s + l * 768, ln2_b + l * 768);
    // FF1: grid 1536 (large: single-buf core)
    k_gemm1<2><<<1536, 256, 0, stream>>>(h, 768, ff1T, 768, 768,
                                         nullptr, gbuf, 3072,
                                         ff1b + l * 3072, 24);
    // FF2: grid 384 (small: pipelined 3-buf core)
    k_gemm3<1><<<384, 256, 0, stream>>>(gbuf, 3072, ff2T, 3072, 3072, x,
                                        nullptr, 768, ff2b + l * 768, 6);
  }
  k_final<<<16, 192, 0, stream>>>(x, fln_s, fln_b, cw, cb, out);
}

// Round 15
// 3640.575 us; speedup vs baseline: 1.1735x; 1.1007x over previous
//
#include <hip/hip_runtime.h>
#include <hip/hip_bf16.h>
#include <math.h>

// Dims: B=16 S=512 D=768 H=12 DH=64 F=3072 LYR=12 NLAB=2; rows = B*S = 8192
typedef __bf16 bf16_t;
typedef __attribute__((ext_vector_type(8))) __bf16 bf16x8;
typedef __attribute__((ext_vector_type(4))) float f32x4;

typedef const __attribute__((address_space(1))) void av1_void;
typedef __attribute__((address_space(3))) void av3_void;

#define DEV static __device__ __forceinline__

DEV void gload16(const void* g, void* l) {
  __builtin_amdgcn_global_load_lds((av1_void*)g, (av3_void*)l, 16, 0, 0);
}

// ---- block reduction over 3 waves (block=192) ----
DEV float bsum3(float v, float* red) {
#pragma unroll
  for (int o = 32; o > 0; o >>= 1) v += __shfl_xor(v, o, 64);
  __syncthreads();
  if ((threadIdx.x & 63) == 0) red[threadIdx.x >> 6] = v;
  __syncthreads();
  return red[0] + red[1] + red[2];
}

// ---- embedding gather + emb-LN -> x (fp32), then ln1(layer0) -> h (bf16) ----
__global__ __launch_bounds__(192) void k_embed(
    const int* __restrict__ ids, const float* __restrict__ tok,
    const float* __restrict__ pos, const float* __restrict__ gam,
    const float* __restrict__ bet, const float* __restrict__ gam2,
    const float* __restrict__ bet2, float* __restrict__ x,
    bf16_t* __restrict__ h) {
  __shared__ float red[3];
  int row = blockIdx.x;          // b*512 + s
  int s = row & 511;
  int t = threadIdx.x;
  int id = ids[row];
  const float4 tv = *(const float4*)&tok[(size_t)id * 768 + t * 4];
  const float4 pv = *(const float4*)&pos[(size_t)s * 768 + t * 4];
  float v[4] = {tv.x + pv.x, tv.y + pv.y, tv.z + pv.z, tv.w + pv.w};
  float tot = bsum3(v[0] + v[1] + v[2] + v[3], red);
  float mu = tot * (1.f / 768.f);
  float sq = 0.f;
#pragma unroll
  for (int u = 0; u < 4; ++u) { float d = v[u] - mu; sq += d * d; }
  float var = bsum3(sq, red) * (1.f / 768.f);
  float rstd = rsqrtf(var + 1e-5f);
  const float4 g4 = *(const float4*)&gam[t * 4];
  const float4 b4 = *(const float4*)&bet[t * 4];
  float o[4];
  o[0] = (v[0] - mu) * rstd * g4.x + b4.x;
  o[1] = (v[1] - mu) * rstd * g4.y + b4.y;
  o[2] = (v[2] - mu) * rstd * g4.z + b4.z;
  o[3] = (v[3] - mu) * rstd * g4.w + b4.w;
  float4 ov = {o[0], o[1], o[2], o[3]};
  *(float4*)&x[(size_t)row * 768 + t * 4] = ov;
  // second LN (ln1 of layer 0) -> h
  float tot2 = bsum3(o[0] + o[1] + o[2] + o[3], red);
  float mu2 = tot2 * (1.f / 768.f);
  float sq2 = 0.f;
#pragma unroll
  for (int u = 0; u < 4; ++u) { float d = o[u] - mu2; sq2 += d * d; }
  float var2 = bsum3(sq2, red) * (1.f / 768.f);
  float rstd2 = rsqrtf(var2 + 1e-5f);
  const float4 G = *(const float4*)&gam2[t * 4];
  const float4 Bb = *(const float4*)&bet2[t * 4];
  union { bf16_t ob[4]; uint2 u2; } pk;
  pk.ob[0] = (bf16_t)((o[0] - mu2) * rstd2 * G.x + Bb.x);
  pk.ob[1] = (bf16_t)((o[1] - mu2) * rstd2 * G.y + Bb.y);
  pk.ob[2] = (bf16_t)((o[2] - mu2) * rstd2 * G.z + Bb.z);
  pk.ob[3] = (bf16_t)((o[3] - mu2) * rstd2 * G.w + Bb.w);
  *(uint2*)&h[(size_t)row * 768 + t * 4] = pk.u2;
}

// ---- LN: x (fp32) -> h (bf16); wave-per-row, lane owns 12 cols ----
__global__ __launch_bounds__(256) void k_ln(
    const float* __restrict__ xin, bf16_t* __restrict__ hout,
    const float* __restrict__ gam, const float* __restrict__ bet) {
  int row = blockIdx.x * 4 + (threadIdx.x >> 6);
  int lane = threadIdx.x & 63;
  const float* xr = xin + (size_t)row * 768 + lane * 12;
  float4 a = *(const float4*)&xr[0];
  float4 b = *(const float4*)&xr[4];
  float4 c = *(const float4*)&xr[8];
  float v[12] = {a.x, a.y, a.z, a.w, b.x, b.y, b.z, b.w, c.x, c.y, c.z, c.w};
  float sm = 0.f;
#pragma unroll
  for (int u = 0; u < 12; ++u) sm += v[u];
#pragma unroll
  for (int o = 32; o > 0; o >>= 1) sm += __shfl_xor(sm, o, 64);
  float mu = sm * (1.f / 768.f);
  float sq = 0.f;
#pragma unroll
  for (int u = 0; u < 12; ++u) { float d = v[u] - mu; sq += d * d; }
#pragma unroll
  for (int o = 32; o > 0; o >>= 1) sq += __shfl_xor(sq, o, 64);
  float rstd = rsqrtf(sq * (1.f / 768.f) + 1e-5f);
  const float4 ga = *(const float4*)&gam[lane * 12];
  const float4 gb = *(const float4*)&gam[lane * 12 + 4];
  const float4 gc = *(const float4*)&gam[lane * 12 + 8];
  const float4 ba = *(const float4*)&bet[lane * 12];
  const float4 bb = *(const float4*)&bet[lane * 12 + 4];
  const float4 bc = *(const float4*)&bet[lane * 12 + 8];
  float g[12] = {ga.x, ga.y, ga.z, ga.w, gb.x, gb.y, gb.z, gb.w,
                 gc.x, gc.y, gc.z, gc.w};
  float be[12] = {ba.x, ba.y, ba.z, ba.w, bb.x, bb.y, bb.z, bb.w,
                  bc.x, bc.y, bc.z, bc.w};
  union { bf16_t o[12]; uint2 u2[3]; } pk;
#pragma unroll
  for (int u = 0; u < 12; ++u)
    pk.o[u] = (bf16_t)((v[u] - mu) * rstd * g[u] + be[u]);
  bf16_t* hr = hout + (size_t)row * 768 + lane * 12;
#pragma unroll
  for (int u = 0; u < 3; ++u) *(uint2*)&hr[u * 4] = pk.u2[u];
}

// ---- transpose-convert fp32 [K][N] -> bf16 [N][K], per z-slice ----
__global__ __launch_bounds__(256) void k_convT(
    const float* __restrict__ in, size_t in_slice, bf16_t* __restrict__ out,
    size_t out_slice, int N, int K) {
  __shared__ float tbuf[32][33];
  int slice = blockIdx.z;
  const float* ip = in + (size_t)slice * in_slice;
  bf16_t* op = out + (size_t)slice * out_slice;
  int n0 = blockIdx.x * 32, k0 = blockIdx.y * 32;
  int c = threadIdx.x & 31, r8 = threadIdx.x >> 5;
#pragma unroll
  for (int i = 0; i < 4; ++i) {
    int rr = r8 + i * 8;
    tbuf[rr][c] = ip[(size_t)(k0 + rr) * N + n0 + c];
  }
  __syncthreads();
#pragma unroll
  for (int i = 0; i < 4; ++i) {
    int rr = r8 + i * 8;
    op[(size_t)(n0 + rr) * K + k0 + c] = (bf16_t)tbuf[c][rr];
  }
}

// ---- fused wq/wk/wv transpose-convert, NL layers: z = l*36 + which*12 + head
__global__ __launch_bounds__(256) void k_convT3(
    const float* __restrict__ wq, const float* __restrict__ wk,
    const float* __restrict__ wv, bf16_t* __restrict__ out,
    size_t in_lstride, size_t out_lstride) {
  __shared__ float tbuf[32][33];
  int z = blockIdx.z;
  int l = z / 36, r = z % 36;
  int which = r / 12, head = r % 12;
  const float* ip = (which == 0 ? wq : which == 1 ? wk : wv) +
                    (size_t)l * in_lstride + (size_t)head * 768 * 64;
  bf16_t* op = out + (size_t)l * out_lstride + (size_t)which * 768 * 768 +
               (size_t)head * 64 * 768;
  int n0 = blockIdx.x * 32, k0 = blockIdx.y * 32;   // N=64, K=768
  int c = threadIdx.x & 31, r8 = threadIdx.x >> 5;
#pragma unroll
  for (int i = 0; i < 4; ++i) {
    int rr = r8 + i * 8;
    tbuf[rr][c] = ip[(size_t)(k0 + rr) * 64 + n0 + c];
  }
  __syncthreads();
#pragma unroll
  for (int i = 0; i < 4; ++i) {
    int rr = r8 + i * 8;
    op[(size_t)(n0 + rr) * 768 + k0 + c] = (bf16_t)tbuf[c][rr];
  }
}

// ======================================================================
// k_gemm1 (round-10 core): BK=64, SINGLE-buffered LDS (32KB -> 5
// blocks/CU). Best for LARGE grids (QKV, FF1): cross-block overlap.
// ======================================================================
template <int EPI>
__global__ __launch_bounds__(256) void k_gemm1(
    const bf16_t* __restrict__ A, int lda, const bf16_t* __restrict__ Bt,
    int ldb, int K, float* __restrict__ Cf, bf16_t* __restrict__ Cb, int ldc,
    const float* __restrict__ bias, int gx) {
  __shared__ __attribute__((aligned(16))) bf16_t As[128 * 64];
  __shared__ __attribute__((aligned(16))) bf16_t Bs[128 * 64];
  const int nwg = gridDim.x;
  const int bid = blockIdx.x;
  const int cpx = nwg >> 3;
  const int swz = (bid & 7) * cpx + (bid >> 3);
  const int bx = swz % gx, by = swz / gx;
  const int m0 = by << 7, n0 = bx << 7;
  const int tid = threadIdx.x;
  const int lane = tid & 63, w = tid >> 6;
  const int wm = w >> 1, wn = w & 1;
  const int r = lane & 15, g4 = lane >> 4;

  f32x4 acc[4][4];
#pragma unroll
  for (int m = 0; m < 4; ++m)
#pragma unroll
    for (int n = 0; n < 4; ++n)
#pragma unroll
      for (int e = 0; e < 4; ++e) acc[m][n][e] = 0.f;

  const bf16_t* pa[4];
  const bf16_t* pb[4];
  char* la[4];
  char* lb[4];
#pragma unroll
  for (int u = 0; u < 4; ++u) {
    int s = u * 256 + tid;
    int row = s >> 3;
    int c = (s & 7) ^ (row & 7);
    pa[u] = A + (size_t)(m0 + row) * lda + c * 8;
    pb[u] = Bt + (size_t)(n0 + row) * ldb + c * 8;
    la[u] = (char*)As + (size_t)(u * 256 + (w << 6)) * 16;
    lb[u] = (char*)Bs + (size_t)(u * 256 + (w << 6)) * 16;
  }

  const int NT = K >> 6;
  for (int t = 0; t < NT; ++t) {
    const int k0 = t << 6;
#pragma unroll
    for (int u = 0; u < 4; ++u) gload16(pa[u] + k0, la[u]);
#pragma unroll
    for (int u = 0; u < 4; ++u) gload16(pb[u] + k0, lb[u]);
    __syncthreads();

#pragma unroll
    for (int kk = 0; kk < 2; ++kk) {
      bf16x8 af[4], bb[4];
#pragma unroll
      for (int m = 0; m < 4; ++m) {
        int row = wm * 64 + m * 16 + r;
        af[m] = *(const bf16x8*)&As[row * 64 +
                                    (((kk << 2) + g4) ^ (row & 7)) * 8];
      }
#pragma unroll
      for (int n = 0; n < 4; ++n) {
        int row = wn * 64 + n * 16 + r;
        bb[n] = *(const bf16x8*)&Bs[row * 64 +
                                    (((kk << 2) + g4) ^ (row & 7)) * 8];
      }
#pragma unroll
      for (int m = 0; m < 4; ++m)
#pragma unroll
        for (int n = 0; n < 4; ++n)
          acc[m][n] = __builtin_amdgcn_mfma_f32_16x16x32_bf16(af[m], bb[n],
                                                              acc[m][n], 0, 0, 0);
    }
    __syncthreads();
  }

#pragma unroll
  for (int m = 0; m < 4; ++m) {
#pragma unroll
    for (int n = 0; n < 4; ++n) {
      int col = n0 + wn * 64 + n * 16 + r;
      float bv = 0.f;
      if constexpr (EPI != 0) bv = bias[col];
#pragma unroll
      for (int j = 0; j < 4; ++j) {
        int row = m0 + wm * 64 + m * 16 + g4 * 4 + j;
        float v = acc[m][n][j];
        if constexpr (EPI == 0) {
          Cb[(size_t)row * ldc + col] = (bf16_t)v;
        } else if constexpr (EPI == 1) {
          size_t o = (size_t)row * ldc + col;
          Cf[o] += v + bv;
        } else {
          float tt = v + bv;
          float ge = 0.5f * tt * (1.f + erff(tt * 0.70710678118f));
          Cb[(size_t)row * ldc + col] = (bf16_t)ge;
        }
      }
    }
  }
}

// ======================================================================
// k_gemm3 (round-11 core): BK=32, THREE-buffer LDS, counted vmcnt(4).
// Best for SMALL grids (WO, FF2): fill-starved, needs in-block pipeline.
// ======================================================================
template <int EPI>
__global__ __launch_bounds__(256) void k_gemm3(
    const bf16_t* __restrict__ A, int lda, const bf16_t* __restrict__ Bt,
    int ldb, int K, float* __restrict__ Cf, bf16_t* __restrict__ Cb, int ldc,
    const float* __restrict__ bias, int gx) {
  __shared__ __attribute__((aligned(16))) bf16_t As[3][128 * 32];
  __shared__ __attribute__((aligned(16))) bf16_t Bs[3][128 * 32];
  const int nwg = gridDim.x;
  const int bid = blockIdx.x;
  const int cpx = nwg >> 3;
  const int swz = (bid & 7) * cpx + (bid >> 3);
  const int bx = swz % gx, by = swz / gx;
  const int m0 = by << 7, n0 = bx << 7;
  const int tid = threadIdx.x;
  const int lane = tid & 63, w = tid >> 6;
  const int wm = w >> 1, wn = w & 1;
  const int r = lane & 15, g4 = lane >> 4;

  f32x4 acc[4][4];
#pragma unroll
  for (int m = 0; m < 4; ++m)
#pragma unroll
    for (int n = 0; n < 4; ++n)
#pragma unroll
      for (int e = 0; e < 4; ++e) acc[m][n][e] = 0.f;

  const bf16_t* pa[2];
  const bf16_t* pb[2];
  uint32_t lo[2];
#pragma unroll
  for (int u = 0; u < 2; ++u) {
    int s = u * 256 + tid;
    int row = s >> 2;
    int c = (s & 3) ^ ((row >> 1) & 3);
    pa[u] = A + (size_t)(m0 + row) * lda + c * 8;
    pb[u] = Bt + (size_t)(n0 + row) * ldb + c * 8;
    lo[u] = (uint32_t)(u * 256 + (w << 6)) * 16;
  }

  const int NT = K >> 5;
  auto STAGE = [&](int t, int bufi) {
    int k0 = (t < NT ? t : NT - 1) << 5;
#pragma unroll
    for (int u = 0; u < 2; ++u) gload16(pa[u] + k0, (char*)&As[bufi][0] + lo[u]);
#pragma unroll
    for (int u = 0; u < 2; ++u) gload16(pb[u] + k0, (char*)&Bs[bufi][0] + lo[u]);
  };

  STAGE(0, 0);
  STAGE(1, 1);
  int bi = 0, si = 2;
  const int co = (g4 ^ ((r >> 1) & 3)) << 3;
  for (int t = 0; t < NT; ++t) {
    asm volatile("s_waitcnt vmcnt(4)" ::: "memory");
    asm volatile("s_barrier" ::: "memory");
    bf16x8 af[4], bb[4];
#pragma unroll
    for (int m = 0; m < 4; ++m) {
      int row = wm * 64 + m * 16 + r;
      af[m] = *(const bf16x8*)&As[bi][row * 32 + co];
    }
#pragma unroll
    for (int n = 0; n < 4; ++n) {
      int row = wn * 64 + n * 16 + r;
      bb[n] = *(const bf16x8*)&Bs[bi][row * 32 + co];
    }
#pragma unroll
    for (int m = 0; m < 4; ++m)
#pragma unroll
      for (int n = 0; n < 4; ++n)
        acc[m][n] = __builtin_amdgcn_mfma_f32_16x16x32_bf16(af[m], bb[n],
                                                            acc[m][n], 0, 0, 0);
    asm volatile("s_barrier" ::: "memory");
    STAGE(t + 2, si);
    si = bi;
    bi = (bi == 2) ? 0 : bi + 1;
  }
  asm volatile("s_waitcnt vmcnt(0)" ::: "memory");

#pragma unroll
  for (int m = 0; m < 4; ++m) {
#pragma unroll
    for (int n = 0; n < 4; ++n) {
      int col = n0 + wn * 64 + n * 16 + r;
      float bv = 0.f;
      if constexpr (EPI != 0) bv = bias[col];
#pragma unroll
      for (int j = 0; j < 4; ++j) {
        int row = m0 + wm * 64 + m * 16 + g4 * 4 + j;
        float v = acc[m][n][j];
        if constexpr (EPI == 0) {
          Cb[(size_t)row * ldc + col] = (bf16_t)v;
        } else if constexpr (EPI == 1) {
          size_t o = (size_t)row * ldc + col;
          Cf[o] += v + bv;
        } else {
          float tt = v + bv;
          float ge = 0.5f * tt * (1.f + erff(tt * 0.70710678118f));
          Cb[(size_t)row * ldc + col] = (bf16_t)ge;
        }
      }
    }
  }
}

// ======================================================================
// Fused attention (log-softmax decomposition), one block per (b,h),
// 512 threads (8 waves):
//   1. stage K[512][64] once (XOR-swizzled, resident)
//   2. stream V tiles -> M = K^T V / 8 (wave owns 8 e2 cols) + sumv
//   3. 4 double-buffered 128-row Q chunks: QK^T (MFMA) -> lse in-register
//      -> ctx = Q*Mt - lse (x) sumv -> store
// LDS: 64 + 32 + 32 + 8 + 2.3 KB = ~138 KB (1 block/CU, 8 waves)
// ======================================================================
__global__ __launch_bounds__(512) void k_attn(const bf16_t* __restrict__ qkv,
                                              bf16_t* __restrict__ ctx) {
  __shared__ __attribute__((aligned(16))) bf16_t Ks[512 * 64];    // swizzled
  __shared__ __attribute__((aligned(16))) float Vs[128 * 64];
  __shared__ __attribute__((aligned(16))) bf16_t Qs[2][128 * 64]; // swizzled
  __shared__ __attribute__((aligned(16))) bf16_t Mt[64 * 64];     // swizzled
  __shared__ float svp[8 * 64];
  __shared__ float svs[64];

  int bh = blockIdx.x;
  int b = bh / 12, hh = bh % 12;
  int tid = threadIdx.x, lane = tid & 63, w = tid >> 6;   // 8 waves
  int r = lane & 15, g4 = lane >> 4;
  const bf16_t* qb = qkv + (size_t)b * 512 * 2304 + hh * 64;
  const bf16_t* kb = qb + 768;
  const bf16_t* vb = qb + 1536;

  // stage full K (swizzled): 4096 16B slots over 512 threads
#pragma unroll
  for (int i = 0; i < 8; ++i) {
    int s = i * 512 + tid;
    int row = s >> 3;
    int c = (s & 7) ^ (row & 7);
    gload16(kb + (size_t)row * 2304 + c * 8,
            (char*)Ks + (size_t)(i * 512 + (w << 6)) * 16);
  }

  // ---- phase 1: M = K^T V / 8 (lane owns e1; wave owns 8 e2 cols) ----
  f32x4 macc[2];
#pragma unroll
  for (int jj = 0; jj < 2; ++jj)
#pragma unroll
    for (int e = 0; e < 4; ++e) macc[jj][e] = 0.f;
  float svacc = 0.f;
  const int e1hi = (lane >> 3), e1lo = (lane & 7);

  for (int t0 = 0; t0 < 512; t0 += 128) {
    // stage V tile: 1024 16B src chunks over 512 threads
#pragma unroll
    for (int i = 0; i < 2; ++i) {
      int cs = i * 512 + tid;
      int row = cs >> 3, col = (cs & 7) * 8;
      bf16x8 raw = *(const bf16x8*)(vb + (size_t)(t0 + row) * 2304 + col);
      f32x4 v0, v1;
#pragma unroll
      for (int u = 0; u < 4; ++u) { v0[u] = (float)raw[u]; v1[u] = (float)raw[u + 4]; }
      *(f32x4*)&Vs[row * 64 + col] = v0;
      *(f32x4*)&Vs[row * 64 + col + 4] = v1;
    }
    __syncthreads();          // V tile ready (and Ks on first iter)
    for (int tt = 0; tt < 128; ++tt) {
      int t = t0 + tt;
      float kv = (float)Ks[t * 64 + (((e1hi ^ (t & 7)) << 3) | e1lo)];
#pragma unroll
      for (int jj = 0; jj < 2; ++jj) {
        f32x4 vv = *(const f32x4*)&Vs[tt * 64 + w * 8 + jj * 4];
        macc[jj] += kv * vv;
      }
    }
    // per-wave sumv partial: wave w sums rows [w*16, w*16+16)
    for (int q = 0; q < 16; ++q)
      svacc += Vs[((w << 4) + q) * 64 + lane];
    __syncthreads();          // done reading before next tile overwrite
  }

  // write Mt (transposed, bf16, swizzled): Mt[e2][e1] = M[e1][e2]*0.125
#pragma unroll
  for (int jj = 0; jj < 2; ++jj)
#pragma unroll
    for (int u = 0; u < 4; ++u) {
      int e2 = w * 8 + jj * 4 + u;
      Mt[e2 * 64 + (((e1hi ^ (e2 & 7)) << 3) | e1lo)] =
          (bf16_t)(macc[jj][u] * 0.125f);
    }
  svp[w * 64 + lane] = svacc;
  __syncthreads();
  if (w == 0) {
    float s = 0.f;
#pragma unroll
    for (int u = 0; u < 8; ++u) s += svp[u * 64 + lane];
    svs[lane] = s;
  }

  // ---- phase 2: per 128-row Q chunk: QK^T -> lse -> ctx ----
  auto stageQ = [&](int qc, int bufi) {
#pragma unroll
    for (int u = 0; u < 2; ++u) {
      int s = u * 512 + tid;
      int row = s >> 3;
      int c = (s & 7) ^ (row & 7);
      gload16(qb + (size_t)(qc * 128 + row) * 2304 + c * 8,
              (char*)&Qs[bufi][0] + (size_t)(u * 512 + (w << 6)) * 16);
    }
  };
  stageQ(0, 0);
  const int arow = w * 16 + r;

  for (int qc = 0; qc < 4; ++qc) {
    __syncthreads();          // Q(qc) ready; svs visible (qc=0); prev reads done
    if (qc < 3) stageQ(qc + 1, (qc + 1) & 1);
    const bf16_t* Qb = &Qs[qc & 1][0];

    f32x4 acc2[32];
#pragma unroll
    for (int n = 0; n < 32; ++n)
#pragma unroll
      for (int e = 0; e < 4; ++e) acc2[n][e] = 0.f;

#pragma unroll
    for (int kk = 0; kk < 2; ++kk) {
      bf16x8 aq = *(const bf16x8*)&Qb[arow * 64 +
                                      (((kk << 2) + g4) ^ (arow & 7)) * 8];
#pragma unroll
      for (int n = 0; n < 32; ++n) {
        int krow = n * 16 + r;
        bf16x8 bk = *(const bf16x8*)&Ks[krow * 64 +
                                        (((kk << 2) + g4) ^ (krow & 7)) * 8];
        acc2[n] = __builtin_amdgcn_mfma_f32_16x16x32_bf16(aq, bk, acc2[n], 0, 0, 0);
      }
    }

    float lse_j[4];
#pragma unroll
    for (int j = 0; j < 4; ++j) {
      float mx = -1e30f;
#pragma unroll
      for (int n = 0; n < 32; ++n) mx = fmaxf(mx, acc2[n][j] * 0.125f);
#pragma unroll
      for (int o = 1; o < 16; o <<= 1) mx = fmaxf(mx, __shfl_xor(mx, o, 64));
      float sm = 0.f;
#pragma unroll
      for (int n = 0; n < 32; ++n) sm += expf(acc2[n][j] * 0.125f - mx);
#pragma unroll
      for (int o = 1; o < 16; o <<= 1) sm += __shfl_xor(sm, o, 64);
      lse_j[j] = mx + logf(sm);
    }

    f32x4 acc3[4];
#pragma unroll
    for (int n = 0; n < 4; ++n)
#pragma unroll
      for (int e = 0; e < 4; ++e) acc3[n][e] = 0.f;
#pragma unroll
    for (int kk = 0; kk < 2; ++kk) {
      bf16x8 aq = *(const bf16x8*)&Qb[arow * 64 +
                                      (((kk << 2) + g4) ^ (arow & 7)) * 8];
#pragma unroll
      for (int n2 = 0; n2 < 4; ++n2) {
        int mrow = n2 * 16 + r;
        bf16x8 bm = *(const bf16x8*)&Mt[mrow * 64 +
                                        (((kk << 2) + g4) ^ (mrow & 7)) * 8];
        acc3[n2] = __builtin_amdgcn_mfma_f32_16x16x32_bf16(aq, bm, acc3[n2], 0, 0, 0);
      }
    }
#pragma unroll
    for (int n2 = 0; n2 < 4; ++n2) {
      int col = n2 * 16 + r;
      float svv = svs[col];
#pragma unroll
      for (int j = 0; j < 4; ++j) {
        int srow = qc * 128 + w * 16 + g4 * 4 + j;
        ctx[((size_t)(b * 512 + srow)) * 768 + hh * 64 + col] =
            (bf16_t)(acc3[n2][j] - lse_j[j] * svv);
      }
    }
  }
}

// ---- final LN (row s=0 per batch) + classifier ----
__global__ __launch_bounds__(192) void k_final(
    const float* __restrict__ x, const float* __restrict__ gam,
    const float* __restrict__ bet, const float* __restrict__ cw,
    const float* __restrict__ cb, float* __restrict__ out) {
  __shared__ float red[3];
  int b = blockIdx.x, t = threadIdx.x;
  const float* xr = x + (size_t)b * 512 * 768;
  const float4 xv = *(const float4*)&xr[t * 4];
  float v[4] = {xv.x, xv.y, xv.z, xv.w};
  float tot = bsum3(v[0] + v[1] + v[2] + v[3], red);
  float mu = tot * (1.f / 768.f);
  float sq = 0.f;
#pragma unroll
  for (int u = 0; u < 4; ++u) { float d = v[u] - mu; sq += d * d; }
  float var = bsum3(sq, red) * (1.f / 768.f);
  float rstd = rsqrtf(var + 1e-5f);
  const float4 g4 = *(const float4*)&gam[t * 4];
  const float4 b4 = *(const float4*)&bet[t * 4];
  float nv[4];
  nv[0] = (v[0] - mu) * rstd * g4.x + b4.x;
  nv[1] = (v[1] - mu) * rstd * g4.y + b4.y;
  nv[2] = (v[2] - mu) * rstd * g4.z + b4.z;
  nv[3] = (v[3] - mu) * rstd * g4.w + b4.w;
  const float4 wa = *(const float4*)&cw[t * 8];
  const float4 wb = *(const float4*)&cw[t * 8 + 4];
  float d0 = nv[0] * wa.x + nv[1] * wa.z + nv[2] * wb.x + nv[3] * wb.z;
  float d1 = nv[0] * wa.y + nv[1] * wa.w + nv[2] * wb.y + nv[3] * wb.w;
  d0 = bsum3(d0, red);
  d1 = bsum3(d1, red);
  if (t == 0) {
    out[b * 2 + 0] = d0 + cb[0];
    out[b * 2 + 1] = d1 + cb[1];
  }
}

// ---- workspace layout ----
static constexpr size_t OFF_X = 0;                                  // f32 8192x768
static constexpr size_t OFF_H = OFF_X + 8192ull * 768 * 4;          // bf16 8192x768
static constexpr size_t OFF_QG = OFF_H + 8192ull * 768 * 2;         // bf16 arena (qkv | gelu)
static constexpr size_t OFF_CTX = OFF_QG + 8192ull * 3072 * 2;      // bf16 8192x768
static constexpr size_t OFF_LSE = OFF_CTX + 8192ull * 768 * 2;      // f32 (unused)
static constexpr size_t OFF_W = OFF_LSE + 192ull * 512 * 4;         // bf16 weights
static constexpr size_t WPL = 7077888;                              // elems per layer
static constexpr size_t WS_SMALL = OFF_W + WPL * 2;                 // 1-layer buffer
static constexpr size_t WS_BIG = OFF_W + 12ull * WPL * 2;           // all layers

extern "C" void kernel_launch(void* const* d_in, const int* in_sizes, int n_in,
                              void* d_out, int out_size, void* d_ws,
                              size_t ws_size, hipStream_t stream) {
  const int* ids = (const int*)d_in[0];
  const float* tok = (const float*)d_in[1];
  const float* pos = (const float*)d_in[2];
  const float* eln_s = (const float*)d_in[3];
  const float* eln_b = (const float*)d_in[4];
  const float* wq = (const float*)d_in[5];
  const float* wk = (const float*)d_in[6];
  const float* wv = (const float*)d_in[7];
  const float* wo = (const float*)d_in[8];
  const float* wo_b = (const float*)d_in[9];
  const float* ln1_s = (const float*)d_in[10];
  const float* ln1_b = (const float*)d_in[11];
  const float* ln2_s = (const float*)d_in[12];
  const float* ln2_b = (const float*)d_in[13];
  const float* ff1w = (const float*)d_in[14];
  const float* ff1b = (const float*)d_in[15];
  const float* ff2w = (const float*)d_in[16];
  const float* ff2b = (const float*)d_in[17];
  const float* fln_s = (const float*)d_in[18];
  const float* fln_b = (const float*)d_in[19];
  const float* cw = (const float*)d_in[20];
  const float* cb = (const float*)d_in[21];
  float* out = (float*)d_out;

  if (ws_size < WS_SMALL) return;
  const bool big = ws_size >= WS_BIG;

  char* ws = (char*)d_ws;
  float* x = (float*)(ws + OFF_X);
  bf16_t* h = (bf16_t*)(ws + OFF_H);
  bf16_t* qkv = (bf16_t*)(ws + OFF_QG);
  bf16_t* gbuf = (bf16_t*)(ws + OFF_QG);
  bf16_t* ctx = (bf16_t*)(ws + OFF_CTX);
  bf16_t* wT = (bf16_t*)(ws + OFF_W);

  // embedding + emb-LN + ln1(layer0)
  k_embed<<<8192, 192, 0, stream>>>(ids, tok, pos, eln_s, eln_b,
                                    ln1_s, ln1_b, x, h);

  if (big) {
    // convert ALL layers' weights upfront: 4 launches
    k_convT3<<<dim3(2, 24, 432), 256, 0, stream>>>(wq, wk, wv, wT,
                                                   589824, WPL);
    k_convT<<<dim3(24, 24, 12), 256, 0, stream>>>(wo, 589824,
                                                  wT + 1769472, WPL, 768, 768);
    k_convT<<<dim3(96, 24, 12), 256, 0, stream>>>(ff1w, 2359296,
                                                  wT + 2359296, WPL, 3072, 768);
    k_convT<<<dim3(24, 96, 12), 256, 0, stream>>>(ff2w, 2359296,
                                                  wT + 4718592, WPL, 768, 3072);
  }

  for (int l = 0; l < 12; ++l) {
    bf16_t* wl = big ? wT + (size_t)l * WPL : wT;
    bf16_t* qkvT = wl;
    bf16_t* woT = wl + 1769472;
    bf16_t* ff1T = wl + 2359296;
    bf16_t* ff2T = wl + 4718592;

    if (l > 0)
      k_ln<<<2048, 256, 0, stream>>>(x, h, ln1_s + l * 768, ln1_b + l * 768);
    if (!big) {
      k_convT3<<<dim3(2, 24, 36), 256, 0, stream>>>(
          wq + (size_t)l * 589824, wk + (size_t)l * 589824,
          wv + (size_t)l * 589824, qkvT, 589824, 0);
      k_convT<<<dim3(24, 24, 1), 256, 0, stream>>>(wo + (size_t)l * 589824, 0,
                                                   woT, 0, 768, 768);
      k_convT<<<dim3(96, 24, 1), 256, 0, stream>>>(ff1w + (size_t)l * 2359296,
                                                   0, ff1T, 0, 3072, 768);
      k_convT<<<dim3(24, 96, 1), 256, 0, stream>>>(ff2w + (size_t)l * 2359296,
                                                   0, ff2T, 0, 768, 3072);
    }
    // QKV: M=8192 N=2304 K=768 -> grid 1152 (large: single-buf core)
    k_gemm1<0><<<1152, 256, 0, stream>>>(h, 768, qkvT, 768, 768,
                                         nullptr, qkv, 2304, nullptr, 18);
    // fused attention (log-softmax decomposition), 8 waves/block
    k_attn<<<192, 512, 0, stream>>>(qkv, ctx);
    // WO + residual: grid 384 (small: pipelined 3-buf core)
    k_gemm3<1><<<384, 256, 0, stream>>>(ctx, 768, woT, 768, 768, x,
                                        nullptr, 768, wo_b + l * 768, 6);
    // FFN
    k_ln<<<2048, 256, 0, stream>>>(x, h, ln2_s + l * 768, ln2_b + l * 768);
    // FF1: grid 1536 (large: single-buf core)
    k_gemm1<2><<<1536, 256, 0, stream>>>(h, 768, ff1T, 768, 768,
                                         nullptr, gbuf, 3072,
                                         ff1b + l * 3072, 24);
    // FF2: grid 384 (small: pipelined 3-buf core)
    k_gemm3<1><<<384, 256, 0, stream>>>(gbuf, 3072, ff2T, 3072, 3072, x,
                                        nullptr, 768, ff2b + l * 768, 6);
  }
  k_final<<<16, 192, 0, stream>>>(x, fln_s, fln_b, cw, cb, out);
}

// Round 16
// 3432.567 us; speedup vs baseline: 1.2446x; 1.0606x over previous
//
#include <hip/hip_runtime.h>
#include <hip/hip_bf16.h>
#include <math.h>

// Dims: B=16 S=512 D=768 H=12 DH=64 F=3072 LYR=12 NLAB=2; rows = B*S = 8192
typedef __bf16 bf16_t;
typedef __attribute__((ext_vector_type(8))) __bf16 bf16x8;
typedef __attribute__((ext_vector_type(4))) float f32x4;

typedef const __attribute__((address_space(1))) void av1_void;
typedef __attribute__((address_space(3))) void av3_void;

#define DEV static __device__ __forceinline__

DEV void gload16(const void* g, void* l) {
  __builtin_amdgcn_global_load_lds((av1_void*)g, (av3_void*)l, 16, 0, 0);
}

// ---- block reduction over 3 waves (block=192) ----
DEV float bsum3(float v, float* red) {
#pragma unroll
  for (int o = 32; o > 0; o >>= 1) v += __shfl_xor(v, o, 64);
  __syncthreads();
  if ((threadIdx.x & 63) == 0) red[threadIdx.x >> 6] = v;
  __syncthreads();
  return red[0] + red[1] + red[2];
}

// ---- embedding gather + emb-LN -> x (fp32), then ln1(layer0) -> h (bf16) ----
__global__ __launch_bounds__(192) void k_embed(
    const int* __restrict__ ids, const float* __restrict__ tok,
    const float* __restrict__ pos, const float* __restrict__ gam,
    const float* __restrict__ bet, const float* __restrict__ gam2,
    const float* __restrict__ bet2, float* __restrict__ x,
    bf16_t* __restrict__ h) {
  __shared__ float red[3];
  int row = blockIdx.x;          // b*512 + s
  int s = row & 511;
  int t = threadIdx.x;
  int id = ids[row];
  const float4 tv = *(const float4*)&tok[(size_t)id * 768 + t * 4];
  const float4 pv = *(const float4*)&pos[(size_t)s * 768 + t * 4];
  float v[4] = {tv.x + pv.x, tv.y + pv.y, tv.z + pv.z, tv.w + pv.w};
  float tot = bsum3(v[0] + v[1] + v[2] + v[3], red);
  float mu = tot * (1.f / 768.f);
  float sq = 0.f;
#pragma unroll
  for (int u = 0; u < 4; ++u) { float d = v[u] - mu; sq += d * d; }
  float var = bsum3(sq, red) * (1.f / 768.f);
  float rstd = rsqrtf(var + 1e-5f);
  const float4 g4 = *(const float4*)&gam[t * 4];
  const float4 b4 = *(const float4*)&bet[t * 4];
  float o[4];
  o[0] = (v[0] - mu) * rstd * g4.x + b4.x;
  o[1] = (v[1] - mu) * rstd * g4.y + b4.y;
  o[2] = (v[2] - mu) * rstd * g4.z + b4.z;
  o[3] = (v[3] - mu) * rstd * g4.w + b4.w;
  float4 ov = {o[0], o[1], o[2], o[3]};
  *(float4*)&x[(size_t)row * 768 + t * 4] = ov;
  // second LN (ln1 of layer 0) -> h
  float tot2 = bsum3(o[0] + o[1] + o[2] + o[3], red);
  float mu2 = tot2 * (1.f / 768.f);
  float sq2 = 0.f;
#pragma unroll
  for (int u = 0; u < 4; ++u) { float d = o[u] - mu2; sq2 += d * d; }
  float var2 = bsum3(sq2, red) * (1.f / 768.f);
  float rstd2 = rsqrtf(var2 + 1e-5f);
  const float4 G = *(const float4*)&gam2[t * 4];
  const float4 Bb = *(const float4*)&bet2[t * 4];
  union { bf16_t ob[4]; uint2 u2; } pk;
  pk.ob[0] = (bf16_t)((o[0] - mu2) * rstd2 * G.x + Bb.x);
  pk.ob[1] = (bf16_t)((o[1] - mu2) * rstd2 * G.y + Bb.y);
  pk.ob[2] = (bf16_t)((o[2] - mu2) * rstd2 * G.z + Bb.z);
  pk.ob[3] = (bf16_t)((o[3] - mu2) * rstd2 * G.w + Bb.w);
  *(uint2*)&h[(size_t)row * 768 + t * 4] = pk.u2;
}

// ---- LN: x (fp32) -> h (bf16); wave-per-row, lane owns 12 cols ----
__global__ __launch_bounds__(256) void k_ln(
    const float* __restrict__ xin, bf16_t* __restrict__ hout,
    const float* __restrict__ gam, const float* __restrict__ bet) {
  int row = blockIdx.x * 4 + (threadIdx.x >> 6);
  int lane = threadIdx.x & 63;
  const float* xr = xin + (size_t)row * 768 + lane * 12;
  float4 a = *(const float4*)&xr[0];
  float4 b = *(const float4*)&xr[4];
  float4 c = *(const float4*)&xr[8];
  float v[12] = {a.x, a.y, a.z, a.w, b.x, b.y, b.z, b.w, c.x, c.y, c.z, c.w};
  float sm = 0.f;
#pragma unroll
  for (int u = 0; u < 12; ++u) sm += v[u];
#pragma unroll
  for (int o = 32; o > 0; o >>= 1) sm += __shfl_xor(sm, o, 64);
  float mu = sm * (1.f / 768.f);
  float sq = 0.f;
#pragma unroll
  for (int u = 0; u < 12; ++u) { float d = v[u] - mu; sq += d * d; }
#pragma unroll
  for (int o = 32; o > 0; o >>= 1) sq += __shfl_xor(sq, o, 64);
  float rstd = rsqrtf(sq * (1.f / 768.f) + 1e-5f);
  const float4 ga = *(const float4*)&gam[lane * 12];
  const float4 gb = *(const float4*)&gam[lane * 12 + 4];
  const float4 gc = *(const float4*)&gam[lane * 12 + 8];
  const float4 ba = *(const float4*)&bet[lane * 12];
  const float4 bb = *(const float4*)&bet[lane * 12 + 4];
  const float4 bc = *(const float4*)&bet[lane * 12 + 8];
  float g[12] = {ga.x, ga.y, ga.z, ga.w, gb.x, gb.y, gb.z, gb.w,
                 gc.x, gc.y, gc.z, gc.w};
  float be[12] = {ba.x, ba.y, ba.z, ba.w, bb.x, bb.y, bb.z, bb.w,
                  bc.x, bc.y, bc.z, bc.w};
  union { bf16_t o[12]; uint2 u2[3]; } pk;
#pragma unroll
  for (int u = 0; u < 12; ++u)
    pk.o[u] = (bf16_t)((v[u] - mu) * rstd * g[u] + be[u]);
  bf16_t* hr = hout + (size_t)row * 768 + lane * 12;
#pragma unroll
  for (int u = 0; u < 3; ++u) *(uint2*)&hr[u * 4] = pk.u2[u];
}

// ---- transpose-convert fp32 [K][N] -> bf16 [N][K], per z-slice ----
__global__ __launch_bounds__(256) void k_convT(
    const float* __restrict__ in, size_t in_slice, bf16_t* __restrict__ out,
    size_t out_slice, int N, int K) {
  __shared__ float tbuf[32][33];
  int slice = blockIdx.z;
  const float* ip = in + (size_t)slice * in_slice;
  bf16_t* op = out + (size_t)slice * out_slice;
  int n0 = blockIdx.x * 32, k0 = blockIdx.y * 32;
  int c = threadIdx.x & 31, r8 = threadIdx.x >> 5;
#pragma unroll
  for (int i = 0; i < 4; ++i) {
    int rr = r8 + i * 8;
    tbuf[rr][c] = ip[(size_t)(k0 + rr) * N + n0 + c];
  }
  __syncthreads();
#pragma unroll
  for (int i = 0; i < 4; ++i) {
    int rr = r8 + i * 8;
    op[(size_t)(n0 + rr) * K + k0 + c] = (bf16_t)tbuf[c][rr];
  }
}

// ---- fused wq/wk/wv transpose-convert, NL layers: z = l*36 + which*12 + head
__global__ __launch_bounds__(256) void k_convT3(
    const float* __restrict__ wq, const float* __restrict__ wk,
    const float* __restrict__ wv, bf16_t* __restrict__ out,
    size_t in_lstride, size_t out_lstride) {
  __shared__ float tbuf[32][33];
  int z = blockIdx.z;
  int l = z / 36, r = z % 36;
  int which = r / 12, head = r % 12;
  const float* ip = (which == 0 ? wq : which == 1 ? wk : wv) +
                    (size_t)l * in_lstride + (size_t)head * 768 * 64;
  bf16_t* op = out + (size_t)l * out_lstride + (size_t)which * 768 * 768 +
               (size_t)head * 64 * 768;
  int n0 = blockIdx.x * 32, k0 = blockIdx.y * 32;   // N=64, K=768
  int c = threadIdx.x & 31, r8 = threadIdx.x >> 5;
#pragma unroll
  for (int i = 0; i < 4; ++i) {
    int rr = r8 + i * 8;
    tbuf[rr][c] = ip[(size_t)(k0 + rr) * 64 + n0 + c];
  }
  __syncthreads();
#pragma unroll
  for (int i = 0; i < 4; ++i) {
    int rr = r8 + i * 8;
    op[(size_t)(n0 + rr) * 768 + k0 + c] = (bf16_t)tbuf[c][rr];
  }
}

// ======================================================================
// k_gemm1 (round-10 core): BK=64, SINGLE-buffered LDS (32KB -> 5
// blocks/CU). Best for LARGE grids (QKV, FF1): cross-block overlap.
// ======================================================================
template <int EPI>
__global__ __launch_bounds__(256) void k_gemm1(
    const bf16_t* __restrict__ A, int lda, const bf16_t* __restrict__ Bt,
    int ldb, int K, float* __restrict__ Cf, bf16_t* __restrict__ Cb, int ldc,
    const float* __restrict__ bias, int gx) {
  __shared__ __attribute__((aligned(16))) bf16_t As[128 * 64];
  __shared__ __attribute__((aligned(16))) bf16_t Bs[128 * 64];
  const int nwg = gridDim.x;
  const int bid = blockIdx.x;
  const int cpx = nwg >> 3;
  const int swz = (bid & 7) * cpx + (bid >> 3);
  const int bx = swz % gx, by = swz / gx;
  const int m0 = by << 7, n0 = bx << 7;
  const int tid = threadIdx.x;
  const int lane = tid & 63, w = tid >> 6;
  const int wm = w >> 1, wn = w & 1;
  const int r = lane & 15, g4 = lane >> 4;

  f32x4 acc[4][4];
#pragma unroll
  for (int m = 0; m < 4; ++m)
#pragma unroll
    for (int n = 0; n < 4; ++n)
#pragma unroll
      for (int e = 0; e < 4; ++e) acc[m][n][e] = 0.f;

  const bf16_t* pa[4];
  const bf16_t* pb[4];
  char* la[4];
  char* lb[4];
#pragma unroll
  for (int u = 0; u < 4; ++u) {
    int s = u * 256 + tid;
    int row = s >> 3;
    int c = (s & 7) ^ (row & 7);
    pa[u] = A + (size_t)(m0 + row) * lda + c * 8;
    pb[u] = Bt + (size_t)(n0 + row) * ldb + c * 8;
    la[u] = (char*)As + (size_t)(u * 256 + (w << 6)) * 16;
    lb[u] = (char*)Bs + (size_t)(u * 256 + (w << 6)) * 16;
  }

  const int NT = K >> 6;
  for (int t = 0; t < NT; ++t) {
    const int k0 = t << 6;
#pragma unroll
    for (int u = 0; u < 4; ++u) gload16(pa[u] + k0, la[u]);
#pragma unroll
    for (int u = 0; u < 4; ++u) gload16(pb[u] + k0, lb[u]);
    __syncthreads();

#pragma unroll
    for (int kk = 0; kk < 2; ++kk) {
      bf16x8 af[4], bb[4];
#pragma unroll
      for (int m = 0; m < 4; ++m) {
        int row = wm * 64 + m * 16 + r;
        af[m] = *(const bf16x8*)&As[row * 64 +
                                    (((kk << 2) + g4) ^ (row & 7)) * 8];
      }
#pragma unroll
      for (int n = 0; n < 4; ++n) {
        int row = wn * 64 + n * 16 + r;
        bb[n] = *(const bf16x8*)&Bs[row * 64 +
                                    (((kk << 2) + g4) ^ (row & 7)) * 8];
      }
#pragma unroll
      for (int m = 0; m < 4; ++m)
#pragma unroll
        for (int n = 0; n < 4; ++n)
          acc[m][n] = __builtin_amdgcn_mfma_f32_16x16x32_bf16(af[m], bb[n],
                                                              acc[m][n], 0, 0, 0);
    }
    __syncthreads();
  }

#pragma unroll
  for (int m = 0; m < 4; ++m) {
#pragma unroll
    for (int n = 0; n < 4; ++n) {
      int col = n0 + wn * 64 + n * 16 + r;
      float bv = 0.f;
      if constexpr (EPI != 0) bv = bias[col];
#pragma unroll
      for (int j = 0; j < 4; ++j) {
        int row = m0 + wm * 64 + m * 16 + g4 * 4 + j;
        float v = acc[m][n][j];
        if constexpr (EPI == 0) {
          Cb[(size_t)row * ldc + col] = (bf16_t)v;
        } else if constexpr (EPI == 1) {
          size_t o = (size_t)row * ldc + col;
          Cf[o] += v + bv;
        } else {
          float tt = v + bv;
          float ge = 0.5f * tt * (1.f + erff(tt * 0.70710678118f));
          Cb[(size_t)row * ldc + col] = (bf16_t)ge;
        }
      }
    }
  }
}

// ======================================================================
// k_gemm3 (round-11 core): BK=32, THREE-buffer LDS, counted vmcnt(4).
// Best for SMALL grids (WO, FF2): fill-starved, needs in-block pipeline.
// ======================================================================
template <int EPI>
__global__ __launch_bounds__(256) void k_gemm3(
    const bf16_t* __restrict__ A, int lda, const bf16_t* __restrict__ Bt,
    int ldb, int K, float* __restrict__ Cf, bf16_t* __restrict__ Cb, int ldc,
    const float* __restrict__ bias, int gx) {
  __shared__ __attribute__((aligned(16))) bf16_t As[3][128 * 32];
  __shared__ __attribute__((aligned(16))) bf16_t Bs[3][128 * 32];
  const int nwg = gridDim.x;
  const int bid = blockIdx.x;
  const int cpx = nwg >> 3;
  const int swz = (bid & 7) * cpx + (bid >> 3);
  const int bx = swz % gx, by = swz / gx;
  const int m0 = by << 7, n0 = bx << 7;
  const int tid = threadIdx.x;
  const int lane = tid & 63, w = tid >> 6;
  const int wm = w >> 1, wn = w & 1;
  const int r = lane & 15, g4 = lane >> 4;

  f32x4 acc[4][4];
#pragma unroll
  for (int m = 0; m < 4; ++m)
#pragma unroll
    for (int n = 0; n < 4; ++n)
#pragma unroll
      for (int e = 0; e < 4; ++e) acc[m][n][e] = 0.f;

  const bf16_t* pa[2];
  const bf16_t* pb[2];
  uint32_t lo[2];
#pragma unroll
  for (int u = 0; u < 2; ++u) {
    int s = u * 256 + tid;
    int row = s >> 2;
    int c = (s & 3) ^ ((row >> 1) & 3);
    pa[u] = A + (size_t)(m0 + row) * lda + c * 8;
    pb[u] = Bt + (size_t)(n0 + row) * ldb + c * 8;
    lo[u] = (uint32_t)(u * 256 + (w << 6)) * 16;
  }

  const int NT = K >> 5;
  auto STAGE = [&](int t, int bufi) {
    int k0 = (t < NT ? t : NT - 1) << 5;
#pragma unroll
    for (int u = 0; u < 2; ++u) gload16(pa[u] + k0, (char*)&As[bufi][0] + lo[u]);
#pragma unroll
    for (int u = 0; u < 2; ++u) gload16(pb[u] + k0, (char*)&Bs[bufi][0] + lo[u]);
  };

  STAGE(0, 0);
  STAGE(1, 1);
  int bi = 0, si = 2;
  const int co = (g4 ^ ((r >> 1) & 3)) << 3;
  for (int t = 0; t < NT; ++t) {
    asm volatile("s_waitcnt vmcnt(4)" ::: "memory");
    asm volatile("s_barrier" ::: "memory");
    bf16x8 af[4], bb[4];
#pragma unroll
    for (int m = 0; m < 4; ++m) {
      int row = wm * 64 + m * 16 + r;
      af[m] = *(const bf16x8*)&As[bi][row * 32 + co];
    }
#pragma unroll
    for (int n = 0; n < 4; ++n) {
      int row = wn * 64 + n * 16 + r;
      bb[n] = *(const bf16x8*)&Bs[bi][row * 32 + co];
    }
#pragma unroll
    for (int m = 0; m < 4; ++m)
#pragma unroll
      for (int n = 0; n < 4; ++n)
        acc[m][n] = __builtin_amdgcn_mfma_f32_16x16x32_bf16(af[m], bb[n],
                                                            acc[m][n], 0, 0, 0);
    asm volatile("s_barrier" ::: "memory");
    STAGE(t + 2, si);
    si = bi;
    bi = (bi == 2) ? 0 : bi + 1;
  }
  asm volatile("s_waitcnt vmcnt(0)" ::: "memory");

#pragma unroll
  for (int m = 0; m < 4; ++m) {
#pragma unroll
    for (int n = 0; n < 4; ++n) {
      int col = n0 + wn * 64 + n * 16 + r;
      float bv = 0.f;
      if constexpr (EPI != 0) bv = bias[col];
#pragma unroll
      for (int j = 0; j < 4; ++j) {
        int row = m0 + wm * 64 + m * 16 + g4 * 4 + j;
        float v = acc[m][n][j];
        if constexpr (EPI == 0) {
          Cb[(size_t)row * ldc + col] = (bf16_t)v;
        } else if constexpr (EPI == 1) {
          size_t o = (size_t)row * ldc + col;
          Cf[o] += v + bv;
        } else {
          float tt = v + bv;
          float ge = 0.5f * tt * (1.f + erff(tt * 0.70710678118f));
          Cb[(size_t)row * ldc + col] = (bf16_t)ge;
        }
      }
    }
  }
}

// ======================================================================
// Fused attention (log-softmax decomposition), one block per (b,h),
// 512 threads (8 waves):
//   1. stage K[512][64] once (XOR-swizzled, resident)
//   2. stream V tiles (register-prefetched, T14 async-split) ->
//      M = K^T V / 8 (unrolled scalar FMA) + per-wave sumv
//   3. 4 double-buffered 128-row Q chunks: QK^T (MFMA) -> lse in-register
//      (fast __expf/__logf) -> ctx = Q*Mt - lse (x) sumv -> store
// LDS: 64 + 32 + 32 + 8 + 2.3 KB = ~138 KB (1 block/CU, 8 waves)
// ======================================================================
__global__ __launch_bounds__(512) void k_attn(const bf16_t* __restrict__ qkv,
                                              bf16_t* __restrict__ ctx) {
  __shared__ __attribute__((aligned(16))) bf16_t Ks[512 * 64];    // swizzled
  __shared__ __attribute__((aligned(16))) float Vs[128 * 64];
  __shared__ __attribute__((aligned(16))) bf16_t Qs[2][128 * 64]; // swizzled
  __shared__ __attribute__((aligned(16))) bf16_t Mt[64 * 64];     // swizzled
  __shared__ float svp[8 * 64];
  __shared__ float svs[64];

  int bh = blockIdx.x;
  int b = bh / 12, hh = bh % 12;
  int tid = threadIdx.x, lane = tid & 63, w = tid >> 6;   // 8 waves
  int r = lane & 15, g4 = lane >> 4;
  const bf16_t* qb = qkv + (size_t)b * 512 * 2304 + hh * 64;
  const bf16_t* kb = qb + 768;
  const bf16_t* vb = qb + 1536;

  // stage full K (swizzled): 4096 16B slots over 512 threads
#pragma unroll
  for (int i = 0; i < 8; ++i) {
    int s = i * 512 + tid;
    int row = s >> 3;
    int c = (s & 7) ^ (row & 7);
    gload16(kb + (size_t)row * 2304 + c * 8,
            (char*)Ks + (size_t)(i * 512 + (w << 6)) * 16);
  }

  // ---- phase 1: M = K^T V / 8 (lane owns e1; wave owns 8 e2 cols) ----
  f32x4 macc[2];
#pragma unroll
  for (int jj = 0; jj < 2; ++jj)
#pragma unroll
    for (int e = 0; e < 4; ++e) macc[jj][e] = 0.f;
  float svacc = 0.f;
  const int e1hi = (lane >> 3), e1lo = (lane & 7);

  // register-prefetched V tile staging (T14 async-split)
  bf16x8 vreg[2];
  auto ldV = [&](int t0) {
#pragma unroll
    for (int i = 0; i < 2; ++i) {
      int cs = i * 512 + tid;
      int row = cs >> 3, col = (cs & 7) * 8;
      vreg[i] = *(const bf16x8*)(vb + (size_t)(t0 + row) * 2304 + col);
    }
  };
  auto wrV = [&]() {
#pragma unroll
    for (int i = 0; i < 2; ++i) {
      int cs = i * 512 + tid;
      int row = cs >> 3, col = (cs & 7) * 8;
      f32x4 v0, v1;
#pragma unroll
      for (int u = 0; u < 4; ++u) {
        v0[u] = (float)vreg[i][u];
        v1[u] = (float)vreg[i][u + 4];
      }
      *(f32x4*)&Vs[row * 64 + col] = v0;
      *(f32x4*)&Vs[row * 64 + col + 4] = v1;
    }
  };

  ldV(0);
  wrV();
  __syncthreads();              // V tile 0 + Ks ready

  for (int t0 = 0; t0 < 4; ++t0) {
    if (t0 < 3) ldV((t0 + 1) * 128);   // in flight during compute
#pragma unroll 8
    for (int tt = 0; tt < 128; ++tt) {
      int t = t0 * 128 + tt;
      float kv = (float)Ks[t * 64 + (((e1hi ^ (t & 7)) << 3) | e1lo)];
#pragma unroll
      for (int jj = 0; jj < 2; ++jj) {
        f32x4 vv = *(const f32x4*)&Vs[tt * 64 + w * 8 + jj * 4];
        macc[jj] += kv * vv;
      }
    }
    // per-wave sumv partial: wave w sums rows [w*16, w*16+16)
#pragma unroll
    for (int q = 0; q < 16; ++q)
      svacc += Vs[((w << 4) + q) * 64 + lane];
    __syncthreads();            // done reading before overwrite
    if (t0 < 3) {
      wrV();
      __syncthreads();          // next V tile ready
    }
  }

  // write Mt (transposed, bf16, swizzled): Mt[e2][e1] = M[e1][e2]*0.125
#pragma unroll
  for (int jj = 0; jj < 2; ++jj)
#pragma unroll
    for (int u = 0; u < 4; ++u) {
      int e2 = w * 8 + jj * 4 + u;
      Mt[e2 * 64 + (((e1hi ^ (e2 & 7)) << 3) | e1lo)] =
          (bf16_t)(macc[jj][u] * 0.125f);
    }
  svp[w * 64 + lane] = svacc;
  __syncthreads();
  if (w == 0) {
    float s = 0.f;
#pragma unroll
    for (int u = 0; u < 8; ++u) s += svp[u * 64 + lane];
    svs[lane] = s;
  }

  // ---- phase 2: per 128-row Q chunk: QK^T -> lse -> ctx ----
  auto stageQ = [&](int qc, int bufi) {
#pragma unroll
    for (int u = 0; u < 2; ++u) {
      int s = u * 512 + tid;
      int row = s >> 3;
      int c = (s & 7) ^ (row & 7);
      gload16(qb + (size_t)(qc * 128 + row) * 2304 + c * 8,
              (char*)&Qs[bufi][0] + (size_t)(u * 512 + (w << 6)) * 16);
    }
  };
  stageQ(0, 0);
  const int arow = w * 16 + r;

  for (int qc = 0; qc < 4; ++qc) {
    __syncthreads();            // Q(qc) ready; svs visible; prev reads done
    if (qc < 3) stageQ(qc + 1, (qc + 1) & 1);
    const bf16_t* Qb = &Qs[qc & 1][0];

    f32x4 acc2[32];
#pragma unroll
    for (int n = 0; n < 32; ++n)
#pragma unroll
      for (int e = 0; e < 4; ++e) acc2[n][e] = 0.f;

#pragma unroll
    for (int kk = 0; kk < 2; ++kk) {
      bf16x8 aq = *(const bf16x8*)&Qb[arow * 64 +
                                      (((kk << 2) + g4) ^ (arow & 7)) * 8];
#pragma unroll
      for (int n = 0; n < 32; ++n) {
        int krow = n * 16 + r;
        bf16x8 bk = *(const bf16x8*)&Ks[krow * 64 +
                                        (((kk << 2) + g4) ^ (krow & 7)) * 8];
        acc2[n] = __builtin_amdgcn_mfma_f32_16x16x32_bf16(aq, bk, acc2[n], 0, 0, 0);
      }
    }

    float lse_j[4];
#pragma unroll
    for (int j = 0; j < 4; ++j) {
      float mx = -1e30f;
#pragma unroll
      for (int n = 0; n < 32; ++n) mx = fmaxf(mx, acc2[n][j] * 0.125f);
#pragma unroll
      for (int o = 1; o < 16; o <<= 1) mx = fmaxf(mx, __shfl_xor(mx, o, 64));
      float sm = 0.f;
#pragma unroll
      for (int n = 0; n < 32; ++n) sm += __expf(acc2[n][j] * 0.125f - mx);
#pragma unroll
      for (int o = 1; o < 16; o <<= 1) sm += __shfl_xor(sm, o, 64);
      lse_j[j] = mx + __logf(sm);
    }

    f32x4 acc3[4];
#pragma unroll
    for (int n = 0; n < 4; ++n)
#pragma unroll
      for (int e = 0; e < 4; ++e) acc3[n][e] = 0.f;
#pragma unroll
    for (int kk = 0; kk < 2; ++kk) {
      bf16x8 aq = *(const bf16x8*)&Qb[arow * 64 +
                                      (((kk << 2) + g4) ^ (arow & 7)) * 8];
#pragma unroll
      for (int n2 = 0; n2 < 4; ++n2) {
        int mrow = n2 * 16 + r;
        bf16x8 bm = *(const bf16x8*)&Mt[mrow * 64 +
                                        (((kk << 2) + g4) ^ (mrow & 7)) * 8];
        acc3[n2] = __builtin_amdgcn_mfma_f32_16x16x32_bf16(aq, bm, acc3[n2], 0, 0, 0);
      }
    }
#pragma unroll
    for (int n2 = 0; n2 < 4; ++n2) {
      int col = n2 * 16 + r;
      float svv = svs[col];
#pragma unroll
      for (int j = 0; j < 4; ++j) {
        int srow = qc * 128 + w * 16 + g4 * 4 + j;
        ctx[((size_t)(b * 512 + srow)) * 768 + hh * 64 + col] =
            (bf16_t)(acc3[n2][j] - lse_j[j] * svv);
      }
    }
  }
}

// ---- final LN (row s=0 per batch) + classifier ----
__global__ __launch_bounds__(192) void k_final(
    const float* __restrict__ x, const float* __restrict__ gam,
    const float* __restrict__ bet, const float* __restrict__ cw,
    const float* __restrict__ cb, float* __restrict__ out) {
  __shared__ float red[3];
  int b = blockIdx.x, t = threadIdx.x;
  const float* xr = x + (size_t)b * 512 * 768;
  const float4 xv = *(const float4*)&xr[t * 4];
  float v[4] = {xv.x, xv.y, xv.z, xv.w};
  float tot = bsum3(v[0] + v[1] + v[2] + v[3], red);
  float mu = tot * (1.f / 768.f);
  float sq = 0.f;
#pragma unroll
  for (int u = 0; u < 4; ++u) { float d = v[u] - mu; sq += d * d; }
  float var = bsum3(sq, red) * (1.f / 768.f);
  float rstd = rsqrtf(var + 1e-5f);
  const float4 g4 = *(const float4*)&gam[t * 4];
  const float4 b4 = *(const float4*)&bet[t * 4];
  float nv[4];
  nv[0] = (v[0] - mu) * rstd * g4.x + b4.x;
  nv[1] = (v[1] - mu) * rstd * g4.y + b4.y;
  nv[2] = (v[2] - mu) * rstd * g4.z + b4.z;
  nv[3] = (v[3] - mu) * rstd * g4.w + b4.w;
  const float4 wa = *(const float4*)&cw[t * 8];
  const float4 wb = *(const float4*)&cw[t * 8 + 4];
  float d0 = nv[0] * wa.x + nv[1] * wa.z + nv[2] * wb.x + nv[3] * wb.z;
  float d1 = nv[0] * wa.y + nv[1] * wa.w + nv[2] * wb.y + nv[3] * wb.w;
  d0 = bsum3(d0, red);
  d1 = bsum3(d1, red);
  if (t == 0) {
    out[b * 2 + 0] = d0 + cb[0];
    out[b * 2 + 1] = d1 + cb[1];
  }
}

// ---- workspace layout ----
static constexpr size_t OFF_X = 0;                                  // f32 8192x768
static constexpr size_t OFF_H = OFF_X + 8192ull * 768 * 4;          // bf16 8192x768
static constexpr size_t OFF_QG = OFF_H + 8192ull * 768 * 2;         // bf16 arena (qkv | gelu)
static constexpr size_t OFF_CTX = OFF_QG + 8192ull * 3072 * 2;      // bf16 8192x768
static constexpr size_t OFF_LSE = OFF_CTX + 8192ull * 768 * 2;      // f32 (unused)
static constexpr size_t OFF_W = OFF_LSE + 192ull * 512 * 4;         // bf16 weights
static constexpr size_t WPL = 7077888;                              // elems per layer
static constexpr size_t WS_SMALL = OFF_W + WPL * 2;                 // 1-layer buffer
static constexpr size_t WS_BIG = OFF_W + 12ull * WPL * 2;           // all layers

extern "C" void kernel_launch(void* const* d_in, const int* in_sizes, int n_in,
                              void* d_out, int out_size, void* d_ws,
                              size_t ws_size, hipStream_t stream) {
  const int* ids = (const int*)d_in[0];
  const float* tok = (const float*)d_in[1];
  const float* pos = (const float*)d_in[2];
  const float* eln_s = (const float*)d_in[3];
  const float* eln_b = (const float*)d_in[4];
  const float* wq = (const float*)d_in[5];
  const float* wk = (const float*)d_in[6];
  const float* wv = (const float*)d_in[7];
  const float* wo = (const float*)d_in[8];
  const float* wo_b = (const float*)d_in[9];
  const float* ln1_s = (const float*)d_in[10];
  const float* ln1_b = (const float*)d_in[11];
  const float* ln2_s = (const float*)d_in[12];
  const float* ln2_b = (const float*)d_in[13];
  const float* ff1w = (const float*)d_in[14];
  const float* ff1b = (const float*)d_in[15];
  const float* ff2w = (const float*)d_in[16];
  const float* ff2b = (const float*)d_in[17];
  const float* fln_s = (const float*)d_in[18];
  const float* fln_b = (const float*)d_in[19];
  const float* cw = (const float*)d_in[20];
  const float* cb = (const float*)d_in[21];
  float* out = (float*)d_out;

  if (ws_size < WS_SMALL) return;
  const bool big = ws_size >= WS_BIG;

  char* ws = (char*)d_ws;
  float* x = (float*)(ws + OFF_X);
  bf16_t* h = (bf16_t*)(ws + OFF_H);
  bf16_t* qkv = (bf16_t*)(ws + OFF_QG);
  bf16_t* gbuf = (bf16_t*)(ws + OFF_QG);
  bf16_t* ctx = (bf16_t*)(ws + OFF_CTX);
  bf16_t* wT = (bf16_t*)(ws + OFF_W);

  // embedding + emb-LN + ln1(layer0)
  k_embed<<<8192, 192, 0, stream>>>(ids, tok, pos, eln_s, eln_b,
                                    ln1_s, ln1_b, x, h);

  if (big) {
    // convert ALL layers' weights upfront: 4 launches
    k_convT3<<<dim3(2, 24, 432), 256, 0, stream>>>(wq, wk, wv, wT,
                                                   589824, WPL);
    k_convT<<<dim3(24, 24, 12), 256, 0, stream>>>(wo, 589824,
                                                  wT + 1769472, WPL, 768, 768);
    k_convT<<<dim3(96, 24, 12), 256, 0, stream>>>(ff1w, 2359296,
                                                  wT + 2359296, WPL, 3072, 768);
    k_convT<<<dim3(24, 96, 12), 256, 0, stream>>>(ff2w, 2359296,
                                                  wT + 4718592, WPL, 768, 3072);
  }

  for (int l = 0; l < 12; ++l) {
    bf16_t* wl = big ? wT + (size_t)l * WPL : wT;
    bf16_t* qkvT = wl;
    bf16_t* woT = wl + 1769472;
    bf16_t* ff1T = wl + 2359296;
    bf16_t* ff2T = wl + 4718592;

    if (l > 0)
      k_ln<<<2048, 256, 0, stream>>>(x, h, ln1_s + l * 768, ln1_b + l * 768);
    if (!big) {
      k_convT3<<<dim3(2, 24, 36), 256, 0, stream>>>(
          wq + (size_t)l * 589824, wk + (size_t)l * 589824,
          wv + (size_t)l * 589824, qkvT, 589824, 0);
      k_convT<<<dim3(24, 24, 1), 256, 0, stream>>>(wo + (size_t)l * 589824, 0,
                                                   woT, 0, 768, 768);
      k_convT<<<dim3(96, 24, 1), 256, 0, stream>>>(ff1w + (size_t)l * 2359296,
                                                   0, ff1T, 0, 3072, 768);
      k_convT<<<dim3(24, 96, 1), 256, 0, stream>>>(ff2w + (size_t)l * 2359296,
                                                   0, ff2T, 0, 768, 3072);
    }
    // QKV: M=8192 N=2304 K=768 -> grid 1152 (large: single-buf core)
    k_gemm1<0><<<1152, 256, 0, stream>>>(h, 768, qkvT, 768, 768,
                                         nullptr, qkv, 2304, nullptr, 18);
    // fused attention (log-softmax decomposition), 8 waves/block
    k_attn<<<192, 512, 0, stream>>>(qkv, ctx);
    // WO + residual: grid 384 (small: pipelined 3-buf core)
    k_gemm3<1><<<384, 256, 0, stream>>>(ctx, 768, woT, 768, 768, x,
                                        nullptr, 768, wo_b + l * 768, 6);
    // FFN
    k_ln<<<2048, 256, 0, stream>>>(x, h, ln2_s + l * 768, ln2_b + l * 768);
    // FF1: grid 1536 (large: single-buf core)
    k_gemm1<2><<<1536, 256, 0, stream>>>(h, 768, ff1T, 768, 768,
                                         nullptr, gbuf, 3072,
                                         ff1b + l * 3072, 24);
    // FF2: grid 384 (small: pipelined 3-buf core)
    k_gemm3<1><<<384, 256, 0, stream>>>(gbuf, 3072, ff2T, 3072, 3072, x,
                                        nullptr, 768, ff2b + l * 768, 6);
  }
  k_final<<<16, 192, 0, stream>>>(x, fln_s, fln_b, cw, cb, out);
}

// Round 17
// 3396.755 us; speedup vs baseline: 1.2577x; 1.0105x over previous
//
#include <hip/hip_runtime.h>
#include <hip/hip_bf16.h>
#include <math.h>

// Dims: B=16 S=512 D=768 H=12 DH=64 F=3072 LYR=12 NLAB=2; rows = B*S = 8192
typedef __bf16 bf16_t;
typedef __attribute__((ext_vector_type(8))) __bf16 bf16x8;
typedef __attribute__((ext_vector_type(4))) float f32x4;

typedef const __attribute__((address_space(1))) void av1_void;
typedef __attribute__((address_space(3))) void av3_void;

#define DEV static __device__ __forceinline__

DEV void gload16(const void* g, void* l) {
  __builtin_amdgcn_global_load_lds((av1_void*)g, (av3_void*)l, 16, 0, 0);
}

// ---- block reduction over 3 waves (block=192) ----
DEV float bsum3(float v, float* red) {
#pragma unroll
  for (int o = 32; o > 0; o >>= 1) v += __shfl_xor(v, o, 64);
  __syncthreads();
  if ((threadIdx.x & 63) == 0) red[threadIdx.x >> 6] = v;
  __syncthreads();
  return red[0] + red[1] + red[2];
}

// ---- embedding gather + emb-LN -> x (fp32), then ln1(layer0) -> h (bf16) ----
__global__ __launch_bounds__(192) void k_embed(
    const int* __restrict__ ids, const float* __restrict__ tok,
    const float* __restrict__ pos, const float* __restrict__ gam,
    const float* __restrict__ bet, const float* __restrict__ gam2,
    const float* __restrict__ bet2, float* __restrict__ x,
    bf16_t* __restrict__ h) {
  __shared__ float red[3];
  int row = blockIdx.x;          // b*512 + s
  int s = row & 511;
  int t = threadIdx.x;
  int id = ids[row];
  const float4 tv = *(const float4*)&tok[(size_t)id * 768 + t * 4];
  const float4 pv = *(const float4*)&pos[(size_t)s * 768 + t * 4];
  float v[4] = {tv.x + pv.x, tv.y + pv.y, tv.z + pv.z, tv.w + pv.w};
  float tot = bsum3(v[0] + v[1] + v[2] + v[3], red);
  float mu = tot * (1.f / 768.f);
  float sq = 0.f;
#pragma unroll
  for (int u = 0; u < 4; ++u) { float d = v[u] - mu; sq += d * d; }
  float var = bsum3(sq, red) * (1.f / 768.f);
  float rstd = rsqrtf(var + 1e-5f);
  const float4 g4 = *(const float4*)&gam[t * 4];
  const float4 b4 = *(const float4*)&bet[t * 4];
  float o[4];
  o[0] = (v[0] - mu) * rstd * g4.x + b4.x;
  o[1] = (v[1] - mu) * rstd * g4.y + b4.y;
  o[2] = (v[2] - mu) * rstd * g4.z + b4.z;
  o[3] = (v[3] - mu) * rstd * g4.w + b4.w;
  float4 ov = {o[0], o[1], o[2], o[3]};
  *(float4*)&x[(size_t)row * 768 + t * 4] = ov;
  // second LN (ln1 of layer 0) -> h
  float tot2 = bsum3(o[0] + o[1] + o[2] + o[3], red);
  float mu2 = tot2 * (1.f / 768.f);
  float sq2 = 0.f;
#pragma unroll
  for (int u = 0; u < 4; ++u) { float d = o[u] - mu2; sq2 += d * d; }
  float var2 = bsum3(sq2, red) * (1.f / 768.f);
  float rstd2 = rsqrtf(var2 + 1e-5f);
  const float4 G = *(const float4*)&gam2[t * 4];
  const float4 Bb = *(const float4*)&bet2[t * 4];
  union { bf16_t ob[4]; uint2 u2; } pk;
  pk.ob[0] = (bf16_t)((o[0] - mu2) * rstd2 * G.x + Bb.x);
  pk.ob[1] = (bf16_t)((o[1] - mu2) * rstd2 * G.y + Bb.y);
  pk.ob[2] = (bf16_t)((o[2] - mu2) * rstd2 * G.z + Bb.z);
  pk.ob[3] = (bf16_t)((o[3] - mu2) * rstd2 * G.w + Bb.w);
  *(uint2*)&h[(size_t)row * 768 + t * 4] = pk.u2;
}

// ---- LN: x (fp32) -> h (bf16); wave-per-row, lane owns 12 cols ----
__global__ __launch_bounds__(256) void k_ln(
    const float* __restrict__ xin, bf16_t* __restrict__ hout,
    const float* __restrict__ gam, const float* __restrict__ bet) {
  int row = blockIdx.x * 4 + (threadIdx.x >> 6);
  int lane = threadIdx.x & 63;
  const float* xr = xin + (size_t)row * 768 + lane * 12;
  float4 a = *(const float4*)&xr[0];
  float4 b = *(const float4*)&xr[4];
  float4 c = *(const float4*)&xr[8];
  float v[12] = {a.x, a.y, a.z, a.w, b.x, b.y, b.z, b.w, c.x, c.y, c.z, c.w};
  float sm = 0.f;
#pragma unroll
  for (int u = 0; u < 12; ++u) sm += v[u];
#pragma unroll
  for (int o = 32; o > 0; o >>= 1) sm += __shfl_xor(sm, o, 64);
  float mu = sm * (1.f / 768.f);
  float sq = 0.f;
#pragma unroll
  for (int u = 0; u < 12; ++u) { float d = v[u] - mu; sq += d * d; }
#pragma unroll
  for (int o = 32; o > 0; o >>= 1) sq += __shfl_xor(sq, o, 64);
  float rstd = rsqrtf(sq * (1.f / 768.f) + 1e-5f);
  const float4 ga = *(const float4*)&gam[lane * 12];
  const float4 gb = *(const float4*)&gam[lane * 12 + 4];
  const float4 gc = *(const float4*)&gam[lane * 12 + 8];
  const float4 ba = *(const float4*)&bet[lane * 12];
  const float4 bb = *(const float4*)&bet[lane * 12 + 4];
  const float4 bc = *(const float4*)&bet[lane * 12 + 8];
  float g[12] = {ga.x, ga.y, ga.z, ga.w, gb.x, gb.y, gb.z, gb.w,
                 gc.x, gc.y, gc.z, gc.w};
  float be[12] = {ba.x, ba.y, ba.z, ba.w, bb.x, bb.y, bb.z, bb.w,
                  bc.x, bc.y, bc.z, bc.w};
  union { bf16_t o[12]; uint2 u2[3]; } pk;
#pragma unroll
  for (int u = 0; u < 12; ++u)
    pk.o[u] = (bf16_t)((v[u] - mu) * rstd * g[u] + be[u]);
  bf16_t* hr = hout + (size_t)row * 768 + lane * 12;
#pragma unroll
  for (int u = 0; u < 3; ++u) *(uint2*)&hr[u * 4] = pk.u2[u];
}

// ---- transpose-convert fp32 [K][N] -> bf16 [N][K], per z-slice ----
__global__ __launch_bounds__(256) void k_convT(
    const float* __restrict__ in, size_t in_slice, bf16_t* __restrict__ out,
    size_t out_slice, int N, int K) {
  __shared__ float tbuf[32][33];
  int slice = blockIdx.z;
  const float* ip = in + (size_t)slice * in_slice;
  bf16_t* op = out + (size_t)slice * out_slice;
  int n0 = blockIdx.x * 32, k0 = blockIdx.y * 32;
  int c = threadIdx.x & 31, r8 = threadIdx.x >> 5;
#pragma unroll
  for (int i = 0; i < 4; ++i) {
    int rr = r8 + i * 8;
    tbuf[rr][c] = ip[(size_t)(k0 + rr) * N + n0 + c];
  }
  __syncthreads();
#pragma unroll
  for (int i = 0; i < 4; ++i) {
    int rr = r8 + i * 8;
    op[(size_t)(n0 + rr) * K + k0 + c] = (bf16_t)tbuf[c][rr];
  }
}

// ---- fused wq/wk/wv transpose-convert, NL layers: z = l*36 + which*12 + head
__global__ __launch_bounds__(256) void k_convT3(
    const float* __restrict__ wq, const float* __restrict__ wk,
    const float* __restrict__ wv, bf16_t* __restrict__ out,
    size_t in_lstride, size_t out_lstride) {
  __shared__ float tbuf[32][33];
  int z = blockIdx.z;
  int l = z / 36, r = z % 36;
  int which = r / 12, head = r % 12;
  const float* ip = (which == 0 ? wq : which == 1 ? wk : wv) +
                    (size_t)l * in_lstride + (size_t)head * 768 * 64;
  bf16_t* op = out + (size_t)l * out_lstride + (size_t)which * 768 * 768 +
               (size_t)head * 64 * 768;
  int n0 = blockIdx.x * 32, k0 = blockIdx.y * 32;   // N=64, K=768
  int c = threadIdx.x & 31, r8 = threadIdx.x >> 5;
#pragma unroll
  for (int i = 0; i < 4; ++i) {
    int rr = r8 + i * 8;
    tbuf[rr][c] = ip[(size_t)(k0 + rr) * 64 + n0 + c];
  }
  __syncthreads();
#pragma unroll
  for (int i = 0; i < 4; ++i) {
    int rr = r8 + i * 8;
    op[(size_t)(n0 + rr) * 768 + k0 + c] = (bf16_t)tbuf[c][rr];
  }
}

// ======================================================================
// k_gemm1 (round-10 core): BK=64, SINGLE-buffered LDS (32KB -> 5
// blocks/CU). Best for LARGE grids (QKV, FF1): cross-block overlap.
// ======================================================================
template <int EPI>
__global__ __launch_bounds__(256) void k_gemm1(
    const bf16_t* __restrict__ A, int lda, const bf16_t* __restrict__ Bt,
    int ldb, int K, float* __restrict__ Cf, bf16_t* __restrict__ Cb, int ldc,
    const float* __restrict__ bias, int gx) {
  __shared__ __attribute__((aligned(16))) bf16_t As[128 * 64];
  __shared__ __attribute__((aligned(16))) bf16_t Bs[128 * 64];
  const int nwg = gridDim.x;
  const int bid = blockIdx.x;
  const int cpx = nwg >> 3;
  const int swz = (bid & 7) * cpx + (bid >> 3);
  const int bx = swz % gx, by = swz / gx;
  const int m0 = by << 7, n0 = bx << 7;
  const int tid = threadIdx.x;
  const int lane = tid & 63, w = tid >> 6;
  const int wm = w >> 1, wn = w & 1;
  const int r = lane & 15, g4 = lane >> 4;

  f32x4 acc[4][4];
#pragma unroll
  for (int m = 0; m < 4; ++m)
#pragma unroll
    for (int n = 0; n < 4; ++n)
#pragma unroll
      for (int e = 0; e < 4; ++e) acc[m][n][e] = 0.f;

  const bf16_t* pa[4];
  const bf16_t* pb[4];
  char* la[4];
  char* lb[4];
#pragma unroll
  for (int u = 0; u < 4; ++u) {
    int s = u * 256 + tid;
    int row = s >> 3;
    int c = (s & 7) ^ (row & 7);
    pa[u] = A + (size_t)(m0 + row) * lda + c * 8;
    pb[u] = Bt + (size_t)(n0 + row) * ldb + c * 8;
    la[u] = (char*)As + (size_t)(u * 256 + (w << 6)) * 16;
    lb[u] = (char*)Bs + (size_t)(u * 256 + (w << 6)) * 16;
  }

  const int NT = K >> 6;
  for (int t = 0; t < NT; ++t) {
    const int k0 = t << 6;
#pragma unroll
    for (int u = 0; u < 4; ++u) gload16(pa[u] + k0, la[u]);
#pragma unroll
    for (int u = 0; u < 4; ++u) gload16(pb[u] + k0, lb[u]);
    __syncthreads();

#pragma unroll
    for (int kk = 0; kk < 2; ++kk) {
      bf16x8 af[4], bb[4];
#pragma unroll
      for (int m = 0; m < 4; ++m) {
        int row = wm * 64 + m * 16 + r;
        af[m] = *(const bf16x8*)&As[row * 64 +
                                    (((kk << 2) + g4) ^ (row & 7)) * 8];
      }
#pragma unroll
      for (int n = 0; n < 4; ++n) {
        int row = wn * 64 + n * 16 + r;
        bb[n] = *(const bf16x8*)&Bs[row * 64 +
                                    (((kk << 2) + g4) ^ (row & 7)) * 8];
      }
#pragma unroll
      for (int m = 0; m < 4; ++m)
#pragma unroll
        for (int n = 0; n < 4; ++n)
          acc[m][n] = __builtin_amdgcn_mfma_f32_16x16x32_bf16(af[m], bb[n],
                                                              acc[m][n], 0, 0, 0);
    }
    __syncthreads();
  }

#pragma unroll
  for (int m = 0; m < 4; ++m) {
#pragma unroll
    for (int n = 0; n < 4; ++n) {
      int col = n0 + wn * 64 + n * 16 + r;
      float bv = 0.f;
      if constexpr (EPI != 0) bv = bias[col];
#pragma unroll
      for (int j = 0; j < 4; ++j) {
        int row = m0 + wm * 64 + m * 16 + g4 * 4 + j;
        float v = acc[m][n][j];
        if constexpr (EPI == 0) {
          Cb[(size_t)row * ldc + col] = (bf16_t)v;
        } else if constexpr (EPI == 1) {
          size_t o = (size_t)row * ldc + col;
          Cf[o] += v + bv;
        } else {
          float tt = v + bv;
          float ge = 0.5f * tt * (1.f + erff(tt * 0.70710678118f));
          Cb[(size_t)row * ldc + col] = (bf16_t)ge;
        }
      }
    }
  }
}

// ======================================================================
// k_gemm3h: BM=64 x BN=128 pipelined core (derived from round-11 gemm3):
// BK=32, THREE-buffer LDS (36KB -> 4 blocks/CU), counted vmcnt(3)
// (3 loads/thread/tile, 2 tiles in flight). For SMALL-N GEMMs (WO, FF2):
// grid doubles to 768 = 3 blocks/CU exact fill.
// EPI 1: Cf += C + bias (fp32 residual)
// ======================================================================
template <int EPI>
__global__ __launch_bounds__(256) void k_gemm3h(
    const bf16_t* __restrict__ A, int lda, const bf16_t* __restrict__ Bt,
    int ldb, int K, float* __restrict__ Cf, bf16_t* __restrict__ Cb, int ldc,
    const float* __restrict__ bias, int gx) {
  __shared__ __attribute__((aligned(16))) bf16_t As[3][64 * 32];
  __shared__ __attribute__((aligned(16))) bf16_t Bs[3][128 * 32];
  const int nwg = gridDim.x;
  const int bid = blockIdx.x;
  const int cpx = nwg >> 3;
  const int swz = (bid & 7) * cpx + (bid >> 3);
  const int bx = swz % gx, by = swz / gx;
  const int m0 = by << 6, n0 = bx << 7;     // BM=64, BN=128
  const int tid = threadIdx.x;
  const int lane = tid & 63, w = tid >> 6;
  const int wm = w >> 1, wn = w & 1;        // 2M x 2N -> wave tile 32x64
  const int r = lane & 15, g4 = lane >> 4;

  f32x4 acc[2][4];
#pragma unroll
  for (int m = 0; m < 2; ++m)
#pragma unroll
    for (int n = 0; n < 4; ++n)
#pragma unroll
      for (int e = 0; e < 4; ++e) acc[m][n][e] = 0.f;

  // A: 256 slots (64 rows x 4 chunks), 1/thread; B: 512 slots, 2/thread
  const bf16_t* pa0;
  const bf16_t* pb[2];
  uint32_t loa, lob[2];
  {
    int s = tid;
    int row = s >> 2;
    int c = (s & 3) ^ ((row >> 1) & 3);
    pa0 = A + (size_t)(m0 + row) * lda + c * 8;
    loa = (uint32_t)(w << 6) * 16;
#pragma unroll
    for (int u = 0; u < 2; ++u) {
      int sb = u * 256 + tid;
      int rowb = sb >> 2;
      int cb = (sb & 3) ^ ((rowb >> 1) & 3);
      pb[u] = Bt + (size_t)(n0 + rowb) * ldb + cb * 8;
      lob[u] = (uint32_t)(u * 256 + (w << 6)) * 16;
    }
  }

  const int NT = K >> 5;
  auto STAGE = [&](int t, int bufi) {
    int k0 = (t < NT ? t : NT - 1) << 5;    // clamped dummy tail stage
    gload16(pa0 + k0, (char*)&As[bufi][0] + loa);
#pragma unroll
    for (int u = 0; u < 2; ++u) gload16(pb[u] + k0, (char*)&Bs[bufi][0] + lob[u]);
  };

  STAGE(0, 0);
  STAGE(1, 1);
  int bi = 0, si = 2;
  const int co = (g4 ^ ((r >> 1) & 3)) << 3;
  for (int t = 0; t < NT; ++t) {
    asm volatile("s_waitcnt vmcnt(3)" ::: "memory");  // own loads(t) landed
    asm volatile("s_barrier" ::: "memory");           // all waves' loads(t) landed
    bf16x8 af[2], bb[4];
#pragma unroll
    for (int m = 0; m < 2; ++m) {
      int row = wm * 32 + m * 16 + r;
      af[m] = *(const bf16x8*)&As[bi][row * 32 + co];
    }
#pragma unroll
    for (int n = 0; n < 4; ++n) {
      int row = wn * 64 + n * 16 + r;
      bb[n] = *(const bf16x8*)&Bs[bi][row * 32 + co];
    }
#pragma unroll
    for (int m = 0; m < 2; ++m)
#pragma unroll
      for (int n = 0; n < 4; ++n)
        acc[m][n] = __builtin_amdgcn_mfma_f32_16x16x32_bf16(af[m], bb[n],
                                                            acc[m][n], 0, 0, 0);
    asm volatile("s_barrier" ::: "memory");
    STAGE(t + 2, si);                        // writes dead buffer (t-1)%3
    si = bi;
    bi = (bi == 2) ? 0 : bi + 1;
  }
  asm volatile("s_waitcnt vmcnt(0)" ::: "memory");

#pragma unroll
  for (int m = 0; m < 2; ++m) {
#pragma unroll
    for (int n = 0; n < 4; ++n) {
      int col = n0 + wn * 64 + n * 16 + r;
      float bv = 0.f;
      if constexpr (EPI != 0) bv = bias[col];
#pragma unroll
      for (int j = 0; j < 4; ++j) {
        int row = m0 + wm * 32 + m * 16 + g4 * 4 + j;
        float v = acc[m][n][j];
        if constexpr (EPI == 0) {
          Cb[(size_t)row * ldc + col] = (bf16_t)v;
        } else if constexpr (EPI == 1) {
          size_t o = (size_t)row * ldc + col;
          Cf[o] += v + bv;
        } else {
          float tt = v + bv;
          float ge = 0.5f * tt * (1.f + erff(tt * 0.70710678118f));
          Cb[(size_t)row * ldc + col] = (bf16_t)ge;
        }
      }
    }
  }
}

// ======================================================================
// Fused attention (log-softmax decomposition), one block per (b,h),
// 512 threads (8 waves). (round-16 verified version)
// ======================================================================
__global__ __launch_bounds__(512) void k_attn(const bf16_t* __restrict__ qkv,
                                              bf16_t* __restrict__ ctx) {
  __shared__ __attribute__((aligned(16))) bf16_t Ks[512 * 64];    // swizzled
  __shared__ __attribute__((aligned(16))) float Vs[128 * 64];
  __shared__ __attribute__((aligned(16))) bf16_t Qs[2][128 * 64]; // swizzled
  __shared__ __attribute__((aligned(16))) bf16_t Mt[64 * 64];     // swizzled
  __shared__ float svp[8 * 64];
  __shared__ float svs[64];

  int bh = blockIdx.x;
  int b = bh / 12, hh = bh % 12;
  int tid = threadIdx.x, lane = tid & 63, w = tid >> 6;   // 8 waves
  int r = lane & 15, g4 = lane >> 4;
  const bf16_t* qb = qkv + (size_t)b * 512 * 2304 + hh * 64;
  const bf16_t* kb = qb + 768;
  const bf16_t* vb = qb + 1536;

#pragma unroll
  for (int i = 0; i < 8; ++i) {
    int s = i * 512 + tid;
    int row = s >> 3;
    int c = (s & 7) ^ (row & 7);
    gload16(kb + (size_t)row * 2304 + c * 8,
            (char*)Ks + (size_t)(i * 512 + (w << 6)) * 16);
  }

  f32x4 macc[2];
#pragma unroll
  for (int jj = 0; jj < 2; ++jj)
#pragma unroll
    for (int e = 0; e < 4; ++e) macc[jj][e] = 0.f;
  float svacc = 0.f;
  const int e1hi = (lane >> 3), e1lo = (lane & 7);

  bf16x8 vreg[2];
  auto ldV = [&](int t0) {
#pragma unroll
    for (int i = 0; i < 2; ++i) {
      int cs = i * 512 + tid;
      int row = cs >> 3, col = (cs & 7) * 8;
      vreg[i] = *(const bf16x8*)(vb + (size_t)(t0 + row) * 2304 + col);
    }
  };
  auto wrV = [&]() {
#pragma unroll
    for (int i = 0; i < 2; ++i) {
      int cs = i * 512 + tid;
      int row = cs >> 3, col = (cs & 7) * 8;
      f32x4 v0, v1;
#pragma unroll
      for (int u = 0; u < 4; ++u) {
        v0[u] = (float)vreg[i][u];
        v1[u] = (float)vreg[i][u + 4];
      }
      *(f32x4*)&Vs[row * 64 + col] = v0;
      *(f32x4*)&Vs[row * 64 + col + 4] = v1;
    }
  };

  ldV(0);
  wrV();
  __syncthreads();

  for (int t0 = 0; t0 < 4; ++t0) {
    if (t0 < 3) ldV((t0 + 1) * 128);
#pragma unroll 8
    for (int tt = 0; tt < 128; ++tt) {
      int t = t0 * 128 + tt;
      float kv = (float)Ks[t * 64 + (((e1hi ^ (t & 7)) << 3) | e1lo)];
#pragma unroll
      for (int jj = 0; jj < 2; ++jj) {
        f32x4 vv = *(const f32x4*)&Vs[tt * 64 + w * 8 + jj * 4];
        macc[jj] += kv * vv;
      }
    }
#pragma unroll
    for (int q = 0; q < 16; ++q)
      svacc += Vs[((w << 4) + q) * 64 + lane];
    __syncthreads();
    if (t0 < 3) {
      wrV();
      __syncthreads();
    }
  }

#pragma unroll
  for (int jj = 0; jj < 2; ++jj)
#pragma unroll
    for (int u = 0; u < 4; ++u) {
      int e2 = w * 8 + jj * 4 + u;
      Mt[e2 * 64 + (((e1hi ^ (e2 & 7)) << 3) | e1lo)] =
          (bf16_t)(macc[jj][u] * 0.125f);
    }
  svp[w * 64 + lane] = svacc;
  __syncthreads();
  if (w == 0) {
    float s = 0.f;
#pragma unroll
    for (int u = 0; u < 8; ++u) s += svp[u * 64 + lane];
    svs[lane] = s;
  }

  auto stageQ = [&](int qc, int bufi) {
#pragma unroll
    for (int u = 0; u < 2; ++u) {
      int s = u * 512 + tid;
      int row = s >> 3;
      int c = (s & 7) ^ (row & 7);
      gload16(qb + (size_t)(qc * 128 + row) * 2304 + c * 8,
              (char*)&Qs[bufi][0] + (size_t)(u * 512 + (w << 6)) * 16);
    }
  };
  stageQ(0, 0);
  const int arow = w * 16 + r;

  for (int qc = 0; qc < 4; ++qc) {
    __syncthreads();
    if (qc < 3) stageQ(qc + 1, (qc + 1) & 1);
    const bf16_t* Qb = &Qs[qc & 1][0];

    f32x4 acc2[32];
#pragma unroll
    for (int n = 0; n < 32; ++n)
#pragma unroll
      for (int e = 0; e < 4; ++e) acc2[n][e] = 0.f;

#pragma unroll
    for (int kk = 0; kk < 2; ++kk) {
      bf16x8 aq = *(const bf16x8*)&Qb[arow * 64 +
                                      (((kk << 2) + g4) ^ (arow & 7)) * 8];
#pragma unroll
      for (int n = 0; n < 32; ++n) {
        int krow = n * 16 + r;
        bf16x8 bk = *(const bf16x8*)&Ks[krow * 64 +
                                        (((kk << 2) + g4) ^ (krow & 7)) * 8];
        acc2[n] = __builtin_amdgcn_mfma_f32_16x16x32_bf16(aq, bk, acc2[n], 0, 0, 0);
      }
    }

    float lse_j[4];
#pragma unroll
    for (int j = 0; j < 4; ++j) {
      float mx = -1e30f;
#pragma unroll
      for (int n = 0; n < 32; ++n) mx = fmaxf(mx, acc2[n][j] * 0.125f);
#pragma unroll
      for (int o = 1; o < 16; o <<= 1) mx = fmaxf(mx, __shfl_xor(mx, o, 64));
      float sm = 0.f;
#pragma unroll
      for (int n = 0; n < 32; ++n) sm += __expf(acc2[n][j] * 0.125f - mx);
#pragma unroll
      for (int o = 1; o < 16; o <<= 1) sm += __shfl_xor(sm, o, 64);
      lse_j[j] = mx + __logf(sm);
    }

    f32x4 acc3[4];
#pragma unroll
    for (int n = 0; n < 4; ++n)
#pragma unroll
      for (int e = 0; e < 4; ++e) acc3[n][e] = 0.f;
#pragma unroll
    for (int kk = 0; kk < 2; ++kk) {
      bf16x8 aq = *(const bf16x8*)&Qb[arow * 64 +
                                      (((kk << 2) + g4) ^ (arow & 7)) * 8];
#pragma unroll
      for (int n2 = 0; n2 < 4; ++n2) {
        int mrow = n2 * 16 + r;
        bf16x8 bm = *(const bf16x8*)&Mt[mrow * 64 +
                                        (((kk << 2) + g4) ^ (mrow & 7)) * 8];
        acc3[n2] = __builtin_amdgcn_mfma_f32_16x16x32_bf16(aq, bm, acc3[n2], 0, 0, 0);
      }
    }
#pragma unroll
    for (int n2 = 0; n2 < 4; ++n2) {
      int col = n2 * 16 + r;
      float svv = svs[col];
#pragma unroll
      for (int j = 0; j < 4; ++j) {
        int srow = qc * 128 + w * 16 + g4 * 4 + j;
        ctx[((size_t)(b * 512 + srow)) * 768 + hh * 64 + col] =
            (bf16_t)(acc3[n2][j] - lse_j[j] * svv);
      }
    }
  }
}

// ---- final LN (row s=0 per batch) + classifier ----
__global__ __launch_bounds__(192) void k_final(
    const float* __restrict__ x, const float* __restrict__ gam,
    const float* __restrict__ bet, const float* __restrict__ cw,
    const float* __restrict__ cb, float* __restrict__ out) {
  __shared__ float red[3];
  int b = blockIdx.x, t = threadIdx.x;
  const float* xr = x + (size_t)b * 512 * 768;
  const float4 xv = *(const float4*)&xr[t * 4];
  float v[4] = {xv.x, xv.y, xv.z, xv.w};
  float tot = bsum3(v[0] + v[1] + v[2] + v[3], red);
  float mu = tot * (1.f / 768.f);
  float sq = 0.f;
#pragma unroll
  for (int u = 0; u < 4; ++u) { float d = v[u] - mu; sq += d * d; }
  float var = bsum3(sq, red) * (1.f / 768.f);
  float rstd = rsqrtf(var + 1e-5f);
  const float4 g4 = *(const float4*)&gam[t * 4];
  const float4 b4 = *(const float4*)&bet[t * 4];
  float nv[4];
  nv[0] = (v[0] - mu) * rstd * g4.x + b4.x;
  nv[1] = (v[1] - mu) * rstd * g4.y + b4.y;
  nv[2] = (v[2] - mu) * rstd * g4.z + b4.z;
  nv[3] = (v[3] - mu) * rstd * g4.w + b4.w;
  const float4 wa = *(const float4*)&cw[t * 8];
  const float4 wb = *(const float4*)&cw[t * 8 + 4];
  float d0 = nv[0] * wa.x + nv[1] * wa.z + nv[2] * wb.x + nv[3] * wb.z;
  float d1 = nv[0] * wa.y + nv[1] * wa.w + nv[2] * wb.y + nv[3] * wb.w;
  d0 = bsum3(d0, red);
  d1 = bsum3(d1, red);
  if (t == 0) {
    out[b * 2 + 0] = d0 + cb[0];
    out[b * 2 + 1] = d1 + cb[1];
  }
}

// ---- workspace layout ----
static constexpr size_t OFF_X = 0;                                  // f32 8192x768
static constexpr size_t OFF_H = OFF_X + 8192ull * 768 * 4;          // bf16 8192x768
static constexpr size_t OFF_QG = OFF_H + 8192ull * 768 * 2;         // bf16 arena (qkv | gelu)
static constexpr size_t OFF_CTX = OFF_QG + 8192ull * 3072 * 2;      // bf16 8192x768
static constexpr size_t OFF_LSE = OFF_CTX + 8192ull * 768 * 2;      // f32 (unused)
static constexpr size_t OFF_W = OFF_LSE + 192ull * 512 * 4;         // bf16 weights
static constexpr size_t WPL = 7077888;                              // elems per layer
static constexpr size_t WS_SMALL = OFF_W + WPL * 2;                 // 1-layer buffer
static constexpr size_t WS_BIG = OFF_W + 12ull * WPL * 2;           // all layers

extern "C" void kernel_launch(void* const* d_in, const int* in_sizes, int n_in,
                              void* d_out, int out_size, void* d_ws,
                              size_t ws_size, hipStream_t stream) {
  const int* ids = (const int*)d_in[0];
  const float* tok = (const float*)d_in[1];
  const float* pos = (const float*)d_in[2];
  const float* eln_s = (const float*)d_in[3];
  const float* eln_b = (const float*)d_in[4];
  const float* wq = (const float*)d_in[5];
  const float* wk = (const float*)d_in[6];
  const float* wv = (const float*)d_in[7];
  const float* wo = (const float*)d_in[8];
  const float* wo_b = (const float*)d_in[9];
  const float* ln1_s = (const float*)d_in[10];
  const float* ln1_b = (const float*)d_in[11];
  const float* ln2_s = (const float*)d_in[12];
  const float* ln2_b = (const float*)d_in[13];
  const float* ff1w = (const float*)d_in[14];
  const float* ff1b = (const float*)d_in[15];
  const float* ff2w = (const float*)d_in[16];
  const float* ff2b = (const float*)d_in[17];
  const float* fln_s = (const float*)d_in[18];
  const float* fln_b = (const float*)d_in[19];
  const float* cw = (const float*)d_in[20];
  const float* cb = (const float*)d_in[21];
  float* out = (float*)d_out;

  if (ws_size < WS_SMALL) return;
  const bool big = ws_size >= WS_BIG;

  char* ws = (char*)d_ws;
  float* x = (float*)(ws + OFF_X);
  bf16_t* h = (bf16_t*)(ws + OFF_H);
  bf16_t* qkv = (bf16_t*)(ws + OFF_QG);
  bf16_t* gbuf = (bf16_t*)(ws + OFF_QG);
  bf16_t* ctx = (bf16_t*)(ws + OFF_CTX);
  bf16_t* wT = (bf16_t*)(ws + OFF_W);

  // embedding + emb-LN + ln1(layer0)
  k_embed<<<8192, 192, 0, stream>>>(ids, tok, pos, eln_s, eln_b,
                                    ln1_s, ln1_b, x, h);

  if (big) {
    // convert ALL layers' weights upfront: 4 launches
    k_convT3<<<dim3(2, 24, 432), 256, 0, stream>>>(wq, wk, wv, wT,
                                                   589824, WPL);
    k_convT<<<dim3(24, 24, 12), 256, 0, stream>>>(wo, 589824,
                                                  wT + 1769472, WPL, 768, 768);
    k_convT<<<dim3(96, 24, 12), 256, 0, stream>>>(ff1w, 2359296,
                                                  wT + 2359296, WPL, 3072, 768);
    k_convT<<<dim3(24, 96, 12), 256, 0, stream>>>(ff2w, 2359296,
                                                  wT + 4718592, WPL, 768, 3072);
  }

  for (int l = 0; l < 12; ++l) {
    bf16_t* wl = big ? wT + (size_t)l * WPL : wT;
    bf16_t* qkvT = wl;
    bf16_t* woT = wl + 1769472;
    bf16_t* ff1T = wl + 2359296;
    bf16_t* ff2T = wl + 4718592;

    if (l > 0)
      k_ln<<<2048, 256, 0, stream>>>(x, h, ln1_s + l * 768, ln1_b + l * 768);
    if (!big) {
      k_convT3<<<dim3(2, 24, 36), 256, 0, stream>>>(
          wq + (size_t)l * 589824, wk + (size_t)l * 589824,
          wv + (size_t)l * 589824, qkvT, 589824, 0);
      k_convT<<<dim3(24, 24, 1), 256, 0, stream>>>(wo + (size_t)l * 589824, 0,
                                                   woT, 0, 768, 768);
      k_convT<<<dim3(96, 24, 1), 256, 0, stream>>>(ff1w + (size_t)l * 2359296,
                                                   0, ff1T, 0, 3072, 768);
      k_convT<<<dim3(24, 96, 1), 256, 0, stream>>>(ff2w + (size_t)l * 2359296,
                                                   0, ff2T, 0, 768, 3072);
    }
    // QKV: M=8192 N=2304 K=768 -> grid 1152 (large: single-buf core)
    k_gemm1<0><<<1152, 256, 0, stream>>>(h, 768, qkvT, 768, 768,
                                         nullptr, qkv, 2304, nullptr, 18);
    // fused attention (log-softmax decomposition), 8 waves/block
    k_attn<<<192, 512, 0, stream>>>(qkv, ctx);
    // WO + residual: BM=64 pipelined core -> grid 6*128=768
    k_gemm3h<1><<<768, 256, 0, stream>>>(ctx, 768, woT, 768, 768, x,
                                         nullptr, 768, wo_b + l * 768, 6);
    // FFN
    k_ln<<<2048, 256, 0, stream>>>(x, h, ln2_s + l * 768, ln2_b + l * 768);
    // FF1: grid 1536 (large: single-buf core)
    k_gemm1<2><<<1536, 256, 0, stream>>>(h, 768, ff1T, 768, 768,
                                         nullptr, gbuf, 3072,
                                         ff1b + l * 3072, 24);
    // FF2: BM=64 pipelined core -> grid 6*128=768
    k_gemm3h<1><<<768, 256, 0, stream>>>(gbuf, 3072, ff2T, 3072, 3072, x,
                                         nullptr, 768, ff2b + l * 768, 6);
  }
  k_final<<<16, 192, 0, stream>>>(x, fln_s, fln_b, cw, cb, out);
}

// Round 18
// 3306.814 us; speedup vs baseline: 1.2919x; 1.0272x over previous
//
#include <hip/hip_runtime.h>
#include <hip/hip_bf16.h>
#include <math.h>

// Dims: B=16 S=512 D=768 H=12 DH=64 F=3072 LYR=12 NLAB=2; rows = B*S = 8192
typedef __bf16 bf16_t;
typedef __attribute__((ext_vector_type(8))) __bf16 bf16x8;
typedef __attribute__((ext_vector_type(4))) float f32x4;

typedef const __attribute__((address_space(1))) void av1_void;
typedef __attribute__((address_space(3))) void av3_void;

#define DEV static __device__ __forceinline__

DEV void gload16(const void* g, void* l) {
  __builtin_amdgcn_global_load_lds((av1_void*)g, (av3_void*)l, 16, 0, 0);
}

DEV float b2f(bf16_t v) { return (float)v; }

// ---- block reduction over 3 waves (block=192) ----
DEV float bsum3(float v, float* red) {
#pragma unroll
  for (int o = 32; o > 0; o >>= 1) v += __shfl_xor(v, o, 64);
  __syncthreads();
  if ((threadIdx.x & 63) == 0) red[threadIdx.x >> 6] = v;
  __syncthreads();
  return red[0] + red[1] + red[2];
}

// ---- embedding gather + emb-LN -> x (bf16), then ln1(layer0) -> h (bf16) ----
__global__ __launch_bounds__(192) void k_embed(
    const int* __restrict__ ids, const float* __restrict__ tok,
    const float* __restrict__ pos, const float* __restrict__ gam,
    const float* __restrict__ bet, const float* __restrict__ gam2,
    const float* __restrict__ bet2, bf16_t* __restrict__ x,
    bf16_t* __restrict__ h) {
  __shared__ float red[3];
  int row = blockIdx.x;          // b*512 + s
  int s = row & 511;
  int t = threadIdx.x;
  int id = ids[row];
  const float4 tv = *(const float4*)&tok[(size_t)id * 768 + t * 4];
  const float4 pv = *(const float4*)&pos[(size_t)s * 768 + t * 4];
  float v[4] = {tv.x + pv.x, tv.y + pv.y, tv.z + pv.z, tv.w + pv.w};
  float tot = bsum3(v[0] + v[1] + v[2] + v[3], red);
  float mu = tot * (1.f / 768.f);
  float sq = 0.f;
#pragma unroll
  for (int u = 0; u < 4; ++u) { float d = v[u] - mu; sq += d * d; }
  float var = bsum3(sq, red) * (1.f / 768.f);
  float rstd = rsqrtf(var + 1e-5f);
  const float4 g4 = *(const float4*)&gam[t * 4];
  const float4 b4 = *(const float4*)&bet[t * 4];
  float o[4];
  o[0] = (v[0] - mu) * rstd * g4.x + b4.x;
  o[1] = (v[1] - mu) * rstd * g4.y + b4.y;
  o[2] = (v[2] - mu) * rstd * g4.z + b4.z;
  o[3] = (v[3] - mu) * rstd * g4.w + b4.w;
  union { bf16_t ob[4]; uint2 u2; } px;
  px.ob[0] = (bf16_t)o[0]; px.ob[1] = (bf16_t)o[1];
  px.ob[2] = (bf16_t)o[2]; px.ob[3] = (bf16_t)o[3];
  *(uint2*)&x[(size_t)row * 768 + t * 4] = px.u2;
  // second LN (ln1 of layer 0) -> h  (on the bf16-rounded residual value)
  float q[4] = {b2f(px.ob[0]), b2f(px.ob[1]), b2f(px.ob[2]), b2f(px.ob[3])};
  float tot2 = bsum3(q[0] + q[1] + q[2] + q[3], red);
  float mu2 = tot2 * (1.f / 768.f);
  float sq2 = 0.f;
#pragma unroll
  for (int u = 0; u < 4; ++u) { float d = q[u] - mu2; sq2 += d * d; }
  float var2 = bsum3(sq2, red) * (1.f / 768.f);
  float rstd2 = rsqrtf(var2 + 1e-5f);
  const float4 G = *(const float4*)&gam2[t * 4];
  const float4 Bb = *(const float4*)&bet2[t * 4];
  union { bf16_t ob[4]; uint2 u2; } pk;
  pk.ob[0] = (bf16_t)((q[0] - mu2) * rstd2 * G.x + Bb.x);
  pk.ob[1] = (bf16_t)((q[1] - mu2) * rstd2 * G.y + Bb.y);
  pk.ob[2] = (bf16_t)((q[2] - mu2) * rstd2 * G.z + Bb.z);
  pk.ob[3] = (bf16_t)((q[3] - mu2) * rstd2 * G.w + Bb.w);
  *(uint2*)&h[(size_t)row * 768 + t * 4] = pk.u2;
}

// ---- LN: x (bf16) -> h (bf16); wave-per-row, lane owns 12 cols ----
__global__ __launch_bounds__(256) void k_ln(
    const bf16_t* __restrict__ xin, bf16_t* __restrict__ hout,
    const float* __restrict__ gam, const float* __restrict__ bet) {
  int row = blockIdx.x * 4 + (threadIdx.x >> 6);
  int lane = threadIdx.x & 63;
  const bf16_t* xr = xin + (size_t)row * 768 + lane * 12;
  union { uint2 u; bf16_t h[4]; } ua, ub, uc;
  ua.u = *(const uint2*)&xr[0];
  ub.u = *(const uint2*)&xr[4];
  uc.u = *(const uint2*)&xr[8];
  float v[12] = {b2f(ua.h[0]), b2f(ua.h[1]), b2f(ua.h[2]), b2f(ua.h[3]),
                 b2f(ub.h[0]), b2f(ub.h[1]), b2f(ub.h[2]), b2f(ub.h[3]),
                 b2f(uc.h[0]), b2f(uc.h[1]), b2f(uc.h[2]), b2f(uc.h[3])};
  float sm = 0.f;
#pragma unroll
  for (int u = 0; u < 12; ++u) sm += v[u];
#pragma unroll
  for (int o = 32; o > 0; o >>= 1) sm += __shfl_xor(sm, o, 64);
  float mu = sm * (1.f / 768.f);
  float sq = 0.f;
#pragma unroll
  for (int u = 0; u < 12; ++u) { float d = v[u] - mu; sq += d * d; }
#pragma unroll
  for (int o = 32; o > 0; o >>= 1) sq += __shfl_xor(sq, o, 64);
  float rstd = rsqrtf(sq * (1.f / 768.f) + 1e-5f);
  const float4 ga = *(const float4*)&gam[lane * 12];
  const float4 gb = *(const float4*)&gam[lane * 12 + 4];
  const float4 gc = *(const float4*)&gam[lane * 12 + 8];
  const float4 ba = *(const float4*)&bet[lane * 12];
  const float4 bb = *(const float4*)&bet[lane * 12 + 4];
  const float4 bc = *(const float4*)&bet[lane * 12 + 8];
  float g[12] = {ga.x, ga.y, ga.z, ga.w, gb.x, gb.y, gb.z, gb.w,
                 gc.x, gc.y, gc.z, gc.w};
  float be[12] = {ba.x, ba.y, ba.z, ba.w, bb.x, bb.y, bb.z, bb.w,
                  bc.x, bc.y, bc.z, bc.w};
  union { bf16_t o[12]; uint2 u2[3]; } pk;
#pragma unroll
  for (int u = 0; u < 12; ++u)
    pk.o[u] = (bf16_t)((v[u] - mu) * rstd * g[u] + be[u]);
  bf16_t* hr = hout + (size_t)row * 768 + lane * 12;
#pragma unroll
  for (int u = 0; u < 3; ++u) *(uint2*)&hr[u * 4] = pk.u2[u];
}

// ---- transpose-convert fp32 [K][N] -> bf16 [N][K], per z-slice ----
__global__ __launch_bounds__(256) void k_convT(
    const float* __restrict__ in, size_t in_slice, bf16_t* __restrict__ out,
    size_t out_slice, int N, int K) {
  __shared__ float tbuf[32][33];
  int slice = blockIdx.z;
  const float* ip = in + (size_t)slice * in_slice;
  bf16_t* op = out + (size_t)slice * out_slice;
  int n0 = blockIdx.x * 32, k0 = blockIdx.y * 32;
  int c = threadIdx.x & 31, r8 = threadIdx.x >> 5;
#pragma unroll
  for (int i = 0; i < 4; ++i) {
    int rr = r8 + i * 8;
    tbuf[rr][c] = ip[(size_t)(k0 + rr) * N + n0 + c];
  }
  __syncthreads();
#pragma unroll
  for (int i = 0; i < 4; ++i) {
    int rr = r8 + i * 8;
    op[(size_t)(n0 + rr) * K + k0 + c] = (bf16_t)tbuf[c][rr];
  }
}

// ---- fused wq/wk/wv transpose-convert, NL layers: z = l*36 + which*12 + head
__global__ __launch_bounds__(256) void k_convT3(
    const float* __restrict__ wq, const float* __restrict__ wk,
    const float* __restrict__ wv, bf16_t* __restrict__ out,
    size_t in_lstride, size_t out_lstride) {
  __shared__ float tbuf[32][33];
  int z = blockIdx.z;
  int l = z / 36, r = z % 36;
  int which = r / 12, head = r % 12;
  const float* ip = (which == 0 ? wq : which == 1 ? wk : wv) +
                    (size_t)l * in_lstride + (size_t)head * 768 * 64;
  bf16_t* op = out + (size_t)l * out_lstride + (size_t)which * 768 * 768 +
               (size_t)head * 64 * 768;
  int n0 = blockIdx.x * 32, k0 = blockIdx.y * 32;   // N=64, K=768
  int c = threadIdx.x & 31, r8 = threadIdx.x >> 5;
#pragma unroll
  for (int i = 0; i < 4; ++i) {
    int rr = r8 + i * 8;
    tbuf[rr][c] = ip[(size_t)(k0 + rr) * 64 + n0 + c];
  }
  __syncthreads();
#pragma unroll
  for (int i = 0; i < 4; ++i) {
    int rr = r8 + i * 8;
    op[(size_t)(n0 + rr) * 768 + k0 + c] = (bf16_t)tbuf[c][rr];
  }
}

// ======================================================================
// k_gemm1 (round-10 core): BK=64, SINGLE-buffered LDS (32KB -> 5
// blocks/CU). Best for LARGE grids (QKV, FF1): cross-block overlap.
// EPI 0: store bf16; EPI 2: gelu(C+bias) -> bf16
// ======================================================================
template <int EPI>
__global__ __launch_bounds__(256) void k_gemm1(
    const bf16_t* __restrict__ A, int lda, const bf16_t* __restrict__ Bt,
    int ldb, int K, bf16_t* __restrict__ Cf, bf16_t* __restrict__ Cb, int ldc,
    const float* __restrict__ bias, int gx) {
  __shared__ __attribute__((aligned(16))) bf16_t As[128 * 64];
  __shared__ __attribute__((aligned(16))) bf16_t Bs[128 * 64];
  const int nwg = gridDim.x;
  const int bid = blockIdx.x;
  const int cpx = nwg >> 3;
  const int swz = (bid & 7) * cpx + (bid >> 3);
  const int bx = swz % gx, by = swz / gx;
  const int m0 = by << 7, n0 = bx << 7;
  const int tid = threadIdx.x;
  const int lane = tid & 63, w = tid >> 6;
  const int wm = w >> 1, wn = w & 1;
  const int r = lane & 15, g4 = lane >> 4;

  f32x4 acc[4][4];
#pragma unroll
  for (int m = 0; m < 4; ++m)
#pragma unroll
    for (int n = 0; n < 4; ++n)
#pragma unroll
      for (int e = 0; e < 4; ++e) acc[m][n][e] = 0.f;

  const bf16_t* pa[4];
  const bf16_t* pb[4];
  char* la[4];
  char* lb[4];
#pragma unroll
  for (int u = 0; u < 4; ++u) {
    int s = u * 256 + tid;
    int row = s >> 3;
    int c = (s & 7) ^ (row & 7);
    pa[u] = A + (size_t)(m0 + row) * lda + c * 8;
    pb[u] = Bt + (size_t)(n0 + row) * ldb + c * 8;
    la[u] = (char*)As + (size_t)(u * 256 + (w << 6)) * 16;
    lb[u] = (char*)Bs + (size_t)(u * 256 + (w << 6)) * 16;
  }

  const int NT = K >> 6;
  for (int t = 0; t < NT; ++t) {
    const int k0 = t << 6;
#pragma unroll
    for (int u = 0; u < 4; ++u) gload16(pa[u] + k0, la[u]);
#pragma unroll
    for (int u = 0; u < 4; ++u) gload16(pb[u] + k0, lb[u]);
    __syncthreads();

#pragma unroll
    for (int kk = 0; kk < 2; ++kk) {
      bf16x8 af[4], bb[4];
#pragma unroll
      for (int m = 0; m < 4; ++m) {
        int row = wm * 64 + m * 16 + r;
        af[m] = *(const bf16x8*)&As[row * 64 +
                                    (((kk << 2) + g4) ^ (row & 7)) * 8];
      }
#pragma unroll
      for (int n = 0; n < 4; ++n) {
        int row = wn * 64 + n * 16 + r;
        bb[n] = *(const bf16x8*)&Bs[row * 64 +
                                    (((kk << 2) + g4) ^ (row & 7)) * 8];
      }
#pragma unroll
      for (int m = 0; m < 4; ++m)
#pragma unroll
        for (int n = 0; n < 4; ++n)
          acc[m][n] = __builtin_amdgcn_mfma_f32_16x16x32_bf16(af[m], bb[n],
                                                              acc[m][n], 0, 0, 0);
    }
    __syncthreads();
  }

#pragma unroll
  for (int m = 0; m < 4; ++m) {
#pragma unroll
    for (int n = 0; n < 4; ++n) {
      int col = n0 + wn * 64 + n * 16 + r;
      float bv = 0.f;
      if constexpr (EPI != 0) bv = bias[col];
#pragma unroll
      for (int j = 0; j < 4; ++j) {
        int row = m0 + wm * 64 + m * 16 + g4 * 4 + j;
        float v = acc[m][n][j];
        if constexpr (EPI == 0) {
          Cb[(size_t)row * ldc + col] = (bf16_t)v;
        } else if constexpr (EPI == 1) {
          size_t o = (size_t)row * ldc + col;
          Cf[o] = (bf16_t)(b2f(Cf[o]) + v + bv);
        } else {
          float tt = v + bv;
          float ge = 0.5f * tt * (1.f + erff(tt * 0.70710678118f));
          Cb[(size_t)row * ldc + col] = (bf16_t)ge;
        }
      }
    }
  }
}

// ======================================================================
// k_gemm3h: BM=64 x BN=128 pipelined core: BK=32, THREE-buffer LDS,
// counted vmcnt(3). For SMALL-N GEMMs (WO, FF2): grid 768 = 3 blocks/CU.
// EPI 1: x (bf16) += C + bias (residual RMW)
// ======================================================================
template <int EPI>
__global__ __launch_bounds__(256) void k_gemm3h(
    const bf16_t* __restrict__ A, int lda, const bf16_t* __restrict__ Bt,
    int ldb, int K, bf16_t* __restrict__ Cf, bf16_t* __restrict__ Cb, int ldc,
    const float* __restrict__ bias, int gx) {
  __shared__ __attribute__((aligned(16))) bf16_t As[3][64 * 32];
  __shared__ __attribute__((aligned(16))) bf16_t Bs[3][128 * 32];
  const int nwg = gridDim.x;
  const int bid = blockIdx.x;
  const int cpx = nwg >> 3;
  const int swz = (bid & 7) * cpx + (bid >> 3);
  const int bx = swz % gx, by = swz / gx;
  const int m0 = by << 6, n0 = bx << 7;     // BM=64, BN=128
  const int tid = threadIdx.x;
  const int lane = tid & 63, w = tid >> 6;
  const int wm = w >> 1, wn = w & 1;        // 2M x 2N -> wave tile 32x64
  const int r = lane & 15, g4 = lane >> 4;

  f32x4 acc[2][4];
#pragma unroll
  for (int m = 0; m < 2; ++m)
#pragma unroll
    for (int n = 0; n < 4; ++n)
#pragma unroll
      for (int e = 0; e < 4; ++e) acc[m][n][e] = 0.f;

  const bf16_t* pa0;
  const bf16_t* pb[2];
  uint32_t loa, lob[2];
  {
    int s = tid;
    int row = s >> 2;
    int c = (s & 3) ^ ((row >> 1) & 3);
    pa0 = A + (size_t)(m0 + row) * lda + c * 8;
    loa = (uint32_t)(w << 6) * 16;
#pragma unroll
    for (int u = 0; u < 2; ++u) {
      int sb = u * 256 + tid;
      int rowb = sb >> 2;
      int cb = (sb & 3) ^ ((rowb >> 1) & 3);
      pb[u] = Bt + (size_t)(n0 + rowb) * ldb + cb * 8;
      lob[u] = (uint32_t)(u * 256 + (w << 6)) * 16;
    }
  }

  const int NT = K >> 5;
  auto STAGE = [&](int t, int bufi) {
    int k0 = (t < NT ? t : NT - 1) << 5;    // clamped dummy tail stage
    gload16(pa0 + k0, (char*)&As[bufi][0] + loa);
#pragma unroll
    for (int u = 0; u < 2; ++u) gload16(pb[u] + k0, (char*)&Bs[bufi][0] + lob[u]);
  };

  STAGE(0, 0);
  STAGE(1, 1);
  int bi = 0, si = 2;
  const int co = (g4 ^ ((r >> 1) & 3)) << 3;
  for (int t = 0; t < NT; ++t) {
    asm volatile("s_waitcnt vmcnt(3)" ::: "memory");
    asm volatile("s_barrier" ::: "memory");
    bf16x8 af[2], bb[4];
#pragma unroll
    for (int m = 0; m < 2; ++m) {
      int row = wm * 32 + m * 16 + r;
      af[m] = *(const bf16x8*)&As[bi][row * 32 + co];
    }
#pragma unroll
    for (int n = 0; n < 4; ++n) {
      int row = wn * 64 + n * 16 + r;
      bb[n] = *(const bf16x8*)&Bs[bi][row * 32 + co];
    }
#pragma unroll
    for (int m = 0; m < 2; ++m)
#pragma unroll
      for (int n = 0; n < 4; ++n)
        acc[m][n] = __builtin_amdgcn_mfma_f32_16x16x32_bf16(af[m], bb[n],
                                                            acc[m][n], 0, 0, 0);
    asm volatile("s_barrier" ::: "memory");
    STAGE(t + 2, si);
    si = bi;
    bi = (bi == 2) ? 0 : bi + 1;
  }
  asm volatile("s_waitcnt vmcnt(0)" ::: "memory");

#pragma unroll
  for (int m = 0; m < 2; ++m) {
#pragma unroll
    for (int n = 0; n < 4; ++n) {
      int col = n0 + wn * 64 + n * 16 + r;
      float bv = 0.f;
      if constexpr (EPI != 0) bv = bias[col];
#pragma unroll
      for (int j = 0; j < 4; ++j) {
        int row = m0 + wm * 32 + m * 16 + g4 * 4 + j;
        float v = acc[m][n][j];
        if constexpr (EPI == 0) {
          Cb[(size_t)row * ldc + col] = (bf16_t)v;
        } else if constexpr (EPI == 1) {
          size_t o = (size_t)row * ldc + col;
          Cf[o] = (bf16_t)(b2f(Cf[o]) + v + bv);
        } else {
          float tt = v + bv;
          float ge = 0.5f * tt * (1.f + erff(tt * 0.70710678118f));
          Cb[(size_t)row * ldc + col] = (bf16_t)ge;
        }
      }
    }
  }
}

// ======================================================================
// Fused attention (log-softmax decomposition), one block per (b,h),
// 512 threads (8 waves). Round-16 structure + merged aq-load (QK^T and
// Q*Mt share the same A-fragment per kk).
// ======================================================================
__global__ __launch_bounds__(512) void k_attn(const bf16_t* __restrict__ qkv,
                                              bf16_t* __restrict__ ctx) {
  __shared__ __attribute__((aligned(16))) bf16_t Ks[512 * 64];    // swizzled
  __shared__ __attribute__((aligned(16))) float Vs[128 * 64];
  __shared__ __attribute__((aligned(16))) bf16_t Qs[2][128 * 64]; // swizzled
  __shared__ __attribute__((aligned(16))) bf16_t Mt[64 * 64];     // swizzled
  __shared__ float svp[8 * 64];
  __shared__ float svs[64];

  int bh = blockIdx.x;
  int b = bh / 12, hh = bh % 12;
  int tid = threadIdx.x, lane = tid & 63, w = tid >> 6;   // 8 waves
  int r = lane & 15, g4 = lane >> 4;
  const bf16_t* qb = qkv + (size_t)b * 512 * 2304 + hh * 64;
  const bf16_t* kb = qb + 768;
  const bf16_t* vb = qb + 1536;

#pragma unroll
  for (int i = 0; i < 8; ++i) {
    int s = i * 512 + tid;
    int row = s >> 3;
    int c = (s & 7) ^ (row & 7);
    gload16(kb + (size_t)row * 2304 + c * 8,
            (char*)Ks + (size_t)(i * 512 + (w << 6)) * 16);
  }

  f32x4 macc[2];
#pragma unroll
  for (int jj = 0; jj < 2; ++jj)
#pragma unroll
    for (int e = 0; e < 4; ++e) macc[jj][e] = 0.f;
  float svacc = 0.f;
  const int e1hi = (lane >> 3), e1lo = (lane & 7);

  bf16x8 vreg[2];
  auto ldV = [&](int t0) {
#pragma unroll
    for (int i = 0; i < 2; ++i) {
      int cs = i * 512 + tid;
      int row = cs >> 3, col = (cs & 7) * 8;
      vreg[i] = *(const bf16x8*)(vb + (size_t)(t0 + row) * 2304 + col);
    }
  };
  auto wrV = [&]() {
#pragma unroll
    for (int i = 0; i < 2; ++i) {
      int cs = i * 512 + tid;
      int row = cs >> 3, col = (cs & 7) * 8;
      f32x4 v0, v1;
#pragma unroll
      for (int u = 0; u < 4; ++u) {
        v0[u] = (float)vreg[i][u];
        v1[u] = (float)vreg[i][u + 4];
      }
      *(f32x4*)&Vs[row * 64 + col] = v0;
      *(f32x4*)&Vs[row * 64 + col + 4] = v1;
    }
  };

  ldV(0);
  wrV();
  __syncthreads();

  for (int t0 = 0; t0 < 4; ++t0) {
    if (t0 < 3) ldV((t0 + 1) * 128);
#pragma unroll 8
    for (int tt = 0; tt < 128; ++tt) {
      int t = t0 * 128 + tt;
      float kv = (float)Ks[t * 64 + (((e1hi ^ (t & 7)) << 3) | e1lo)];
#pragma unroll
      for (int jj = 0; jj < 2; ++jj) {
        f32x4 vv = *(const f32x4*)&Vs[tt * 64 + w * 8 + jj * 4];
        macc[jj] += kv * vv;
      }
    }
#pragma unroll
    for (int q = 0; q < 16; ++q)
      svacc += Vs[((w << 4) + q) * 64 + lane];
    __syncthreads();
    if (t0 < 3) {
      wrV();
      __syncthreads();
    }
  }

#pragma unroll
  for (int jj = 0; jj < 2; ++jj)
#pragma unroll
    for (int u = 0; u < 4; ++u) {
      int e2 = w * 8 + jj * 4 + u;
      Mt[e2 * 64 + (((e1hi ^ (e2 & 7)) << 3) | e1lo)] =
          (bf16_t)(macc[jj][u] * 0.125f);
    }
  svp[w * 64 + lane] = svacc;
  __syncthreads();
  if (w == 0) {
    float s = 0.f;
#pragma unroll
    for (int u = 0; u < 8; ++u) s += svp[u * 64 + lane];
    svs[lane] = s;
  }

  auto stageQ = [&](int qc, int bufi) {
#pragma unroll
    for (int u = 0; u < 2; ++u) {
      int s = u * 512 + tid;
      int row = s >> 3;
      int c = (s & 7) ^ (row & 7);
      gload16(qb + (size_t)(qc * 128 + row) * 2304 + c * 8,
              (char*)&Qs[bufi][0] + (size_t)(u * 512 + (w << 6)) * 16);
    }
  };
  stageQ(0, 0);
  const int arow = w * 16 + r;

  for (int qc = 0; qc < 4; ++qc) {
    __syncthreads();
    if (qc < 3) stageQ(qc + 1, (qc + 1) & 1);
    const bf16_t* Qb = &Qs[qc & 1][0];

    f32x4 acc2[32];
    f32x4 acc3[4];
#pragma unroll
    for (int n = 0; n < 32; ++n)
#pragma unroll
      for (int e = 0; e < 4; ++e) acc2[n][e] = 0.f;
#pragma unroll
    for (int n = 0; n < 4; ++n)
#pragma unroll
      for (int e = 0; e < 4; ++e) acc3[n][e] = 0.f;

#pragma unroll
    for (int kk = 0; kk < 2; ++kk) {
      bf16x8 aq = *(const bf16x8*)&Qb[arow * 64 +
                                      (((kk << 2) + g4) ^ (arow & 7)) * 8];
#pragma unroll
      for (int n = 0; n < 32; ++n) {
        int krow = n * 16 + r;
        bf16x8 bk = *(const bf16x8*)&Ks[krow * 64 +
                                        (((kk << 2) + g4) ^ (krow & 7)) * 8];
        acc2[n] = __builtin_amdgcn_mfma_f32_16x16x32_bf16(aq, bk, acc2[n], 0, 0, 0);
      }
#pragma unroll
      for (int n2 = 0; n2 < 4; ++n2) {
        int mrow = n2 * 16 + r;
        bf16x8 bm = *(const bf16x8*)&Mt[mrow * 64 +
                                        (((kk << 2) + g4) ^ (mrow & 7)) * 8];
        acc3[n2] = __builtin_amdgcn_mfma_f32_16x16x32_bf16(aq, bm, acc3[n2], 0, 0, 0);
      }
    }

    float lse_j[4];
#pragma unroll
    for (int j = 0; j < 4; ++j) {
      float mx = -1e30f;
#pragma unroll
      for (int n = 0; n < 32; ++n) mx = fmaxf(mx, acc2[n][j] * 0.125f);
#pragma unroll
      for (int o = 1; o < 16; o <<= 1) mx = fmaxf(mx, __shfl_xor(mx, o, 64));
      float sm = 0.f;
#pragma unroll
      for (int n = 0; n < 32; ++n) sm += __expf(acc2[n][j] * 0.125f - mx);
#pragma unroll
      for (int o = 1; o < 16; o <<= 1) sm += __shfl_xor(sm, o, 64);
      lse_j[j] = mx + __logf(sm);
    }

#pragma unroll
    for (int n2 = 0; n2 < 4; ++n2) {
      int col = n2 * 16 + r;
      float svv = svs[col];
#pragma unroll
      for (int j = 0; j < 4; ++j) {
        int srow = qc * 128 + w * 16 + g4 * 4 + j;
        ctx[((size_t)(b * 512 + srow)) * 768 + hh * 64 + col] =
            (bf16_t)(acc3[n2][j] - lse_j[j] * svv);
      }
    }
  }
}

// ---- final LN (row s=0 per batch) + classifier ----
__global__ __launch_bounds__(192) void k_final(
    const bf16_t* __restrict__ x, const float* __restrict__ gam,
    const float* __restrict__ bet, const float* __restrict__ cw,
    const float* __restrict__ cb, float* __restrict__ out) {
  __shared__ float red[3];
  int b = blockIdx.x, t = threadIdx.x;
  const bf16_t* xr = x + (size_t)b * 512 * 768;
  union { uint2 u; bf16_t h[4]; } ux;
  ux.u = *(const uint2*)&xr[t * 4];
  float v[4] = {b2f(ux.h[0]), b2f(ux.h[1]), b2f(ux.h[2]), b2f(ux.h[3])};
  float tot = bsum3(v[0] + v[1] + v[2] + v[3], red);
  float mu = tot * (1.f / 768.f);
  float sq = 0.f;
#pragma unroll
  for (int u = 0; u < 4; ++u) { float d = v[u] - mu; sq += d * d; }
  float var = bsum3(sq, red) * (1.f / 768.f);
  float rstd = rsqrtf(var + 1e-5f);
  const float4 g4 = *(const float4*)&gam[t * 4];
  const float4 b4 = *(const float4*)&bet[t * 4];
  float nv[4];
  nv[0] = (v[0] - mu) * rstd * g4.x + b4.x;
  nv[1] = (v[1] - mu) * rstd * g4.y + b4.y;
  nv[2] = (v[2] - mu) * rstd * g4.z + b4.z;
  nv[3] = (v[3] - mu) * rstd * g4.w + b4.w;
  const float4 wa = *(const float4*)&cw[t * 8];
  const float4 wb = *(const float4*)&cw[t * 8 + 4];
  float d0 = nv[0] * wa.x + nv[1] * wa.z + nv[2] * wb.x + nv[3] * wb.z;
  float d1 = nv[0] * wa.y + nv[1] * wa.w + nv[2] * wb.y + nv[3] * wb.w;
  d0 = bsum3(d0, red);
  d1 = bsum3(d1, red);
  if (t == 0) {
    out[b * 2 + 0] = d0 + cb[0];
    out[b * 2 + 1] = d1 + cb[1];
  }
}

// ---- workspace layout (x slot kept at fp32 size; bf16 uses half) ----
static constexpr size_t OFF_X = 0;                                  // bf16 8192x768
static constexpr size_t OFF_H = OFF_X + 8192ull * 768 * 4;          // bf16 8192x768
static constexpr size_t OFF_QG = OFF_H + 8192ull * 768 * 2;         // bf16 arena (qkv | gelu)
static constexpr size_t OFF_CTX = OFF_QG + 8192ull * 3072 * 2;      // bf16 8192x768
static constexpr size_t OFF_LSE = OFF_CTX + 8192ull * 768 * 2;      // (unused)
static constexpr size_t OFF_W = OFF_LSE + 192ull * 512 * 4;         // bf16 weights
static constexpr size_t WPL = 7077888;                              // elems per layer
static constexpr size_t WS_SMALL = OFF_W + WPL * 2;                 // 1-layer buffer
static constexpr size_t WS_BIG = OFF_W + 12ull * WPL * 2;           // all layers

extern "C" void kernel_launch(void* const* d_in, const int* in_sizes, int n_in,
                              void* d_out, int out_size, void* d_ws,
                              size_t ws_size, hipStream_t stream) {
  const int* ids = (const int*)d_in[0];
  const float* tok = (const float*)d_in[1];
  const float* pos = (const float*)d_in[2];
  const float* eln_s = (const float*)d_in[3];
  const float* eln_b = (const float*)d_in[4];
  const float* wq = (const float*)d_in[5];
  const float* wk = (const float*)d_in[6];
  const float* wv = (const float*)d_in[7];
  const float* wo = (const float*)d_in[8];
  const float* wo_b = (const float*)d_in[9];
  const float* ln1_s = (const float*)d_in[10];
  const float* ln1_b = (const float*)d_in[11];
  const float* ln2_s = (const float*)d_in[12];
  const float* ln2_b = (const float*)d_in[13];
  const float* ff1w = (const float*)d_in[14];
  const float* ff1b = (const float*)d_in[15];
  const float* ff2w = (const float*)d_in[16];
  const float* ff2b = (const float*)d_in[17];
  const float* fln_s = (const float*)d_in[18];
  const float* fln_b = (const float*)d_in[19];
  const float* cw = (const float*)d_in[20];
  const float* cb = (const float*)d_in[21];
  float* out = (float*)d_out;

  if (ws_size < WS_SMALL) return;
  const bool big = ws_size >= WS_BIG;

  char* ws = (char*)d_ws;
  bf16_t* x = (bf16_t*)(ws + OFF_X);
  bf16_t* h = (bf16_t*)(ws + OFF_H);
  bf16_t* qkv = (bf16_t*)(ws + OFF_QG);
  bf16_t* gbuf = (bf16_t*)(ws + OFF_QG);
  bf16_t* ctx = (bf16_t*)(ws + OFF_CTX);
  bf16_t* wT = (bf16_t*)(ws + OFF_W);

  // embedding + emb-LN + ln1(layer0)
  k_embed<<<8192, 192, 0, stream>>>(ids, tok, pos, eln_s, eln_b,
                                    ln1_s, ln1_b, x, h);

  if (big) {
    // convert ALL layers' weights upfront: 4 launches
    k_convT3<<<dim3(2, 24, 432), 256, 0, stream>>>(wq, wk, wv, wT,
                                                   589824, WPL);
    k_convT<<<dim3(24, 24, 12), 256, 0, stream>>>(wo, 589824,
                                                  wT + 1769472, WPL, 768, 768);
    k_convT<<<dim3(96, 24, 12), 256, 0, stream>>>(ff1w, 2359296,
                                                  wT + 2359296, WPL, 3072, 768);
    k_convT<<<dim3(24, 96, 12), 256, 0, stream>>>(ff2w, 2359296,
                                                  wT + 4718592, WPL, 768, 3072);
  }

  for (int l = 0; l < 12; ++l) {
    bf16_t* wl = big ? wT + (size_t)l * WPL : wT;
    bf16_t* qkvT = wl;
    bf16_t* woT = wl + 1769472;
    bf16_t* ff1T = wl + 2359296;
    bf16_t* ff2T = wl + 4718592;

    if (l > 0)
      k_ln<<<2048, 256, 0, stream>>>(x, h, ln1_s + l * 768, ln1_b + l * 768);
    if (!big) {
      k_convT3<<<dim3(2, 24, 36), 256, 0, stream>>>(
          wq + (size_t)l * 589824, wk + (size_t)l * 589824,
          wv + (size_t)l * 589824, qkvT, 589824, 0);
      k_convT<<<dim3(24, 24, 1), 256, 0, stream>>>(wo + (size_t)l * 589824, 0,
                                                   woT, 0, 768, 768);
      k_convT<<<dim3(96, 24, 1), 256, 0, stream>>>(ff1w + (size_t)l * 2359296,
                                                   0, ff1T, 0, 3072, 768);
      k_convT<<<dim3(24, 96, 1), 256, 0, stream>>>(ff2w + (size_t)l * 2359296,
                                                   0, ff2T, 0, 768, 3072);
    }
    // QKV: M=8192 N=2304 K=768 -> grid 1152 (large: single-buf core)
    k_gemm1<0><<<1152, 256, 0, stream>>>(h, 768, qkvT, 768, 768,
                                         nullptr, qkv, 2304, nullptr, 18);
    // fused attention (log-softmax decomposition), 8 waves/block
    k_attn<<<192, 512, 0, stream>>>(qkv, ctx);
    // WO + residual: BM=64 pipelined core -> grid 6*128=768
    k_gemm3h<1><<<768, 256, 0, stream>>>(ctx, 768, woT, 768, 768, x,
                                         nullptr, 768, wo_b + l * 768, 6);
    // FFN
    k_ln<<<2048, 256, 0, stream>>>(x, h, ln2_s + l * 768, ln2_b + l * 768);
    // FF1: grid 1536 (large: single-buf core)
    k_gemm1<2><<<1536, 256, 0, stream>>>(h, 768, ff1T, 768, 768,
                                         nullptr, gbuf, 3072,
                                         ff1b + l * 3072, 24);
    // FF2: BM=64 pipelined core -> grid 6*128=768
    k_gemm3h<1><<<768, 256, 0, stream>>>(gbuf, 3072, ff2T, 3072, 3072, x,
                                         nullptr, 768, ff2b + l * 768, 6);
  }
  k_final<<<16, 192, 0, stream>>>(x, fln_s, fln_b, cw, cb, out);
}